// Round 4
// baseline (1181.767 us; speedup 1.0000x reference)
//
#include <hip/hip_runtime.h>
#include <hip/hip_bf16.h>
#include <math.h>

// Problem constants
#define B_   64
#define N_   576
#define D_   768
#define L_   64
#define H_   8
#define HD_  96
#define NB_  (B_*N_)    // 36864 rows
#define ML_  (B_*L_)    // 4096 rows
#define KV_STRIDE_ 1536
#define SCALE_ 0.10206207f          // 96^-0.5
#define INV_SQRT_D_ 0.03608439182f  // 1/sqrt(768)
#define LO_SCALE_ 4.8828125e-4f     // 2^-11

typedef __hip_bfloat16 bf16;
typedef __attribute__((ext_vector_type(8))) short short8v;      // 8 bf16 (4 VGPRs)
typedef __attribute__((ext_vector_type(8))) _Float16 half8v;    // 8 fp16 (4 VGPRs)
typedef __attribute__((ext_vector_type(4))) float floatx4;      // MFMA C/D

__device__ __forceinline__ float u2f(unsigned short u) { return __uint_as_float(((unsigned)u) << 16); }
__device__ __forceinline__ unsigned short f2bu(float f) {
  bf16 h = __float2bfloat16(f);
  return *(unsigned short*)&h;
}
__device__ __forceinline__ float h2f(unsigned short u) {
  _Float16 h; __builtin_memcpy(&h, &u, 2);
  return (float)h;
}

// ---------------------------------------------------------------------------
// K1: LayerNorm1 -> fp16 hi/lo split planes + token_score + row sum-of-squares
// ---------------------------------------------------------------------------
__global__ __launch_bounds__(256) void k_ln1(const float* __restrict__ x,
    const float* __restrict__ g, const float* __restrict__ bt,
    const float* __restrict__ sw, const float* __restrict__ sb,
    unsigned short* __restrict__ xh, unsigned short* __restrict__ xl,
    float* __restrict__ ts, float* __restrict__ sq)
{
  int row = blockIdx.x, tid = threadIdx.x;
  const float* xr = x + (size_t)row * D_;
  float v0 = xr[tid], v1 = xr[tid + 256], v2 = xr[tid + 512];
  __shared__ float r1[256], r2[256];
  r1[tid] = v0 + v1 + v2;
  r2[tid] = v0 * v0 + v1 * v1 + v2 * v2;
  __syncthreads();
  for (int o = 128; o > 0; o >>= 1) {
    if (tid < o) { r1[tid] += r1[tid + o]; r2[tid] += r2[tid + o]; }
    __syncthreads();
  }
  float mean = r1[0] * (1.0f / D_);
  float var  = r2[0] * (1.0f / D_) - mean * mean;
  float rstd = rsqrtf(var + 1e-5f);
  __syncthreads();
  float o0 = (v0 - mean) * rstd * g[tid      ] + bt[tid      ];
  float o1 = (v1 - mean) * rstd * g[tid + 256] + bt[tid + 256];
  float o2 = (v2 - mean) * rstd * g[tid + 512] + bt[tid + 512];
  auto split = [](float o, unsigned short& hu, unsigned short& lu) {
    _Float16 h = (_Float16)o;
    float hf = (float)h;
    _Float16 l = (_Float16)((o - hf) * 2048.0f);
    __builtin_memcpy(&hu, &h, 2);
    __builtin_memcpy(&lu, &l, 2);
  };
  unsigned short h0, l0, h1, l1, h2, l2;
  split(o0, h0, l0); split(o1, h1, l1); split(o2, h2, l2);
  unsigned short* xho = xh + (size_t)row * D_;
  unsigned short* xlo = xl + (size_t)row * D_;
  xho[tid] = h0; xho[tid + 256] = h1; xho[tid + 512] = h2;
  xlo[tid] = l0; xlo[tid + 256] = l1; xlo[tid + 512] = l2;
  r1[tid] = o0 * sw[tid] + o1 * sw[tid + 256] + o2 * sw[tid + 512];
  r2[tid] = o0 * o0 + o1 * o1 + o2 * o2;
  __syncthreads();
  for (int o = 128; o > 0; o >>= 1) {
    if (tid < o) { r1[tid] += r1[tid + o]; r2[tid] += r2[tid + o]; }
    __syncthreads();
  }
  if (tid == 0) { ts[row] = r1[0] + sb[0]; sq[row] = r2[0]; }
}

// ---------------------------------------------------------------------------
// K2: pairwise distances via fp16x2 split-precision MFMA Gram.
// LDS double-buffered 2-phase pipeline (T3-min + T14 early-issue):
//   loads for K-step t+2 issued at iteration start (latency hidden under
//   MFMA phase), ds_write for t+1 after compute, ONE barrier per K-step.
// XCD batch-affinity swizzle: grid 1344=8*168 flattened; all 21 tiles of a
// batch run on one XCD -> its L2 (4MB) holds the batch panels (1.77MB).
// Numerics identical to prior rounds (same term order). Fused batch-max.
// ---------------------------------------------------------------------------
#define PA_AH 0
#define PA_AL 3840
#define PA_BH 7680
#define PA_BL 11520
__global__ __launch_bounds__(256) void k_dmg(const unsigned short* __restrict__ xh,
    const unsigned short* __restrict__ xl, const float* __restrict__ sq,
    float* __restrict__ dm, float* __restrict__ dmax)
{
  __shared__ __align__(16) unsigned short S[2][4 * 96 * 40];   // 61440 B
  int flat = blockIdx.x;
  int xcd = flat & 7, seq = flat >> 3;
  int b = (seq / 21) * 8 + xcd;
  int t = seq % 21;
  int ti = 0, rl = 6;
  while (t >= rl) { t -= rl; ++ti; --rl; }
  int tj = ti + t;
  int tid = threadIdx.x;
  int wave = tid >> 6, lane = tid & 63;
  int wr = (wave >> 1) * 48, wc = (wave & 1) * 48;
  int mloc = lane & 15, quad = lane >> 4;
  size_t rowA = (size_t)b * N_ + ti * 96;
  size_t rowB = (size_t)b * N_ + tj * 96;

  // uniform staging map: 6 chunks/thread over 4 panels x 96 rows x 4 chunks
  const unsigned short* gp[6];
  int lofs[6];
#pragma unroll
  for (int p = 0; p < 6; ++p) {
    int idx = tid + p * 256;
    int panel = idx / 384, within = idx % 384;
    int r = within >> 2, c = within & 3;
    const unsigned short* base =
        (panel == 0) ? xh + rowA * D_ :
        (panel == 1) ? xl + rowA * D_ :
        (panel == 2) ? xh + rowB * D_ : xl + rowB * D_;
    gp[p] = base + (size_t)r * D_ + c * 8;
    lofs[p] = panel * 3840 + r * 40 + c * 8;
  }

  floatx4 a1[3][3], a2[3][3];
#pragma unroll
  for (int i = 0; i < 3; ++i)
#pragma unroll
    for (int j = 0; j < 3; ++j) {
      a1[i][j] = (floatx4){0.f, 0.f, 0.f, 0.f};
      a2[i][j] = (floatx4){0.f, 0.f, 0.f, 0.f};
    }

  uint4 rgA[6], rgB[6];
  auto LOAD = [&](uint4* rg, int kt) {
#pragma unroll
    for (int p = 0; p < 6; ++p) rg[p] = *(const uint4*)(gp[p] + kt);
  };
  auto WRITE = [&](int bufi, const uint4* rg) {
#pragma unroll
    for (int p = 0; p < 6; ++p) *(uint4*)&S[bufi][lofs[p]] = rg[p];
  };
  auto COMPUTE = [&](int bufi) {
    const unsigned short* Sb = S[bufi];
    half8v ah[3], al[3], bh[3], bl[3];
#pragma unroll
    for (int i = 0; i < 3; ++i) {
      int ro = (wr + i * 16 + mloc) * 40 + quad * 8;
      ah[i] = *(const half8v*)&Sb[PA_AH + ro];
      al[i] = *(const half8v*)&Sb[PA_AL + ro];
    }
#pragma unroll
    for (int j = 0; j < 3; ++j) {
      int ro = (wc + j * 16 + mloc) * 40 + quad * 8;
      bh[j] = *(const half8v*)&Sb[PA_BH + ro];
      bl[j] = *(const half8v*)&Sb[PA_BL + ro];
    }
#pragma unroll
    for (int i = 0; i < 3; ++i)
#pragma unroll
      for (int j = 0; j < 3; ++j) {
        a1[i][j] = __builtin_amdgcn_mfma_f32_16x16x32_f16(ah[i], bh[j], a1[i][j], 0, 0, 0);
        a2[i][j] = __builtin_amdgcn_mfma_f32_16x16x32_f16(ah[i], bl[j], a2[i][j], 0, 0, 0);
        a2[i][j] = __builtin_amdgcn_mfma_f32_16x16x32_f16(al[i], bh[j], a2[i][j], 0, 0, 0);
      }
  };

  // prologue
  LOAD(rgA, 0);
  WRITE(0, rgA);
  LOAD(rgA, 32);
  __syncthreads();
  // main: 24 K-steps, unrolled by 2 (named regsets -> all indices static)
#pragma unroll 1
  for (int t2 = 0; t2 < 24; t2 += 2) {
    if (t2 < 22) LOAD(rgB, (t2 + 2) * 32);
    COMPUTE(0);
    WRITE(1, rgA);
    __syncthreads();
    if (t2 < 21) LOAD(rgA, (t2 + 3) * 32);
    COMPUTE(1);
    if (t2 < 22) WRITE(0, rgB);
    __syncthreads();
  }

  const float* sqb = sq + b * N_;
  float* dmb = dm + (size_t)b * N_ * N_;
  bool diag = (ti == tj);
  float vmax = 0.f;
#pragma unroll
  for (int j = 0; j < 3; ++j) {
    int gj = tj * 96 + wc + j * 16 + mloc;
    float sj = sqb[gj];
#pragma unroll
    for (int i = 0; i < 3; ++i) {
      int gi0 = ti * 96 + wr + i * 16 + quad * 4;
#pragma unroll
      for (int reg = 0; reg < 4; ++reg) {
        int gi = gi0 + reg;
        float g = a1[i][j][reg] + a2[i][j][reg] * LO_SCALE_;
        float d = sqb[gi] + sj - 2.0f * g;
        float v = sqrtf(fmaxf(d, 0.0f)) * INV_SQRT_D_;
        vmax = fmaxf(vmax, v);
        if (!diag || gj >= gi) {
          dmb[(size_t)gi * N_ + gj] = v;
          dmb[(size_t)gj * N_ + gi] = v;
        }
      }
    }
  }
#pragma unroll
  for (int msk = 32; msk >= 1; msk >>= 1) vmax = fmaxf(vmax, __shfl_xor(vmax, msk));
  if (lane == 0) atomicMax((unsigned int*)(dmax + b), __float_as_uint(vmax));
}

// ---------------------------------------------------------------------------
// K3: kNN density
// ---------------------------------------------------------------------------
__global__ __launch_bounds__(64) void k_density(const float* __restrict__ dm,
    const float* __restrict__ noise, float* __restrict__ den)
{
  int row = blockIdx.x, lane = threadIdx.x;
  const float* r = dm + (size_t)row * N_;
  float a0 = 1e30f, a1 = 1e30f, a2 = 1e30f, a3 = 1e30f, a4 = 1e30f;
  auto ins5 = [&](float xv) {
    a4 = fminf(a4, xv);
    float t;
    t = fminf(a3, a4); a4 = fmaxf(a3, a4); a3 = t;
    t = fminf(a2, a3); a3 = fmaxf(a2, a3); a2 = t;
    t = fminf(a1, a2); a2 = fmaxf(a1, a2); a1 = t;
    t = fminf(a0, a1); a1 = fmaxf(a0, a1); a0 = t;
  };
#pragma unroll
  for (int t = 0; t < 9; ++t) ins5(r[lane + 64 * t]);
  for (int m = 1; m < 64; m <<= 1) {
    float b0 = __shfl_xor(a0, m), b1 = __shfl_xor(a1, m), b2 = __shfl_xor(a2, m);
    float b3 = __shfl_xor(a3, m), b4 = __shfl_xor(a4, m);
    ins5(b0); ins5(b1); ins5(b2); ins5(b3); ins5(b4);
  }
  if (lane == 0) {
    float ms = (a0 * a0 + a1 * a1 + a2 * a2 + a3 * a3 + a4 * a4) * 0.2f;
    den[row] = expf(-ms) + noise[row] * 1e-6f;
  }
}

// ---------------------------------------------------------------------------
// K5: dist-to-higher-density + score
// ---------------------------------------------------------------------------
__global__ __launch_bounds__(64) void k_dist(const float* __restrict__ dm,
    const float* __restrict__ den, const float* __restrict__ dmax,
    float* __restrict__ score)
{
  int row = blockIdx.x, lane = threadIdx.x;
  int b = row / N_;
  float di = den[row], dx = dmax[b];
  const float* r = dm + (size_t)row * N_;
  const float* db = den + b * N_;
  float m = dx;
#pragma unroll
  for (int t = 0; t < 9; ++t) {
    int j = lane + 64 * t;
    float v = (db[j] > di) ? r[j] : dx;
    m = fminf(m, v);
  }
  for (int msk = 1; msk < 64; msk <<= 1) m = fminf(m, __shfl_xor(m, msk));
  if (lane == 0) score[row] = m * di;
}

// ---------------------------------------------------------------------------
// K6: top-64 scores per batch
// ---------------------------------------------------------------------------
__global__ __launch_bounds__(256) void k_topL(const float* __restrict__ score,
    int* __restrict__ idxd)
{
  int b = blockIdx.x, tid = threadIdx.x;
  __shared__ float s[N_];
  __shared__ float rv[256];
  __shared__ int   ri[256];
  for (int j = tid; j < N_; j += 256) s[j] = score[b * N_ + j];
  __syncthreads();
  for (int it = 0; it < L_; ++it) {
    float bv = -1e30f; int bi = 1 << 30;
    for (int j = tid; j < N_; j += 256) {
      float v = s[j];
      if (v > bv || (v == bv && j < bi)) { bv = v; bi = j; }
    }
    rv[tid] = bv; ri[tid] = bi; __syncthreads();
    for (int o = 128; o > 0; o >>= 1) {
      if (tid < o) {
        float v2 = rv[tid + o]; int i2 = ri[tid + o];
        if (v2 > rv[tid] || (v2 == rv[tid] && i2 < ri[tid])) { rv[tid] = v2; ri[tid] = i2; }
      }
      __syncthreads();
    }
    if (tid == 0) { idxd[b * L_ + it] = ri[0]; s[ri[0]] = -1e30f; }
    __syncthreads();
  }
}

// ---------------------------------------------------------------------------
// K7: assign tokens to nearest center (+ fused center self-assignment)
// ---------------------------------------------------------------------------
__global__ __launch_bounds__(576) void k_assign(const float* __restrict__ dm,
    const int* __restrict__ idxd, int* __restrict__ idxc)
{
  int b = blockIdx.x, n = threadIdx.x;
  __shared__ int ctr[L_];
  if (n < L_) ctr[n] = idxd[b * L_ + n];
  __syncthreads();
  const float* dmb = dm + (size_t)b * N_ * N_;
  float best = 1e30f; int bl = 0;
  for (int l = 0; l < L_; ++l) {
    float v = dmb[(size_t)ctr[l] * N_ + n];
    if (v < best) { best = v; bl = l; }
  }
  for (int l = 0; l < L_; ++l)
    if (ctr[l] == n) bl = l;
  idxc[b * N_ + n] = bl;
}

// ---------------------------------------------------------------------------
// K8: merger (gather form) — reconstructs xn = hi + lo*2^-11
// ---------------------------------------------------------------------------
__global__ __launch_bounds__(256) void k_merge(const unsigned short* __restrict__ xh,
    const unsigned short* __restrict__ xl,
    const float* __restrict__ ts, const int* __restrict__ idxc,
    float* __restrict__ qin)
{
  int blk = blockIdx.x;
  int b = blk >> 6, l = blk & 63;
  int tid = threadIdx.x;
  const int* ic = idxc + b * N_;
  const float* tsb = ts + b * N_;
  const unsigned short* xhb = xh + (size_t)b * N_ * D_;
  const unsigned short* xlb = xl + (size_t)b * N_ * D_;
  float a0 = 0.f, a1 = 0.f, a2 = 0.f, wsum = 0.f;
  for (int n = 0; n < N_; ++n) {
    if (ic[n] == l) {
      float w = expf(tsb[n]);
      wsum += w;
      const unsigned short* hr = xhb + (size_t)n * D_;
      const unsigned short* lr = xlb + (size_t)n * D_;
      float x0 = h2f(hr[tid      ]) + h2f(lr[tid      ]) * LO_SCALE_;
      float x1 = h2f(hr[tid + 256]) + h2f(lr[tid + 256]) * LO_SCALE_;
      float x2 = h2f(hr[tid + 512]) + h2f(lr[tid + 512]) * LO_SCALE_;
      a0 += w * x0; a1 += w * x1; a2 += w * x2;
    }
  }
  float inv = 1.0f / (wsum + 1e-6f);
  float* q = qin + (size_t)blk * D_;
  q[tid] = a0 * inv; q[tid + 256] = a1 * inv; q[tid + 512] = a2 * inv;
}

// ---------------------------------------------------------------------------
// Weight transpose + bf16 cast: W[K,N] fp32 -> WT[N,K] bf16
// ---------------------------------------------------------------------------
__global__ __launch_bounds__(256) void k_wt(const float* __restrict__ W,
    bf16* __restrict__ WT, int K, int N)
{
  __shared__ float t[32][33];
  int k0 = blockIdx.x * 32, n0 = blockIdx.y * 32;
  int tid = threadIdx.x;
  int r = tid >> 3, c4 = (tid & 7) * 4;
  float4 v = *(const float4*)(W + (size_t)(k0 + r) * N + n0 + c4);
  t[r][c4] = v.x; t[r][c4 + 1] = v.y; t[r][c4 + 2] = v.z; t[r][c4 + 3] = v.w;
  __syncthreads();
  unsigned short* o = (unsigned short*)WT;
  ushort4 s4;
  s4.x = f2bu(t[c4 + 0][r]); s4.y = f2bu(t[c4 + 1][r]);
  s4.z = f2bu(t[c4 + 2][r]); s4.w = f2bu(t[c4 + 3][r]);
  *(ushort4*)(o + (size_t)(n0 + r) * K + k0 + c4) = s4;
}

// ---------------------------------------------------------------------------
// MFMA GEMM: C[M,N] = epilogue(A[M,K] @ WT[N,K]^T), bf16 MFMA, fp32 accum.
// ---------------------------------------------------------------------------
template<int EPI, int ASRC>
__global__ __launch_bounds__(256) void k_mgemm(const void* __restrict__ Ap_,
    const bf16* __restrict__ Wt, const float* __restrict__ bias,
    const float* __restrict__ res, void* __restrict__ outp,
    int M, int Nd, int Kd)
{
  __shared__ __align__(16) unsigned short As[128 * 40];
  __shared__ __align__(16) unsigned short Bs[128 * 40];
  int tid = threadIdx.x;
  int bm = blockIdx.x * 128, bn = blockIdx.y * 128;
  int wave = tid >> 6, lane = tid & 63;
  int wr = (wave >> 1) * 64, wc = (wave & 1) * 64;
  int mloc = lane & 15, quad = lane >> 4;

  floatx4 acc[4][4];
#pragma unroll
  for (int i = 0; i < 4; ++i)
#pragma unroll
    for (int j = 0; j < 4; ++j)
      acc[i][j] = (floatx4){0.f, 0.f, 0.f, 0.f};

  const unsigned short* Wu = (const unsigned short*)Wt;
  for (int kt = 0; kt < Kd; kt += 32) {
    __syncthreads();
#pragma unroll
    for (int it = 0; it < 2; ++it) {
      int idx = tid + it * 256;
      int r = idx >> 2, c = idx & 3;
      uint4 pk;
      if (ASRC == 0) {
        const float* A = (const float*)Ap_;
        const float* ap = A + (size_t)(bm + r) * Kd + kt + c * 8;
        float4 f0 = *(const float4*)ap;
        float4 f1 = *(const float4*)(ap + 4);
        pk.x = (unsigned)f2bu(f0.x) | ((unsigned)f2bu(f0.y) << 16);
        pk.y = (unsigned)f2bu(f0.z) | ((unsigned)f2bu(f0.w) << 16);
        pk.z = (unsigned)f2bu(f1.x) | ((unsigned)f2bu(f1.y) << 16);
        pk.w = (unsigned)f2bu(f1.z) | ((unsigned)f2bu(f1.w) << 16);
      } else if (ASRC == 1) {
        const unsigned short* A = (const unsigned short*)Ap_;
        pk = *(const uint4*)(A + (size_t)(bm + r) * Kd + kt + c * 8);
      } else {
        const unsigned short* A = (const unsigned short*)Ap_;
        uint4 rw = *(const uint4*)(A + (size_t)(bm + r) * Kd + kt + c * 8);
        auto cvt2 = [](unsigned u) -> unsigned {
          unsigned short lo16 = (unsigned short)(u & 0xffffu);
          unsigned short hi16 = (unsigned short)(u >> 16);
          return (unsigned)f2bu(h2f(lo16)) | ((unsigned)f2bu(h2f(hi16)) << 16);
        };
        pk.x = cvt2(rw.x); pk.y = cvt2(rw.y); pk.z = cvt2(rw.z); pk.w = cvt2(rw.w);
      }
      *(uint4*)&As[r * 40 + c * 8] = pk;
      uint4 wb = *(const uint4*)(Wu + (size_t)(bn + r) * Kd + kt + c * 8);
      *(uint4*)&Bs[r * 40 + c * 8] = wb;
    }
    __syncthreads();
    short8v af[4], bf[4];
#pragma unroll
    for (int i = 0; i < 4; ++i)
      af[i] = *(const short8v*)&As[(wr + i * 16 + mloc) * 40 + quad * 8];
#pragma unroll
    for (int j = 0; j < 4; ++j)
      bf[j] = *(const short8v*)&Bs[(wc + j * 16 + mloc) * 40 + quad * 8];
#pragma unroll
    for (int i = 0; i < 4; ++i)
#pragma unroll
      for (int j = 0; j < 4; ++j)
        acc[i][j] = __builtin_amdgcn_mfma_f32_16x16x32_bf16(af[i], bf[j], acc[i][j], 0, 0, 0);
  }

  float bv[4] = {0.f, 0.f, 0.f, 0.f};
  if (EPI >= 1) {
#pragma unroll
    for (int j = 0; j < 4; ++j) bv[j] = bias[bn + wc + j * 16 + mloc];
  }
#pragma unroll
  for (int i = 0; i < 4; ++i) {
    int gr0 = bm + wr + i * 16 + quad * 4;
#pragma unroll
    for (int j = 0; j < 4; ++j) {
      int gc = bn + wc + j * 16 + mloc;
#pragma unroll
      for (int reg = 0; reg < 4; ++reg) {
        float v = acc[i][j][reg];
        size_t off = (size_t)(gr0 + reg) * Nd + gc;
        if (EPI == 0) {
          ((unsigned short*)outp)[off] = f2bu(v);
        } else if (EPI == 1) {
          ((float*)outp)[off] = v + bv[j] + res[off];
        } else {
          v += bv[j];
          v = 0.5f * v * (1.0f + erff(v * 0.70710678f));
          ((unsigned short*)outp)[off] = f2bu(v);
        }
      }
    }
  }
}

// ---------------------------------------------------------------------------
// K12: MFMA flash cross-attention with token-score bias.
// K/V interleaved in one buffer, row stride 1536 (K at col h*96, V at 768+h*96)
// ---------------------------------------------------------------------------
__global__ __launch_bounds__(256) void k_attn(const bf16* __restrict__ qb,
    const bf16* __restrict__ kvb, const float* __restrict__ ts,
    float* __restrict__ aout)
{
  __shared__ __align__(16) unsigned short Ks[64 * 104];
  __shared__ __align__(16) unsigned short VsT[96 * 64];
  __shared__ __align__(16) unsigned short sPa[64 * 64];
  __shared__ float tsb[64];
  int h = blockIdx.x, b = blockIdx.y;
  int tid = threadIdx.x;
  int wave = tid >> 6, lane = tid & 63;
  int mloc = lane & 15, quad = lane >> 4;
  const unsigned short* Qu = (const unsigned short*)qb;
  const unsigned short* KVu = (const unsigned short*)kvb;

  short8v qf[3];
  {
    const unsigned short* qrow = Qu + (size_t)(b * 64 + wave * 16 + mloc) * D_ + h * 96 + quad * 8;
#pragma unroll
    for (int k = 0; k < 3; ++k) qf[k] = *(const short8v*)(qrow + k * 32);
  }

  floatx4 of[6];
#pragma unroll
  for (int dt = 0; dt < 6; ++dt) of[dt] = (floatx4){0.f, 0.f, 0.f, 0.f};
  float m[4], l[4];
#pragma unroll
  for (int r = 0; r < 4; ++r) { m[r] = -1e30f; l[r] = 0.f; }

  for (int jt = 0; jt < 9; ++jt) {
    int j0 = jt * 64;
    __syncthreads();
#pragma unroll
    for (int t = 0; t < 3; ++t) {
      int id = tid + t * 256;
      int row = id / 12, c = id % 12;
      *(uint4*)&Ks[row * 104 + c * 8] =
          *(const uint4*)(KVu + (size_t)(b * N_ + j0 + row) * KV_STRIDE_ + h * 96 + c * 8);
    }
#pragma unroll
    for (int t = 0; t < 3; ++t) {
      int id = tid + t * 256;
      int keyp = id & 31, dq = (id >> 5) * 4;
      int key = keyp * 2;
      const unsigned short* vp =
          KVu + (size_t)(b * N_ + j0 + key) * KV_STRIDE_ + 768 + h * 96 + dq;
      ushort4 v0 = *(const ushort4*)vp;
      ushort4 v1 = *(const ushort4*)(vp + KV_STRIDE_);
      unsigned pk0 = (unsigned)v0.x | ((unsigned)v1.x << 16);
      unsigned pk1 = (unsigned)v0.y | ((unsigned)v1.y << 16);
      unsigned pk2 = (unsigned)v0.z | ((unsigned)v1.z << 16);
      unsigned pk3 = (unsigned)v0.w | ((unsigned)v1.w << 16);
      int cbase = key >> 3, off = key & 7;
#pragma unroll
      for (int i = 0; i < 4; ++i) {
        int d = dq + i;
        unsigned pv = (i == 0) ? pk0 : (i == 1) ? pk1 : (i == 2) ? pk2 : pk3;
        *(unsigned*)&VsT[d * 64 + ((cbase ^ (d & 7)) << 3) + off] = pv;
      }
    }
    if (tid < 64) tsb[tid] = ts[b * N_ + j0 + tid];
    __syncthreads();

    floatx4 acc[4];
#pragma unroll
    for (int j = 0; j < 4; ++j) acc[j] = (floatx4){0.f, 0.f, 0.f, 0.f};
#pragma unroll
    for (int j = 0; j < 4; ++j)
#pragma unroll
      for (int k = 0; k < 3; ++k) {
        short8v kf = *(const short8v*)&Ks[(j * 16 + mloc) * 104 + k * 32 + quad * 8];
        acc[j] = __builtin_amdgcn_mfma_f32_16x16x32_bf16(qf[k], kf, acc[j], 0, 0, 0);
      }

    float ts4[4];
#pragma unroll
    for (int j = 0; j < 4; ++j) ts4[j] = tsb[j * 16 + mloc];
    float rm[4] = {-1e30f, -1e30f, -1e30f, -1e30f};
#pragma unroll
    for (int j = 0; j < 4; ++j)
#pragma unroll
      for (int r = 0; r < 4; ++r) {
        acc[j][r] = acc[j][r] * SCALE_ + ts4[j];
        rm[r] = fmaxf(rm[r], acc[j][r]);
      }
#pragma unroll
    for (int r = 0; r < 4; ++r) {
      rm[r] = fmaxf(rm[r], __shfl_xor(rm[r], 1));
      rm[r] = fmaxf(rm[r], __shfl_xor(rm[r], 2));
      rm[r] = fmaxf(rm[r], __shfl_xor(rm[r], 4));
      rm[r] = fmaxf(rm[r], __shfl_xor(rm[r], 8));
    }
    float alpha[4], rs[4];
#pragma unroll
    for (int r = 0; r < 4; ++r) {
      float mn = fmaxf(m[r], rm[r]);
      alpha[r] = __expf(m[r] - mn);
      m[r] = mn;
      rs[r] = 0.f;
    }
#pragma unroll
    for (int j = 0; j < 4; ++j)
#pragma unroll
      for (int r = 0; r < 4; ++r) {
        float p = __expf(acc[j][r] - m[r]);
        acc[j][r] = p; rs[r] += p;
      }
#pragma unroll
    for (int r = 0; r < 4; ++r) {
      rs[r] += __shfl_xor(rs[r], 1); rs[r] += __shfl_xor(rs[r], 2);
      rs[r] += __shfl_xor(rs[r], 4); rs[r] += __shfl_xor(rs[r], 8);
      l[r] = l[r] * alpha[r] + rs[r];
    }
#pragma unroll
    for (int dt = 0; dt < 6; ++dt)
#pragma unroll
      for (int r = 0; r < 4; ++r) of[dt][r] *= alpha[r];

#pragma unroll
    for (int j = 0; j < 4; ++j)
#pragma unroll
      for (int r = 0; r < 4; ++r) {
        int row = wave * 16 + quad * 4 + r;
        int key = j * 16 + mloc;
        sPa[row * 64 + (((key >> 3) ^ (row & 7)) << 3) + (key & 7)] = f2bu(acc[j][r]);
      }
    short8v pa[2];
    int prow = wave * 16 + mloc;
#pragma unroll
    for (int f2 = 0; f2 < 2; ++f2)
      pa[f2] = *(const short8v*)&sPa[prow * 64 + (((f2 * 4 + quad) ^ (prow & 7)) << 3)];
#pragma unroll
    for (int dt = 0; dt < 6; ++dt)
#pragma unroll
      for (int f2 = 0; f2 < 2; ++f2) {
        int vrow = dt * 16 + mloc;
        short8v vf = *(const short8v*)&VsT[vrow * 64 + (((f2 * 4 + quad) ^ (vrow & 7)) << 3)];
        of[dt] = __builtin_amdgcn_mfma_f32_16x16x32_bf16(pa[f2], vf, of[dt], 0, 0, 0);
      }
  }

  float linv[4];
#pragma unroll
  for (int r = 0; r < 4; ++r) linv[r] = 1.0f / l[r];
#pragma unroll
  for (int dt = 0; dt < 6; ++dt)
#pragma unroll
    for (int r = 0; r < 4; ++r) {
      int row = b * 64 + wave * 16 + quad * 4 + r;
      int col = h * 96 + dt * 16 + mloc;
      aout[(size_t)row * D_ + col] = of[dt][r] * linv[r];
    }
}

// ---------------------------------------------------------------------------
// K14: LayerNorm2 (fp32 in -> fp32 out)
// ---------------------------------------------------------------------------
__global__ __launch_bounds__(256) void k_ln2(const float* __restrict__ f,
    const float* __restrict__ g, const float* __restrict__ bt, float* __restrict__ out)
{
  int row = blockIdx.x, tid = threadIdx.x;
  const float* fr = f + (size_t)row * D_;
  float v0 = fr[tid], v1 = fr[tid + 256], v2 = fr[tid + 512];
  __shared__ float r1[256], r2[256];
  r1[tid] = v0 + v1 + v2;
  r2[tid] = v0 * v0 + v1 * v1 + v2 * v2;
  __syncthreads();
  for (int o = 128; o > 0; o >>= 1) {
    if (tid < o) { r1[tid] += r1[tid + o]; r2[tid] += r2[tid + o]; }
    __syncthreads();
  }
  float mean = r1[0] * (1.0f / D_);
  float var  = r2[0] * (1.0f / D_) - mean * mean;
  float rstd = rsqrtf(var + 1e-5f);
  float* oo = out + (size_t)row * D_;
  oo[tid      ] = (v0 - mean) * rstd * g[tid      ] + bt[tid      ];
  oo[tid + 256] = (v1 - mean) * rstd * g[tid + 256] + bt[tid + 256];
  oo[tid + 512] = (v2 - mean) * rstd * g[tid + 512] + bt[tid + 512];
}

// ---------------------------------------------------------------------------
// Launch
// ---------------------------------------------------------------------------
extern "C" void kernel_launch(void* const* d_in, const int* in_sizes, int n_in,
                              void* d_out, int out_size, void* d_ws, size_t ws_size,
                              hipStream_t stream)
{
  (void)in_sizes; (void)n_in; (void)out_size; (void)ws_size;
  const float* x    = (const float*)d_in[0];
  const float* nois = (const float*)d_in[1];
  const float* n1g  = (const float*)d_in[2];
  const float* n1b  = (const float*)d_in[3];
  const float* sw   = (const float*)d_in[4];
  const float* sb   = (const float*)d_in[5];
  const float* wq   = (const float*)d_in[6];
  const float* wk   = (const float*)d_in[7];
  const float* wv   = (const float*)d_in[8];
  const float* pw   = (const float*)d_in[9];
  const float* pb   = (const float*)d_in[10];
  const float* n2g  = (const float*)d_in[11];
  const float* n2b  = (const float*)d_in[12];
  const float* f1w  = (const float*)d_in[13];
  const float* f1b  = (const float*)d_in[14];
  const float* f2w  = (const float*)d_in[15];
  const float* f2b  = (const float*)d_in[16];

  float* ws    = (float*)d_ws;
  unsigned short* XH = (unsigned short*)ws;                 // fp16 hi plane
  unsigned short* XL = XH + (size_t)NB_ * D_;               // fp16 lo plane
  float* RG    = ws + (size_t)NB_ * D_;
  float* QIN   = RG + (size_t)NB_ * D_;
  float* FEAT  = QIN + (size_t)ML_ * D_;
  float* AOUT  = FEAT + (size_t)ML_ * D_;
  float* QBUF  = AOUT + (size_t)ML_ * D_;
  float* P     = QBUF + (size_t)ML_ * D_;
  bf16*  QB16  = (bf16*)P;             P += (size_t)ML_ * D_ / 2;
  bf16*  WTQ   = (bf16*)P;             P += (size_t)D_ * D_ / 2;
  bf16*  WTKV  = (bf16*)P;             P += (size_t)D_ * D_;     // K rows then V rows
  bf16*  WTP   = (bf16*)P;             P += (size_t)D_ * D_ / 2;
  bf16*  WT1   = (bf16*)P;             P += (size_t)D_ * 4 * D_ / 2;
  bf16*  WT2   = (bf16*)P;             P += (size_t)D_ * 4 * D_ / 2;
  float* TS    = P;
  float* SQ    = TS + NB_;
  float* DEN   = SQ + NB_;
  float* SCORE = DEN + NB_;
  float* DMAX  = SCORE + NB_;
  int*   IDXD  = (int*)(DMAX + 64);
  int*   IDXC  = IDXD + ML_;
  float* DM    = RG;                      // phase 1
  bf16*  KVB   = (bf16*)RG;               // phase 2: [NB_][1536] interleaved K|V
  bf16*  HID   = (bf16*)RG;               // phase 3

  hipMemsetAsync(DMAX, 0, 64 * sizeof(float), stream);
  k_wt<<<dim3(24, 24), 256, 0, stream>>>(wq, WTQ, D_, D_);
  k_wt<<<dim3(24, 24), 256, 0, stream>>>(wk, WTKV, D_, D_);
  k_wt<<<dim3(24, 24), 256, 0, stream>>>(wv, WTKV + (size_t)D_ * D_, D_, D_);
  k_wt<<<dim3(24, 24), 256, 0, stream>>>(pw, WTP, D_, D_);
  k_wt<<<dim3(24, 96), 256, 0, stream>>>(f1w, WT1, D_, 4 * D_);
  k_wt<<<dim3(96, 24), 256, 0, stream>>>(f2w, WT2, 4 * D_, D_);

  k_ln1<<<NB_, 256, 0, stream>>>(x, n1g, n1b, sw, sb, XH, XL, TS, SQ);
  k_dmg<<<1344, 256, 0, stream>>>(XH, XL, SQ, DM, DMAX);
  k_density<<<NB_, 64, 0, stream>>>(DM, nois, DEN);
  k_dist<<<NB_, 64, 0, stream>>>(DM, DEN, DMAX, SCORE);
  k_topL<<<B_, 256, 0, stream>>>(SCORE, IDXD);
  k_assign<<<B_, 576, 0, stream>>>(DM, IDXD, IDXC);
  k_merge<<<ML_, 256, 0, stream>>>(XH, XL, TS, IDXC, QIN);

  k_mgemm<0, 0><<<dim3(ML_ / 128, D_ / 128), 256, 0, stream>>>(
      QIN, WTQ, nullptr, nullptr, QB16, ML_, D_, D_);
  k_mgemm<0, 2><<<dim3(NB_ / 128, KV_STRIDE_ / 128), 256, 0, stream>>>(
      XH, WTKV, nullptr, nullptr, KVB, NB_, KV_STRIDE_, D_);
  k_attn<<<dim3(H_, B_), 256, 0, stream>>>(QB16, KVB, TS, AOUT);
  k_mgemm<1, 0><<<dim3(ML_ / 128, D_ / 128), 256, 0, stream>>>(
      AOUT, WTP, pb, QIN, FEAT, ML_, D_, D_);
  k_ln2<<<ML_, 256, 0, stream>>>(FEAT, n2g, n2b, QBUF);
  k_mgemm<2, 0><<<dim3(ML_ / 128, (4 * D_) / 128), 256, 0, stream>>>(
      QBUF, WT1, f1b, nullptr, HID, ML_, 4 * D_, D_);
  k_mgemm<1, 1><<<dim3(ML_ / 128, D_ / 128), 256, 0, stream>>>(
      HID, WT2, f2b, FEAT, d_out, ML_, D_, 4 * D_);
}

// Round 5
// 1020.732 us; speedup vs baseline: 1.1578x; 1.1578x over previous
//
#include <hip/hip_runtime.h>
#include <math.h>

// Problem constants
#define B_   64
#define N_   576
#define D_   768
#define L_   64
#define H_   8
#define HD_  96
#define NB_  (B_*N_)    // 36864 rows
#define ML_  (B_*L_)    // 4096 rows
#define KV_STRIDE_ 1536
#define SCALE_ 0.10206207f          // 96^-0.5
#define INV_SQRT_D_ 0.03608439182f  // 1/sqrt(768)
#define LO_SCALE_ 4.8828125e-4f     // 2^-11

typedef __attribute__((ext_vector_type(8))) _Float16 half8v;    // 8 fp16 (4 VGPRs)
typedef __attribute__((ext_vector_type(4))) float floatx4;      // MFMA C/D

__device__ __forceinline__ unsigned short f2h(float f) {
  _Float16 h = (_Float16)f;
  unsigned short u; __builtin_memcpy(&u, &h, 2);
  return u;
}
__device__ __forceinline__ float h2f(unsigned short u) {
  _Float16 h; __builtin_memcpy(&h, &u, 2);
  return (float)h;
}

// ---------------------------------------------------------------------------
// K1: LayerNorm1 -> fp16 hi/lo split planes + token_score + row sum-of-squares
// ---------------------------------------------------------------------------
__global__ __launch_bounds__(256) void k_ln1(const float* __restrict__ x,
    const float* __restrict__ g, const float* __restrict__ bt,
    const float* __restrict__ sw, const float* __restrict__ sb,
    unsigned short* __restrict__ xh, unsigned short* __restrict__ xl,
    float* __restrict__ ts, float* __restrict__ sq)
{
  int row = blockIdx.x, tid = threadIdx.x;
  const float* xr = x + (size_t)row * D_;
  float v0 = xr[tid], v1 = xr[tid + 256], v2 = xr[tid + 512];
  __shared__ float r1[256], r2[256];
  r1[tid] = v0 + v1 + v2;
  r2[tid] = v0 * v0 + v1 * v1 + v2 * v2;
  __syncthreads();
  for (int o = 128; o > 0; o >>= 1) {
    if (tid < o) { r1[tid] += r1[tid + o]; r2[tid] += r2[tid + o]; }
    __syncthreads();
  }
  float mean = r1[0] * (1.0f / D_);
  float var  = r2[0] * (1.0f / D_) - mean * mean;
  float rstd = rsqrtf(var + 1e-5f);
  __syncthreads();
  float o0 = (v0 - mean) * rstd * g[tid      ] + bt[tid      ];
  float o1 = (v1 - mean) * rstd * g[tid + 256] + bt[tid + 256];
  float o2 = (v2 - mean) * rstd * g[tid + 512] + bt[tid + 512];
  auto split = [](float o, unsigned short& hu, unsigned short& lu) {
    _Float16 h = (_Float16)o;
    float hf = (float)h;
    _Float16 l = (_Float16)((o - hf) * 2048.0f);
    __builtin_memcpy(&hu, &h, 2);
    __builtin_memcpy(&lu, &l, 2);
  };
  unsigned short h0, l0, h1, l1, h2, l2;
  split(o0, h0, l0); split(o1, h1, l1); split(o2, h2, l2);
  unsigned short* xho = xh + (size_t)row * D_;
  unsigned short* xlo = xl + (size_t)row * D_;
  xho[tid] = h0; xho[tid + 256] = h1; xho[tid + 512] = h2;
  xlo[tid] = l0; xlo[tid + 256] = l1; xlo[tid + 512] = l2;
  r1[tid] = o0 * sw[tid] + o1 * sw[tid + 256] + o2 * sw[tid + 512];
  r2[tid] = o0 * o0 + o1 * o1 + o2 * o2;
  __syncthreads();
  for (int o = 128; o > 0; o >>= 1) {
    if (tid < o) { r1[tid] += r1[tid + o]; r2[tid] += r2[tid + o]; }
    __syncthreads();
  }
  if (tid == 0) { ts[row] = r1[0] + sb[0]; sq[row] = r2[0]; }
}

// ---------------------------------------------------------------------------
// K2: pairwise distance matrix via fp16x2 split-precision MFMA Gram.
// REVERTED to the measured-best r2 structure (159us): single LDS stage,
// 2 barriers per K-step, grid (21,B). Fused per-batch max via atomicMax.
// ---------------------------------------------------------------------------
__global__ __launch_bounds__(256) void k_dmg(const unsigned short* __restrict__ xh,
    const unsigned short* __restrict__ xl, const float* __restrict__ sq,
    float* __restrict__ dm, float* __restrict__ dmax)
{
  __shared__ __align__(16) unsigned short Ah[96 * 40], Al[96 * 40];
  __shared__ __align__(16) unsigned short Bh[96 * 40], Bl[96 * 40];
  int b = blockIdx.y;
  int t = blockIdx.x, ti = 0, rl = 6;
  while (t >= rl) { t -= rl; ++ti; --rl; }
  int tj = ti + t;
  int tid = threadIdx.x;
  int wave = tid >> 6, lane = tid & 63;
  int wr = (wave >> 1) * 48, wc = (wave & 1) * 48;
  int mloc = lane & 15, quad = lane >> 4;
  size_t rowA = (size_t)b * N_ + ti * 96;
  size_t rowB = (size_t)b * N_ + tj * 96;

  floatx4 a1[3][3], a2[3][3];
#pragma unroll
  for (int i = 0; i < 3; ++i)
#pragma unroll
    for (int j = 0; j < 3; ++j) {
      a1[i][j] = (floatx4){0.f, 0.f, 0.f, 0.f};
      a2[i][j] = (floatx4){0.f, 0.f, 0.f, 0.f};
    }

  int r0 = tid >> 2, c0 = tid & 3;
  for (int kt = 0; kt < D_; kt += 32) {
    __syncthreads();
    {
      *(uint4*)&Ah[r0 * 40 + c0 * 8] = *(const uint4*)(xh + (rowA + r0) * D_ + kt + c0 * 8);
      *(uint4*)&Al[r0 * 40 + c0 * 8] = *(const uint4*)(xl + (rowA + r0) * D_ + kt + c0 * 8);
      *(uint4*)&Bh[r0 * 40 + c0 * 8] = *(const uint4*)(xh + (rowB + r0) * D_ + kt + c0 * 8);
      *(uint4*)&Bl[r0 * 40 + c0 * 8] = *(const uint4*)(xl + (rowB + r0) * D_ + kt + c0 * 8);
      if (tid < 128) {
        int r2 = 64 + r0;
        *(uint4*)&Ah[r2 * 40 + c0 * 8] = *(const uint4*)(xh + (rowA + r2) * D_ + kt + c0 * 8);
        *(uint4*)&Al[r2 * 40 + c0 * 8] = *(const uint4*)(xl + (rowA + r2) * D_ + kt + c0 * 8);
        *(uint4*)&Bh[r2 * 40 + c0 * 8] = *(const uint4*)(xh + (rowB + r2) * D_ + kt + c0 * 8);
        *(uint4*)&Bl[r2 * 40 + c0 * 8] = *(const uint4*)(xl + (rowB + r2) * D_ + kt + c0 * 8);
      }
    }
    __syncthreads();
    half8v ah[3], al[3], bh[3], bl[3];
#pragma unroll
    for (int i = 0; i < 3; ++i) {
      ah[i] = *(const half8v*)&Ah[(wr + i * 16 + mloc) * 40 + quad * 8];
      al[i] = *(const half8v*)&Al[(wr + i * 16 + mloc) * 40 + quad * 8];
    }
#pragma unroll
    for (int j = 0; j < 3; ++j) {
      bh[j] = *(const half8v*)&Bh[(wc + j * 16 + mloc) * 40 + quad * 8];
      bl[j] = *(const half8v*)&Bl[(wc + j * 16 + mloc) * 40 + quad * 8];
    }
#pragma unroll
    for (int i = 0; i < 3; ++i)
#pragma unroll
      for (int j = 0; j < 3; ++j) {
        a1[i][j] = __builtin_amdgcn_mfma_f32_16x16x32_f16(ah[i], bh[j], a1[i][j], 0, 0, 0);
        a2[i][j] = __builtin_amdgcn_mfma_f32_16x16x32_f16(ah[i], bl[j], a2[i][j], 0, 0, 0);
        a2[i][j] = __builtin_amdgcn_mfma_f32_16x16x32_f16(al[i], bh[j], a2[i][j], 0, 0, 0);
      }
  }

  const float* sqb = sq + b * N_;
  float* dmb = dm + (size_t)b * N_ * N_;
  bool diag = (ti == tj);
  float vmax = 0.f;
#pragma unroll
  for (int j = 0; j < 3; ++j) {
    int gj = tj * 96 + wc + j * 16 + mloc;
    float sj = sqb[gj];
#pragma unroll
    for (int i = 0; i < 3; ++i) {
      int gi0 = ti * 96 + wr + i * 16 + quad * 4;
#pragma unroll
      for (int reg = 0; reg < 4; ++reg) {
        int gi = gi0 + reg;
        float g = a1[i][j][reg] + a2[i][j][reg] * LO_SCALE_;
        float d = sqb[gi] + sj - 2.0f * g;
        float v = sqrtf(fmaxf(d, 0.0f)) * INV_SQRT_D_;
        vmax = fmaxf(vmax, v);
        if (!diag || gj >= gi) {
          dmb[(size_t)gi * N_ + gj] = v;
          dmb[(size_t)gj * N_ + gi] = v;
        }
      }
    }
  }
#pragma unroll
  for (int msk = 32; msk >= 1; msk >>= 1) vmax = fmaxf(vmax, __shfl_xor(vmax, msk));
  if (lane == 0) atomicMax((unsigned int*)(dmax + b), __float_as_uint(vmax));
}

// ---------------------------------------------------------------------------
// K3: kNN density
// ---------------------------------------------------------------------------
__global__ __launch_bounds__(64) void k_density(const float* __restrict__ dm,
    const float* __restrict__ noise, float* __restrict__ den)
{
  int row = blockIdx.x, lane = threadIdx.x;
  const float* r = dm + (size_t)row * N_;
  float a0 = 1e30f, a1 = 1e30f, a2 = 1e30f, a3 = 1e30f, a4 = 1e30f;
  auto ins5 = [&](float xv) {
    a4 = fminf(a4, xv);
    float t;
    t = fminf(a3, a4); a4 = fmaxf(a3, a4); a3 = t;
    t = fminf(a2, a3); a3 = fmaxf(a2, a3); a2 = t;
    t = fminf(a1, a2); a2 = fmaxf(a1, a2); a1 = t;
    t = fminf(a0, a1); a1 = fmaxf(a0, a1); a0 = t;
  };
#pragma unroll
  for (int t = 0; t < 9; ++t) ins5(r[lane + 64 * t]);
  for (int m = 1; m < 64; m <<= 1) {
    float b0 = __shfl_xor(a0, m), b1 = __shfl_xor(a1, m), b2 = __shfl_xor(a2, m);
    float b3 = __shfl_xor(a3, m), b4 = __shfl_xor(a4, m);
    ins5(b0); ins5(b1); ins5(b2); ins5(b3); ins5(b4);
  }
  if (lane == 0) {
    float ms = (a0 * a0 + a1 * a1 + a2 * a2 + a3 * a3 + a4 * a4) * 0.2f;
    den[row] = expf(-ms) + noise[row] * 1e-6f;
  }
}

// ---------------------------------------------------------------------------
// K5: dist-to-higher-density + score
// ---------------------------------------------------------------------------
__global__ __launch_bounds__(64) void k_dist(const float* __restrict__ dm,
    const float* __restrict__ den, const float* __restrict__ dmax,
    float* __restrict__ score)
{
  int row = blockIdx.x, lane = threadIdx.x;
  int b = row / N_;
  float di = den[row], dx = dmax[b];
  const float* r = dm + (size_t)row * N_;
  const float* db = den + b * N_;
  float m = dx;
#pragma unroll
  for (int t = 0; t < 9; ++t) {
    int j = lane + 64 * t;
    float v = (db[j] > di) ? r[j] : dx;
    m = fminf(m, v);
  }
  for (int msk = 1; msk < 64; msk <<= 1) m = fminf(m, __shfl_xor(m, msk));
  if (lane == 0) score[row] = m * di;
}

// ---------------------------------------------------------------------------
// K6: top-64 scores per batch
// ---------------------------------------------------------------------------
__global__ __launch_bounds__(256) void k_topL(const float* __restrict__ score,
    int* __restrict__ idxd)
{
  int b = blockIdx.x, tid = threadIdx.x;
  __shared__ float s[N_];
  __shared__ float rv[256];
  __shared__ int   ri[256];
  for (int j = tid; j < N_; j += 256) s[j] = score[b * N_ + j];
  __syncthreads();
  for (int it = 0; it < L_; ++it) {
    float bv = -1e30f; int bi = 1 << 30;
    for (int j = tid; j < N_; j += 256) {
      float v = s[j];
      if (v > bv || (v == bv && j < bi)) { bv = v; bi = j; }
    }
    rv[tid] = bv; ri[tid] = bi; __syncthreads();
    for (int o = 128; o > 0; o >>= 1) {
      if (tid < o) {
        float v2 = rv[tid + o]; int i2 = ri[tid + o];
        if (v2 > rv[tid] || (v2 == rv[tid] && i2 < ri[tid])) { rv[tid] = v2; ri[tid] = i2; }
      }
      __syncthreads();
    }
    if (tid == 0) { idxd[b * L_ + it] = ri[0]; s[ri[0]] = -1e30f; }
    __syncthreads();
  }
}

// ---------------------------------------------------------------------------
// K7: assign tokens to nearest center (+ fused center self-assignment)
// ---------------------------------------------------------------------------
__global__ __launch_bounds__(576) void k_assign(const float* __restrict__ dm,
    const int* __restrict__ idxd, int* __restrict__ idxc)
{
  int b = blockIdx.x, n = threadIdx.x;
  __shared__ int ctr[L_];
  if (n < L_) ctr[n] = idxd[b * L_ + n];
  __syncthreads();
  const float* dmb = dm + (size_t)b * N_ * N_;
  float best = 1e30f; int bl = 0;
  for (int l = 0; l < L_; ++l) {
    float v = dmb[(size_t)ctr[l] * N_ + n];
    if (v < best) { best = v; bl = l; }
  }
  for (int l = 0; l < L_; ++l)
    if (ctr[l] == n) bl = l;
  idxc[b * N_ + n] = bl;
}

// ---------------------------------------------------------------------------
// K8: merger (gather form) — reconstructs xn = hi + lo*2^-11
// ---------------------------------------------------------------------------
__global__ __launch_bounds__(256) void k_merge(const unsigned short* __restrict__ xh,
    const unsigned short* __restrict__ xl,
    const float* __restrict__ ts, const int* __restrict__ idxc,
    float* __restrict__ qin)
{
  int blk = blockIdx.x;
  int b = blk >> 6, l = blk & 63;
  int tid = threadIdx.x;
  const int* ic = idxc + b * N_;
  const float* tsb = ts + b * N_;
  const unsigned short* xhb = xh + (size_t)b * N_ * D_;
  const unsigned short* xlb = xl + (size_t)b * N_ * D_;
  float a0 = 0.f, a1 = 0.f, a2 = 0.f, wsum = 0.f;
  for (int n = 0; n < N_; ++n) {
    if (ic[n] == l) {
      float w = expf(tsb[n]);
      wsum += w;
      const unsigned short* hr = xhb + (size_t)n * D_;
      const unsigned short* lr = xlb + (size_t)n * D_;
      float x0 = h2f(hr[tid      ]) + h2f(lr[tid      ]) * LO_SCALE_;
      float x1 = h2f(hr[tid + 256]) + h2f(lr[tid + 256]) * LO_SCALE_;
      float x2 = h2f(hr[tid + 512]) + h2f(lr[tid + 512]) * LO_SCALE_;
      a0 += w * x0; a1 += w * x1; a2 += w * x2;
    }
  }
  float inv = 1.0f / (wsum + 1e-6f);
  float* q = qin + (size_t)blk * D_;
  q[tid] = a0 * inv; q[tid + 256] = a1 * inv; q[tid + 512] = a2 * inv;
}

// ---------------------------------------------------------------------------
// Weight transpose + fp16 cast: W[K,N] fp32 -> WT[N,K] fp16
// ---------------------------------------------------------------------------
__global__ __launch_bounds__(256) void k_wt(const float* __restrict__ W,
    unsigned short* __restrict__ WT, int K, int N)
{
  __shared__ float t[32][33];
  int k0 = blockIdx.x * 32, n0 = blockIdx.y * 32;
  int tid = threadIdx.x;
  int r = tid >> 3, c4 = (tid & 7) * 4;
  float4 v = *(const float4*)(W + (size_t)(k0 + r) * N + n0 + c4);
  t[r][c4] = v.x; t[r][c4 + 1] = v.y; t[r][c4 + 2] = v.z; t[r][c4 + 3] = v.w;
  __syncthreads();
  ushort4 s4;
  s4.x = f2h(t[c4 + 0][r]); s4.y = f2h(t[c4 + 1][r]);
  s4.z = f2h(t[c4 + 2][r]); s4.w = f2h(t[c4 + 3][r]);
  *(ushort4*)(WT + (size_t)(n0 + r) * K + k0 + c4) = s4;
}

// ---------------------------------------------------------------------------
// MFMA GEMM: C[M,N] = epilogue(A[M,K] @ WT[N,K]^T), fp16 MFMA, fp32 accum.
// ASRC 0: A fp32 (cvt fp16 in staging, 1 op/elem)   1: A fp16 (pure copy)
// EPI  0: fp16 out  1: +bias +res -> fp32 out  2: +bias, exact GELU -> fp16
// ---------------------------------------------------------------------------
template<int EPI, int ASRC>
__global__ __launch_bounds__(256) void k_mgemm(const void* __restrict__ Ap_,
    const unsigned short* __restrict__ Wt, const float* __restrict__ bias,
    const float* __restrict__ res, void* __restrict__ outp,
    int M, int Nd, int Kd)
{
  __shared__ __align__(16) unsigned short As[128 * 40];
  __shared__ __align__(16) unsigned short Bs[128 * 40];
  int tid = threadIdx.x;
  int bm = blockIdx.x * 128, bn = blockIdx.y * 128;
  int wave = tid >> 6, lane = tid & 63;
  int wr = (wave >> 1) * 64, wc = (wave & 1) * 64;
  int mloc = lane & 15, quad = lane >> 4;

  floatx4 acc[4][4];
#pragma unroll
  for (int i = 0; i < 4; ++i)
#pragma unroll
    for (int j = 0; j < 4; ++j)
      acc[i][j] = (floatx4){0.f, 0.f, 0.f, 0.f};

  for (int kt = 0; kt < Kd; kt += 32) {
    __syncthreads();
#pragma unroll
    for (int it = 0; it < 2; ++it) {
      int idx = tid + it * 256;
      int r = idx >> 2, c = idx & 3;
      uint4 pk;
      if (ASRC == 0) {
        const float* A = (const float*)Ap_;
        const float* ap = A + (size_t)(bm + r) * Kd + kt + c * 8;
        float4 f0 = *(const float4*)ap;
        float4 f1 = *(const float4*)(ap + 4);
        pk.x = (unsigned)f2h(f0.x) | ((unsigned)f2h(f0.y) << 16);
        pk.y = (unsigned)f2h(f0.z) | ((unsigned)f2h(f0.w) << 16);
        pk.z = (unsigned)f2h(f1.x) | ((unsigned)f2h(f1.y) << 16);
        pk.w = (unsigned)f2h(f1.z) | ((unsigned)f2h(f1.w) << 16);
      } else {
        const unsigned short* A = (const unsigned short*)Ap_;
        pk = *(const uint4*)(A + (size_t)(bm + r) * Kd + kt + c * 8);
      }
      *(uint4*)&As[r * 40 + c * 8] = pk;
      uint4 wb = *(const uint4*)(Wt + (size_t)(bn + r) * Kd + kt + c * 8);
      *(uint4*)&Bs[r * 40 + c * 8] = wb;
    }
    __syncthreads();
    half8v af[4], bf[4];
#pragma unroll
    for (int i = 0; i < 4; ++i)
      af[i] = *(const half8v*)&As[(wr + i * 16 + mloc) * 40 + quad * 8];
#pragma unroll
    for (int j = 0; j < 4; ++j)
      bf[j] = *(const half8v*)&Bs[(wc + j * 16 + mloc) * 40 + quad * 8];
#pragma unroll
    for (int i = 0; i < 4; ++i)
#pragma unroll
      for (int j = 0; j < 4; ++j)
        acc[i][j] = __builtin_amdgcn_mfma_f32_16x16x32_f16(af[i], bf[j], acc[i][j], 0, 0, 0);
  }

  float bv[4] = {0.f, 0.f, 0.f, 0.f};
  if (EPI >= 1) {
#pragma unroll
    for (int j = 0; j < 4; ++j) bv[j] = bias[bn + wc + j * 16 + mloc];
  }
#pragma unroll
  for (int i = 0; i < 4; ++i) {
    int gr0 = bm + wr + i * 16 + quad * 4;
#pragma unroll
    for (int j = 0; j < 4; ++j) {
      int gc = bn + wc + j * 16 + mloc;
#pragma unroll
      for (int reg = 0; reg < 4; ++reg) {
        float v = acc[i][j][reg];
        size_t off = (size_t)(gr0 + reg) * Nd + gc;
        if (EPI == 0) {
          ((unsigned short*)outp)[off] = f2h(v);
        } else if (EPI == 1) {
          ((float*)outp)[off] = v + bv[j] + res[off];
        } else {
          v += bv[j];
          v = 0.5f * v * (1.0f + erff(v * 0.70710678f));
          ((unsigned short*)outp)[off] = f2h(v);
        }
      }
    }
  }
}

// ---------------------------------------------------------------------------
// K12: MFMA flash cross-attention with token-score bias (all fp16 operands).
// K/V interleaved in one buffer, row stride 1536 (K at col h*96, V at 768+h*96)
// ---------------------------------------------------------------------------
__global__ __launch_bounds__(256) void k_attn(const unsigned short* __restrict__ Qu,
    const unsigned short* __restrict__ KVu, const float* __restrict__ ts,
    float* __restrict__ aout)
{
  __shared__ __align__(16) unsigned short Ks[64 * 104];
  __shared__ __align__(16) unsigned short VsT[96 * 64];
  __shared__ __align__(16) unsigned short sPa[64 * 64];
  __shared__ float tsb[64];
  int h = blockIdx.x, b = blockIdx.y;
  int tid = threadIdx.x;
  int wave = tid >> 6, lane = tid & 63;
  int mloc = lane & 15, quad = lane >> 4;

  half8v qf[3];
  {
    const unsigned short* qrow = Qu + (size_t)(b * 64 + wave * 16 + mloc) * D_ + h * 96 + quad * 8;
#pragma unroll
    for (int k = 0; k < 3; ++k) qf[k] = *(const half8v*)(qrow + k * 32);
  }

  floatx4 of[6];
#pragma unroll
  for (int dt = 0; dt < 6; ++dt) of[dt] = (floatx4){0.f, 0.f, 0.f, 0.f};
  float m[4], l[4];
#pragma unroll
  for (int r = 0; r < 4; ++r) { m[r] = -1e30f; l[r] = 0.f; }

  for (int jt = 0; jt < 9; ++jt) {
    int j0 = jt * 64;
    __syncthreads();
#pragma unroll
    for (int t = 0; t < 3; ++t) {
      int id = tid + t * 256;
      int row = id / 12, c = id % 12;
      *(uint4*)&Ks[row * 104 + c * 8] =
          *(const uint4*)(KVu + (size_t)(b * N_ + j0 + row) * KV_STRIDE_ + h * 96 + c * 8);
    }
#pragma unroll
    for (int t = 0; t < 3; ++t) {
      int id = tid + t * 256;
      int keyp = id & 31, dq = (id >> 5) * 4;
      int key = keyp * 2;
      const unsigned short* vp =
          KVu + (size_t)(b * N_ + j0 + key) * KV_STRIDE_ + 768 + h * 96 + dq;
      ushort4 v0 = *(const ushort4*)vp;
      ushort4 v1 = *(const ushort4*)(vp + KV_STRIDE_);
      unsigned pk0 = (unsigned)v0.x | ((unsigned)v1.x << 16);
      unsigned pk1 = (unsigned)v0.y | ((unsigned)v1.y << 16);
      unsigned pk2 = (unsigned)v0.z | ((unsigned)v1.z << 16);
      unsigned pk3 = (unsigned)v0.w | ((unsigned)v1.w << 16);
      int cbase = key >> 3, off = key & 7;
#pragma unroll
      for (int i = 0; i < 4; ++i) {
        int d = dq + i;
        unsigned pv = (i == 0) ? pk0 : (i == 1) ? pk1 : (i == 2) ? pk2 : pk3;
        *(unsigned*)&VsT[d * 64 + ((cbase ^ (d & 7)) << 3) + off] = pv;
      }
    }
    if (tid < 64) tsb[tid] = ts[b * N_ + j0 + tid];
    __syncthreads();

    floatx4 acc[4];
#pragma unroll
    for (int j = 0; j < 4; ++j) acc[j] = (floatx4){0.f, 0.f, 0.f, 0.f};
#pragma unroll
    for (int j = 0; j < 4; ++j)
#pragma unroll
      for (int k = 0; k < 3; ++k) {
        half8v kf = *(const half8v*)&Ks[(j * 16 + mloc) * 104 + k * 32 + quad * 8];
        acc[j] = __builtin_amdgcn_mfma_f32_16x16x32_f16(qf[k], kf, acc[j], 0, 0, 0);
      }

    float ts4[4];
#pragma unroll
    for (int j = 0; j < 4; ++j) ts4[j] = tsb[j * 16 + mloc];
    float rm[4] = {-1e30f, -1e30f, -1e30f, -1e30f};
#pragma unroll
    for (int j = 0; j < 4; ++j)
#pragma unroll
      for (int r = 0; r < 4; ++r) {
        acc[j][r] = acc[j][r] * SCALE_ + ts4[j];
        rm[r] = fmaxf(rm[r], acc[j][r]);
      }
#pragma unroll
    for (int r = 0; r < 4; ++r) {
      rm[r] = fmaxf(rm[r], __shfl_xor(rm[r], 1));
      rm[r] = fmaxf(rm[r], __shfl_xor(rm[r], 2));
      rm[r] = fmaxf(rm[r], __shfl_xor(rm[r], 4));
      rm[r] = fmaxf(rm[r], __shfl_xor(rm[r], 8));
    }
    float alpha[4], rs[4];
#pragma unroll
    for (int r = 0; r < 4; ++r) {
      float mn = fmaxf(m[r], rm[r]);
      alpha[r] = __expf(m[r] - mn);
      m[r] = mn;
      rs[r] = 0.f;
    }
#pragma unroll
    for (int j = 0; j < 4; ++j)
#pragma unroll
      for (int r = 0; r < 4; ++r) {
        float p = __expf(acc[j][r] - m[r]);
        acc[j][r] = p; rs[r] += p;
      }
#pragma unroll
    for (int r = 0; r < 4; ++r) {
      rs[r] += __shfl_xor(rs[r], 1); rs[r] += __shfl_xor(rs[r], 2);
      rs[r] += __shfl_xor(rs[r], 4); rs[r] += __shfl_xor(rs[r], 8);
      l[r] = l[r] * alpha[r] + rs[r];
    }
#pragma unroll
    for (int dt = 0; dt < 6; ++dt)
#pragma unroll
      for (int r = 0; r < 4; ++r) of[dt][r] *= alpha[r];

#pragma unroll
    for (int j = 0; j < 4; ++j)
#pragma unroll
      for (int r = 0; r < 4; ++r) {
        int row = wave * 16 + quad * 4 + r;
        int key = j * 16 + mloc;
        sPa[row * 64 + (((key >> 3) ^ (row & 7)) << 3) + (key & 7)] = f2h(acc[j][r]);
      }
    half8v pa[2];
    int prow = wave * 16 + mloc;
#pragma unroll
    for (int f2 = 0; f2 < 2; ++f2)
      pa[f2] = *(const half8v*)&sPa[prow * 64 + (((f2 * 4 + quad) ^ (prow & 7)) << 3)];
#pragma unroll
    for (int dt = 0; dt < 6; ++dt)
#pragma unroll
      for (int f2 = 0; f2 < 2; ++f2) {
        int vrow = dt * 16 + mloc;
        half8v vf = *(const half8v*)&VsT[vrow * 64 + (((f2 * 4 + quad) ^ (vrow & 7)) << 3)];
        of[dt] = __builtin_amdgcn_mfma_f32_16x16x32_f16(pa[f2], vf, of[dt], 0, 0, 0);
      }
  }

  float linv[4];
#pragma unroll
  for (int r = 0; r < 4; ++r) linv[r] = 1.0f / l[r];
#pragma unroll
  for (int dt = 0; dt < 6; ++dt)
#pragma unroll
    for (int r = 0; r < 4; ++r) {
      int row = b * 64 + wave * 16 + quad * 4 + r;
      int col = h * 96 + dt * 16 + mloc;
      aout[(size_t)row * D_ + col] = of[dt][r] * linv[r];
    }
}

// ---------------------------------------------------------------------------
// K14: LayerNorm2 (fp32 in -> fp32 out)
// ---------------------------------------------------------------------------
__global__ __launch_bounds__(256) void k_ln2(const float* __restrict__ f,
    const float* __restrict__ g, const float* __restrict__ bt, float* __restrict__ out)
{
  int row = blockIdx.x, tid = threadIdx.x;
  const float* fr = f + (size_t)row * D_;
  float v0 = fr[tid], v1 = fr[tid + 256], v2 = fr[tid + 512];
  __shared__ float r1[256], r2[256];
  r1[tid] = v0 + v1 + v2;
  r2[tid] = v0 * v0 + v1 * v1 + v2 * v2;
  __syncthreads();
  for (int o = 128; o > 0; o >>= 1) {
    if (tid < o) { r1[tid] += r1[tid + o]; r2[tid] += r2[tid + o]; }
    __syncthreads();
  }
  float mean = r1[0] * (1.0f / D_);
  float var  = r2[0] * (1.0f / D_) - mean * mean;
  float rstd = rsqrtf(var + 1e-5f);
  float* oo = out + (size_t)row * D_;
  oo[tid      ] = (v0 - mean) * rstd * g[tid      ] + bt[tid      ];
  oo[tid + 256] = (v1 - mean) * rstd * g[tid + 256] + bt[tid + 256];
  oo[tid + 512] = (v2 - mean) * rstd * g[tid + 512] + bt[tid + 512];
}

// ---------------------------------------------------------------------------
// Launch
// ---------------------------------------------------------------------------
extern "C" void kernel_launch(void* const* d_in, const int* in_sizes, int n_in,
                              void* d_out, int out_size, void* d_ws, size_t ws_size,
                              hipStream_t stream)
{
  (void)in_sizes; (void)n_in; (void)out_size; (void)ws_size;
  const float* x    = (const float*)d_in[0];
  const float* nois = (const float*)d_in[1];
  const float* n1g  = (const float*)d_in[2];
  const float* n1b  = (const float*)d_in[3];
  const float* sw   = (const float*)d_in[4];
  const float* sb   = (const float*)d_in[5];
  const float* wq   = (const float*)d_in[6];
  const float* wk   = (const float*)d_in[7];
  const float* wv   = (const float*)d_in[8];
  const float* pw   = (const float*)d_in[9];
  const float* pb   = (const float*)d_in[10];
  const float* n2g  = (const float*)d_in[11];
  const float* n2b  = (const float*)d_in[12];
  const float* f1w  = (const float*)d_in[13];
  const float* f1b  = (const float*)d_in[14];
  const float* f2w  = (const float*)d_in[15];
  const float* f2b  = (const float*)d_in[16];

  float* ws    = (float*)d_ws;
  unsigned short* XH = (unsigned short*)ws;                 // fp16 hi plane
  unsigned short* XL = XH + (size_t)NB_ * D_;               // fp16 lo plane
  float* RG    = ws + (size_t)NB_ * D_;
  float* QIN   = RG + (size_t)NB_ * D_;
  float* FEAT  = QIN + (size_t)ML_ * D_;
  float* AOUT  = FEAT + (size_t)ML_ * D_;
  float* QBUF  = AOUT + (size_t)ML_ * D_;
  float* P     = QBUF + (size_t)ML_ * D_;
  unsigned short* QH16 = (unsigned short*)P;  P += (size_t)ML_ * D_ / 2;
  unsigned short* WTQ  = (unsigned short*)P;  P += (size_t)D_ * D_ / 2;
  unsigned short* WTKV = (unsigned short*)P;  P += (size_t)D_ * D_;     // K then V
  unsigned short* WTP  = (unsigned short*)P;  P += (size_t)D_ * D_ / 2;
  unsigned short* WT1  = (unsigned short*)P;  P += (size_t)D_ * 4 * D_ / 2;
  unsigned short* WT2  = (unsigned short*)P;  P += (size_t)D_ * 4 * D_ / 2;
  float* TS    = P;
  float* SQ    = TS + NB_;
  float* DEN   = SQ + NB_;
  float* SCORE = DEN + NB_;
  float* DMAX  = SCORE + NB_;
  int*   IDXD  = (int*)(DMAX + 64);
  int*   IDXC  = IDXD + ML_;
  float* DM    = RG;                               // phase 1
  unsigned short* KVB = (unsigned short*)RG;       // phase 2: [NB_][1536] K|V
  unsigned short* HID = (unsigned short*)RG;       // phase 3

  hipMemsetAsync(DMAX, 0, 64 * sizeof(float), stream);
  k_wt<<<dim3(24, 24), 256, 0, stream>>>(wq, WTQ, D_, D_);
  k_wt<<<dim3(24, 24), 256, 0, stream>>>(wk, WTKV, D_, D_);
  k_wt<<<dim3(24, 24), 256, 0, stream>>>(wv, WTKV + (size_t)D_ * D_, D_, D_);
  k_wt<<<dim3(24, 24), 256, 0, stream>>>(pw, WTP, D_, D_);
  k_wt<<<dim3(24, 96), 256, 0, stream>>>(f1w, WT1, D_, 4 * D_);
  k_wt<<<dim3(96, 24), 256, 0, stream>>>(f2w, WT2, 4 * D_, D_);

  k_ln1<<<NB_, 256, 0, stream>>>(x, n1g, n1b, sw, sb, XH, XL, TS, SQ);
  k_dmg<<<dim3(21, B_), 256, 0, stream>>>(XH, XL, SQ, DM, DMAX);
  k_density<<<NB_, 64, 0, stream>>>(DM, nois, DEN);
  k_dist<<<NB_, 64, 0, stream>>>(DM, DEN, DMAX, SCORE);
  k_topL<<<B_, 256, 0, stream>>>(SCORE, IDXD);
  k_assign<<<B_, 576, 0, stream>>>(DM, IDXD, IDXC);
  k_merge<<<ML_, 256, 0, stream>>>(XH, XL, TS, IDXC, QIN);

  k_mgemm<0, 0><<<dim3(ML_ / 128, D_ / 128), 256, 0, stream>>>(
      QIN, WTQ, nullptr, nullptr, QH16, ML_, D_, D_);
  k_mgemm<0, 1><<<dim3(NB_ / 128, KV_STRIDE_ / 128), 256, 0, stream>>>(
      XH, WTKV, nullptr, nullptr, KVB, NB_, KV_STRIDE_, D_);
  k_attn<<<dim3(H_, B_), 256, 0, stream>>>(QH16, KVB, TS, AOUT);
  k_mgemm<1, 0><<<dim3(ML_ / 128, D_ / 128), 256, 0, stream>>>(
      AOUT, WTP, pb, QIN, FEAT, ML_, D_, D_);
  k_ln2<<<ML_, 256, 0, stream>>>(FEAT, n2g, n2b, QBUF);
  k_mgemm<2, 0><<<dim3(ML_ / 128, (4 * D_) / 128), 256, 0, stream>>>(
      QBUF, WT1, f1b, nullptr, HID, ML_, 4 * D_, D_);
  k_mgemm<1, 1><<<dim3(ML_ / 128, D_ / 128), 256, 0, stream>>>(
      HID, WT2, f2b, FEAT, d_out, ML_, D_, 4 * D_);
}

// Round 6
// 992.509 us; speedup vs baseline: 1.1907x; 1.0284x over previous
//
#include <hip/hip_runtime.h>
#include <math.h>

// Problem constants
#define B_   64
#define N_   576
#define D_   768
#define L_   64
#define H_   8
#define HD_  96
#define NB_  (B_*N_)    // 36864 rows
#define ML_  (B_*L_)    // 4096 rows
#define KV_STRIDE_ 1536
#define SCALE_ 0.10206207f          // 96^-0.5
#define INV_SQRT_D_ 0.03608439182f  // 1/sqrt(768)
#define LO_SCALE_ 4.8828125e-4f     // 2^-11

typedef __attribute__((ext_vector_type(8))) _Float16 half8v;    // 8 fp16 (4 VGPRs)
typedef __attribute__((ext_vector_type(4))) float floatx4;      // MFMA C/D

__device__ __forceinline__ unsigned short f2h(float f) {
  _Float16 h = (_Float16)f;
  unsigned short u; __builtin_memcpy(&u, &h, 2);
  return u;
}
__device__ __forceinline__ float h2f(unsigned short u) {
  _Float16 h; __builtin_memcpy(&h, &u, 2);
  return (float)h;
}
// async global->LDS, 16B/lane: HW writes lds_base + lane*16 (wave-uniform base),
// global source is per-lane.
__device__ __forceinline__ void gload_lds16(const void* g, void* l) {
  __builtin_amdgcn_global_load_lds(
      (const __attribute__((address_space(1))) unsigned*)g,
      (__attribute__((address_space(3))) unsigned*)l, 16, 0, 0);
}

// ---------------------------------------------------------------------------
// K1: LayerNorm1 -> fp16 hi/lo split planes + token_score + row sum-of-squares
// ---------------------------------------------------------------------------
__global__ __launch_bounds__(256) void k_ln1(const float* __restrict__ x,
    const float* __restrict__ g, const float* __restrict__ bt,
    const float* __restrict__ sw, const float* __restrict__ sb,
    unsigned short* __restrict__ xh, unsigned short* __restrict__ xl,
    float* __restrict__ ts, float* __restrict__ sq)
{
  int row = blockIdx.x, tid = threadIdx.x;
  const float* xr = x + (size_t)row * D_;
  float v0 = xr[tid], v1 = xr[tid + 256], v2 = xr[tid + 512];
  __shared__ float r1[256], r2[256];
  r1[tid] = v0 + v1 + v2;
  r2[tid] = v0 * v0 + v1 * v1 + v2 * v2;
  __syncthreads();
  for (int o = 128; o > 0; o >>= 1) {
    if (tid < o) { r1[tid] += r1[tid + o]; r2[tid] += r2[tid + o]; }
    __syncthreads();
  }
  float mean = r1[0] * (1.0f / D_);
  float var  = r2[0] * (1.0f / D_) - mean * mean;
  float rstd = rsqrtf(var + 1e-5f);
  __syncthreads();
  float o0 = (v0 - mean) * rstd * g[tid      ] + bt[tid      ];
  float o1 = (v1 - mean) * rstd * g[tid + 256] + bt[tid + 256];
  float o2 = (v2 - mean) * rstd * g[tid + 512] + bt[tid + 512];
  auto split = [](float o, unsigned short& hu, unsigned short& lu) {
    _Float16 h = (_Float16)o;
    float hf = (float)h;
    _Float16 l = (_Float16)((o - hf) * 2048.0f);
    __builtin_memcpy(&hu, &h, 2);
    __builtin_memcpy(&lu, &l, 2);
  };
  unsigned short h0, l0, h1, l1, h2, l2;
  split(o0, h0, l0); split(o1, h1, l1); split(o2, h2, l2);
  unsigned short* xho = xh + (size_t)row * D_;
  unsigned short* xlo = xl + (size_t)row * D_;
  xho[tid] = h0; xho[tid + 256] = h1; xho[tid + 512] = h2;
  xlo[tid] = l0; xlo[tid + 256] = l1; xlo[tid + 512] = l2;
  r1[tid] = o0 * sw[tid] + o1 * sw[tid + 256] + o2 * sw[tid + 512];
  r2[tid] = o0 * o0 + o1 * o1 + o2 * o2;
  __syncthreads();
  for (int o = 128; o > 0; o >>= 1) {
    if (tid < o) { r1[tid] += r1[tid + o]; r2[tid] += r2[tid + o]; }
    __syncthreads();
  }
  if (tid == 0) { ts[row] = r1[0] + sb[0]; sq[row] = r2[0]; }
}

// ---------------------------------------------------------------------------
// K2: pairwise distances via fp16x2 split-precision MFMA Gram.
// Staging via global_load_lds width=16 (m97 recipe): linear LDS dest,
// per-lane PRE-SWIZZLED global source; reads apply the same XOR involution
// (chunk ^ row&7). BK=64 -> 12 barrier-pairs (was 24). LDS 48KB -> 3 blk/CU.
// Wave w stages panel w (0:Ah 1:Al 2:Bh 3:Bl), 12x 1KB loads per K-step.
// MFMA order identical to prior rounds -> bit-identical dm. Fused batch-max.
// ---------------------------------------------------------------------------
__global__ __launch_bounds__(256) void k_dmg(const unsigned short* __restrict__ xh,
    const unsigned short* __restrict__ xl, const float* __restrict__ sq,
    float* __restrict__ dm, float* __restrict__ dmax)
{
  __shared__ __align__(16) unsigned short S[4][96 * 64];   // 4 x 12KB = 48KB
  int b = blockIdx.y;
  int t = blockIdx.x, ti = 0, rl = 6;
  while (t >= rl) { t -= rl; ++ti; --rl; }
  int tj = ti + t;
  int tid = threadIdx.x;
  int wave = tid >> 6, lane = tid & 63;
  int wr = (wave >> 1) * 48, wc = (wave & 1) * 48;
  int mloc = lane & 15, quad = lane >> 4;
  size_t rowA = (size_t)b * N_ + ti * 96;
  size_t rowB = (size_t)b * N_ + tj * 96;

  // wave's staging panel source; lane covers row lrow=lane>>3, chunk lane&7.
  // source chunk pre-swizzled: data chunk (c ^ row&7) lands at position c.
  const unsigned short* srcbase =
      (wave == 0) ? xh + rowA * D_ :
      (wave == 1) ? xl + rowA * D_ :
      (wave == 2) ? xh + rowB * D_ : xl + rowB * D_;
  int lrow = lane >> 3, lchunk = lane & 7;
  const unsigned short* gsrc0 = srcbase + (size_t)lrow * D_ + ((lchunk ^ lrow) * 8);
  unsigned short* lbase = &S[wave][0];

  floatx4 a1[3][3], a2[3][3];
#pragma unroll
  for (int i = 0; i < 3; ++i)
#pragma unroll
    for (int j = 0; j < 3; ++j) {
      a1[i][j] = (floatx4){0.f, 0.f, 0.f, 0.f};
      a2[i][j] = (floatx4){0.f, 0.f, 0.f, 0.f};
    }

  for (int kt = 0; kt < D_; kt += 64) {
    __syncthreads();
#pragma unroll
    for (int rb = 0; rb < 12; ++rb)
      gload_lds16(gsrc0 + (size_t)rb * 8 * D_ + kt, lbase + rb * 8 * 64);
    __syncthreads();
#pragma unroll
    for (int ks = 0; ks < 2; ++ks) {
      half8v ah[3], al[3], bh[3], bl[3];
      int cperm = (((ks << 2) | quad) ^ (mloc & 7)) * 8;
#pragma unroll
      for (int i = 0; i < 3; ++i) {
        int ro = (wr + i * 16 + mloc) * 64 + cperm;
        ah[i] = *(const half8v*)&S[0][ro];
        al[i] = *(const half8v*)&S[1][ro];
      }
#pragma unroll
      for (int j = 0; j < 3; ++j) {
        int ro = (wc + j * 16 + mloc) * 64 + cperm;
        bh[j] = *(const half8v*)&S[2][ro];
        bl[j] = *(const half8v*)&S[3][ro];
      }
#pragma unroll
      for (int i = 0; i < 3; ++i)
#pragma unroll
        for (int j = 0; j < 3; ++j) {
          a1[i][j] = __builtin_amdgcn_mfma_f32_16x16x32_f16(ah[i], bh[j], a1[i][j], 0, 0, 0);
          a2[i][j] = __builtin_amdgcn_mfma_f32_16x16x32_f16(ah[i], bl[j], a2[i][j], 0, 0, 0);
          a2[i][j] = __builtin_amdgcn_mfma_f32_16x16x32_f16(al[i], bh[j], a2[i][j], 0, 0, 0);
        }
    }
  }

  const float* sqb = sq + b * N_;
  float* dmb = dm + (size_t)b * N_ * N_;
  bool diag = (ti == tj);
  float vmax = 0.f;
#pragma unroll
  for (int j = 0; j < 3; ++j) {
    int gj = tj * 96 + wc + j * 16 + mloc;
    float sj = sqb[gj];
#pragma unroll
    for (int i = 0; i < 3; ++i) {
      int gi0 = ti * 96 + wr + i * 16 + quad * 4;
#pragma unroll
      for (int reg = 0; reg < 4; ++reg) {
        int gi = gi0 + reg;
        float g = a1[i][j][reg] + a2[i][j][reg] * LO_SCALE_;
        float d = sqb[gi] + sj - 2.0f * g;
        float v = sqrtf(fmaxf(d, 0.0f)) * INV_SQRT_D_;
        vmax = fmaxf(vmax, v);
        if (!diag || gj >= gi) {
          dmb[(size_t)gi * N_ + gj] = v;
          dmb[(size_t)gj * N_ + gi] = v;
        }
      }
    }
  }
#pragma unroll
  for (int msk = 32; msk >= 1; msk >>= 1) vmax = fmaxf(vmax, __shfl_xor(vmax, msk));
  if (lane == 0) atomicMax((unsigned int*)(dmax + b), __float_as_uint(vmax));
}

// ---------------------------------------------------------------------------
// K3: kNN density
// ---------------------------------------------------------------------------
__global__ __launch_bounds__(64) void k_density(const float* __restrict__ dm,
    const float* __restrict__ noise, float* __restrict__ den)
{
  int row = blockIdx.x, lane = threadIdx.x;
  const float* r = dm + (size_t)row * N_;
  float a0 = 1e30f, a1 = 1e30f, a2 = 1e30f, a3 = 1e30f, a4 = 1e30f;
  auto ins5 = [&](float xv) {
    a4 = fminf(a4, xv);
    float t;
    t = fminf(a3, a4); a4 = fmaxf(a3, a4); a3 = t;
    t = fminf(a2, a3); a3 = fmaxf(a2, a3); a2 = t;
    t = fminf(a1, a2); a2 = fmaxf(a1, a2); a1 = t;
    t = fminf(a0, a1); a1 = fmaxf(a0, a1); a0 = t;
  };
#pragma unroll
  for (int t = 0; t < 9; ++t) ins5(r[lane + 64 * t]);
  for (int m = 1; m < 64; m <<= 1) {
    float b0 = __shfl_xor(a0, m), b1 = __shfl_xor(a1, m), b2 = __shfl_xor(a2, m);
    float b3 = __shfl_xor(a3, m), b4 = __shfl_xor(a4, m);
    ins5(b0); ins5(b1); ins5(b2); ins5(b3); ins5(b4);
  }
  if (lane == 0) {
    float ms = (a0 * a0 + a1 * a1 + a2 * a2 + a3 * a3 + a4 * a4) * 0.2f;
    den[row] = expf(-ms) + noise[row] * 1e-6f;
  }
}

// ---------------------------------------------------------------------------
// K5: dist-to-higher-density + score
// ---------------------------------------------------------------------------
__global__ __launch_bounds__(64) void k_dist(const float* __restrict__ dm,
    const float* __restrict__ den, const float* __restrict__ dmax,
    float* __restrict__ score)
{
  int row = blockIdx.x, lane = threadIdx.x;
  int b = row / N_;
  float di = den[row], dx = dmax[b];
  const float* r = dm + (size_t)row * N_;
  const float* db = den + b * N_;
  float m = dx;
#pragma unroll
  for (int t = 0; t < 9; ++t) {
    int j = lane + 64 * t;
    float v = (db[j] > di) ? r[j] : dx;
    m = fminf(m, v);
  }
  for (int msk = 1; msk < 64; msk <<= 1) m = fminf(m, __shfl_xor(m, msk));
  if (lane == 0) score[row] = m * di;
}

// ---------------------------------------------------------------------------
// K6: top-64 scores per batch
// ---------------------------------------------------------------------------
__global__ __launch_bounds__(256) void k_topL(const float* __restrict__ score,
    int* __restrict__ idxd)
{
  int b = blockIdx.x, tid = threadIdx.x;
  __shared__ float s[N_];
  __shared__ float rv[256];
  __shared__ int   ri[256];
  for (int j = tid; j < N_; j += 256) s[j] = score[b * N_ + j];
  __syncthreads();
  for (int it = 0; it < L_; ++it) {
    float bv = -1e30f; int bi = 1 << 30;
    for (int j = tid; j < N_; j += 256) {
      float v = s[j];
      if (v > bv || (v == bv && j < bi)) { bv = v; bi = j; }
    }
    rv[tid] = bv; ri[tid] = bi; __syncthreads();
    for (int o = 128; o > 0; o >>= 1) {
      if (tid < o) {
        float v2 = rv[tid + o]; int i2 = ri[tid + o];
        if (v2 > rv[tid] || (v2 == rv[tid] && i2 < ri[tid])) { rv[tid] = v2; ri[tid] = i2; }
      }
      __syncthreads();
    }
    if (tid == 0) { idxd[b * L_ + it] = ri[0]; s[ri[0]] = -1e30f; }
    __syncthreads();
  }
}

// ---------------------------------------------------------------------------
// K7: assign tokens to nearest center (+ fused center self-assignment)
// ---------------------------------------------------------------------------
__global__ __launch_bounds__(576) void k_assign(const float* __restrict__ dm,
    const int* __restrict__ idxd, int* __restrict__ idxc)
{
  int b = blockIdx.x, n = threadIdx.x;
  __shared__ int ctr[L_];
  if (n < L_) ctr[n] = idxd[b * L_ + n];
  __syncthreads();
  const float* dmb = dm + (size_t)b * N_ * N_;
  float best = 1e30f; int bl = 0;
  for (int l = 0; l < L_; ++l) {
    float v = dmb[(size_t)ctr[l] * N_ + n];
    if (v < best) { best = v; bl = l; }
  }
  for (int l = 0; l < L_; ++l)
    if (ctr[l] == n) bl = l;
  idxc[b * N_ + n] = bl;
}

// ---------------------------------------------------------------------------
// K8: merger (gather form) — reconstructs xn = hi + lo*2^-11
// ---------------------------------------------------------------------------
__global__ __launch_bounds__(256) void k_merge(const unsigned short* __restrict__ xh,
    const unsigned short* __restrict__ xl,
    const float* __restrict__ ts, const int* __restrict__ idxc,
    float* __restrict__ qin)
{
  int blk = blockIdx.x;
  int b = blk >> 6, l = blk & 63;
  int tid = threadIdx.x;
  const int* ic = idxc + b * N_;
  const float* tsb = ts + b * N_;
  const unsigned short* xhb = xh + (size_t)b * N_ * D_;
  const unsigned short* xlb = xl + (size_t)b * N_ * D_;
  float a0 = 0.f, a1 = 0.f, a2 = 0.f, wsum = 0.f;
  for (int n = 0; n < N_; ++n) {
    if (ic[n] == l) {
      float w = expf(tsb[n]);
      wsum += w;
      const unsigned short* hr = xhb + (size_t)n * D_;
      const unsigned short* lr = xlb + (size_t)n * D_;
      float x0 = h2f(hr[tid      ]) + h2f(lr[tid      ]) * LO_SCALE_;
      float x1 = h2f(hr[tid + 256]) + h2f(lr[tid + 256]) * LO_SCALE_;
      float x2 = h2f(hr[tid + 512]) + h2f(lr[tid + 512]) * LO_SCALE_;
      a0 += w * x0; a1 += w * x1; a2 += w * x2;
    }
  }
  float inv = 1.0f / (wsum + 1e-6f);
  float* q = qin + (size_t)blk * D_;
  q[tid] = a0 * inv; q[tid + 256] = a1 * inv; q[tid + 512] = a2 * inv;
}

// ---------------------------------------------------------------------------
// Weight transpose + fp16 cast: W[K,N] fp32 -> WT[N,K] fp16
// ---------------------------------------------------------------------------
__global__ __launch_bounds__(256) void k_wt(const float* __restrict__ W,
    unsigned short* __restrict__ WT, int K, int N)
{
  __shared__ float t[32][33];
  int k0 = blockIdx.x * 32, n0 = blockIdx.y * 32;
  int tid = threadIdx.x;
  int r = tid >> 3, c4 = (tid & 7) * 4;
  float4 v = *(const float4*)(W + (size_t)(k0 + r) * N + n0 + c4);
  t[r][c4] = v.x; t[r][c4 + 1] = v.y; t[r][c4 + 2] = v.z; t[r][c4 + 3] = v.w;
  __syncthreads();
  ushort4 s4;
  s4.x = f2h(t[c4 + 0][r]); s4.y = f2h(t[c4 + 1][r]);
  s4.z = f2h(t[c4 + 2][r]); s4.w = f2h(t[c4 + 3][r]);
  *(ushort4*)(WT + (size_t)(n0 + r) * K + k0 + c4) = s4;
}

// ---------------------------------------------------------------------------
// MFMA GEMM: C[M,N] = epilogue(A[M,K] @ WT[N,K]^T), fp16 MFMA, fp32 accum.
// B staged via global_load_lds (linear [128][32] LDS). A: gload_lds if fp16
// (ASRC==1) else reg-staged fp32->fp16 into padded [128][40].
// ASRC 0: A fp32   1: A fp16
// EPI  0: fp16 out  1: +bias +res -> fp32 out  2: +bias, exact GELU -> fp16
// ---------------------------------------------------------------------------
template<int EPI, int ASRC>
__global__ __launch_bounds__(256) void k_mgemm(const void* __restrict__ Ap_,
    const unsigned short* __restrict__ Wt, const float* __restrict__ bias,
    const float* __restrict__ res, void* __restrict__ outp,
    int M, int Nd, int Kd)
{
  constexpr int APITCH = (ASRC == 1) ? 32 : 40;
  __shared__ __align__(16) unsigned short As[128 * APITCH];
  __shared__ __align__(16) unsigned short Bs[128 * 32];
  int tid = threadIdx.x;
  int bm = blockIdx.x * 128, bn = blockIdx.y * 128;
  int wave = tid >> 6, lane = tid & 63;
  int wr = (wave >> 1) * 64, wc = (wave & 1) * 64;
  int mloc = lane & 15, quad = lane >> 4;

  floatx4 acc[4][4];
#pragma unroll
  for (int i = 0; i < 4; ++i)
#pragma unroll
    for (int j = 0; j < 4; ++j)
      acc[i][j] = (floatx4){0.f, 0.f, 0.f, 0.f};

  // gload lane mapping: 1KB per load = 16 rows x 64B; row=lane>>2, chunk=lane&3
  int gr = wave * 32 + (lane >> 2);
  int gc = (lane & 3) * 8;

  for (int kt = 0; kt < Kd; kt += 32) {
    __syncthreads();
#pragma unroll
    for (int rb = 0; rb < 2; ++rb)
      gload_lds16(Wt + (size_t)(bn + gr + rb * 16) * Kd + kt + gc,
                  &Bs[(wave * 32 + rb * 16) * 32]);
    if (ASRC == 1) {
      const unsigned short* A = (const unsigned short*)Ap_;
#pragma unroll
      for (int rb = 0; rb < 2; ++rb)
        gload_lds16(A + (size_t)(bm + gr + rb * 16) * Kd + kt + gc,
                    &As[(wave * 32 + rb * 16) * 32]);
    } else {
      const float* A = (const float*)Ap_;
#pragma unroll
      for (int it = 0; it < 2; ++it) {
        int idx = tid + it * 256;
        int r = idx >> 2, c = idx & 3;
        const float* ap = A + (size_t)(bm + r) * Kd + kt + c * 8;
        float4 f0 = *(const float4*)ap;
        float4 f1 = *(const float4*)(ap + 4);
        uint4 pk;
        pk.x = (unsigned)f2h(f0.x) | ((unsigned)f2h(f0.y) << 16);
        pk.y = (unsigned)f2h(f0.z) | ((unsigned)f2h(f0.w) << 16);
        pk.z = (unsigned)f2h(f1.x) | ((unsigned)f2h(f1.y) << 16);
        pk.w = (unsigned)f2h(f1.z) | ((unsigned)f2h(f1.w) << 16);
        *(uint4*)&As[r * 40 + c * 8] = pk;
      }
    }
    __syncthreads();
    half8v af[4], bf[4];
#pragma unroll
    for (int i = 0; i < 4; ++i)
      af[i] = *(const half8v*)&As[(wr + i * 16 + mloc) * APITCH + quad * 8];
#pragma unroll
    for (int j = 0; j < 4; ++j)
      bf[j] = *(const half8v*)&Bs[(wc + j * 16 + mloc) * 32 + quad * 8];
#pragma unroll
    for (int i = 0; i < 4; ++i)
#pragma unroll
      for (int j = 0; j < 4; ++j)
        acc[i][j] = __builtin_amdgcn_mfma_f32_16x16x32_f16(af[i], bf[j], acc[i][j], 0, 0, 0);
  }

  float bv[4] = {0.f, 0.f, 0.f, 0.f};
  if (EPI >= 1) {
#pragma unroll
    for (int j = 0; j < 4; ++j) bv[j] = bias[bn + wc + j * 16 + mloc];
  }
#pragma unroll
  for (int i = 0; i < 4; ++i) {
    int gr0 = bm + wr + i * 16 + quad * 4;
#pragma unroll
    for (int j = 0; j < 4; ++j) {
      int gcn = bn + wc + j * 16 + mloc;
#pragma unroll
      for (int reg = 0; reg < 4; ++reg) {
        float v = acc[i][j][reg];
        size_t off = (size_t)(gr0 + reg) * Nd + gcn;
        if (EPI == 0) {
          ((unsigned short*)outp)[off] = f2h(v);
        } else if (EPI == 1) {
          ((float*)outp)[off] = v + bv[j] + res[off];
        } else {
          v += bv[j];
          v = 0.5f * v * (1.0f + erff(v * 0.70710678f));
          ((unsigned short*)outp)[off] = f2h(v);
        }
      }
    }
  }
}

// ---------------------------------------------------------------------------
// K12: MFMA flash cross-attention with token-score bias (all fp16 operands).
// K/V interleaved in one buffer, row stride 1536 (K at col h*96, V at 768+h*96)
// ---------------------------------------------------------------------------
__global__ __launch_bounds__(256) void k_attn(const unsigned short* __restrict__ Qu,
    const unsigned short* __restrict__ KVu, const float* __restrict__ ts,
    float* __restrict__ aout)
{
  __shared__ __align__(16) unsigned short Ks[64 * 104];
  __shared__ __align__(16) unsigned short VsT[96 * 64];
  __shared__ __align__(16) unsigned short sPa[64 * 64];
  __shared__ float tsb[64];
  int h = blockIdx.x, b = blockIdx.y;
  int tid = threadIdx.x;
  int wave = tid >> 6, lane = tid & 63;
  int mloc = lane & 15, quad = lane >> 4;

  half8v qf[3];
  {
    const unsigned short* qrow = Qu + (size_t)(b * 64 + wave * 16 + mloc) * D_ + h * 96 + quad * 8;
#pragma unroll
    for (int k = 0; k < 3; ++k) qf[k] = *(const half8v*)(qrow + k * 32);
  }

  floatx4 of[6];
#pragma unroll
  for (int dt = 0; dt < 6; ++dt) of[dt] = (floatx4){0.f, 0.f, 0.f, 0.f};
  float m[4], l[4];
#pragma unroll
  for (int r = 0; r < 4; ++r) { m[r] = -1e30f; l[r] = 0.f; }

  for (int jt = 0; jt < 9; ++jt) {
    int j0 = jt * 64;
    __syncthreads();
#pragma unroll
    for (int t = 0; t < 3; ++t) {
      int id = tid + t * 256;
      int row = id / 12, c = id % 12;
      *(uint4*)&Ks[row * 104 + c * 8] =
          *(const uint4*)(KVu + (size_t)(b * N_ + j0 + row) * KV_STRIDE_ + h * 96 + c * 8);
    }
#pragma unroll
    for (int t = 0; t < 3; ++t) {
      int id = tid + t * 256;
      int keyp = id & 31, dq = (id >> 5) * 4;
      int key = keyp * 2;
      const unsigned short* vp =
          KVu + (size_t)(b * N_ + j0 + key) * KV_STRIDE_ + 768 + h * 96 + dq;
      ushort4 v0 = *(const ushort4*)vp;
      ushort4 v1 = *(const ushort4*)(vp + KV_STRIDE_);
      unsigned pk0 = (unsigned)v0.x | ((unsigned)v1.x << 16);
      unsigned pk1 = (unsigned)v0.y | ((unsigned)v1.y << 16);
      unsigned pk2 = (unsigned)v0.z | ((unsigned)v1.z << 16);
      unsigned pk3 = (unsigned)v0.w | ((unsigned)v1.w << 16);
      int cbase = key >> 3, off = key & 7;
#pragma unroll
      for (int i = 0; i < 4; ++i) {
        int d = dq + i;
        unsigned pv = (i == 0) ? pk0 : (i == 1) ? pk1 : (i == 2) ? pk2 : pk3;
        *(unsigned*)&VsT[d * 64 + ((cbase ^ (d & 7)) << 3) + off] = pv;
      }
    }
    if (tid < 64) tsb[tid] = ts[b * N_ + j0 + tid];
    __syncthreads();

    floatx4 acc[4];
#pragma unroll
    for (int j = 0; j < 4; ++j) acc[j] = (floatx4){0.f, 0.f, 0.f, 0.f};
#pragma unroll
    for (int j = 0; j < 4; ++j)
#pragma unroll
      for (int k = 0; k < 3; ++k) {
        half8v kf = *(const half8v*)&Ks[(j * 16 + mloc) * 104 + k * 32 + quad * 8];
        acc[j] = __builtin_amdgcn_mfma_f32_16x16x32_f16(qf[k], kf, acc[j], 0, 0, 0);
      }

    float ts4[4];
#pragma unroll
    for (int j = 0; j < 4; ++j) ts4[j] = tsb[j * 16 + mloc];
    float rm[4] = {-1e30f, -1e30f, -1e30f, -1e30f};
#pragma unroll
    for (int j = 0; j < 4; ++j)
#pragma unroll
      for (int r = 0; r < 4; ++r) {
        acc[j][r] = acc[j][r] * SCALE_ + ts4[j];
        rm[r] = fmaxf(rm[r], acc[j][r]);
      }
#pragma unroll
    for (int r = 0; r < 4; ++r) {
      rm[r] = fmaxf(rm[r], __shfl_xor(rm[r], 1));
      rm[r] = fmaxf(rm[r], __shfl_xor(rm[r], 2));
      rm[r] = fmaxf(rm[r], __shfl_xor(rm[r], 4));
      rm[r] = fmaxf(rm[r], __shfl_xor(rm[r], 8));
    }
    float alpha[4], rs[4];
#pragma unroll
    for (int r = 0; r < 4; ++r) {
      float mn = fmaxf(m[r], rm[r]);
      alpha[r] = __expf(m[r] - mn);
      m[r] = mn;
      rs[r] = 0.f;
    }
#pragma unroll
    for (int j = 0; j < 4; ++j)
#pragma unroll
      for (int r = 0; r < 4; ++r) {
        float p = __expf(acc[j][r] - m[r]);
        acc[j][r] = p; rs[r] += p;
      }
#pragma unroll
    for (int r = 0; r < 4; ++r) {
      rs[r] += __shfl_xor(rs[r], 1); rs[r] += __shfl_xor(rs[r], 2);
      rs[r] += __shfl_xor(rs[r], 4); rs[r] += __shfl_xor(rs[r], 8);
      l[r] = l[r] * alpha[r] + rs[r];
    }
#pragma unroll
    for (int dt = 0; dt < 6; ++dt)
#pragma unroll
      for (int r = 0; r < 4; ++r) of[dt][r] *= alpha[r];

#pragma unroll
    for (int j = 0; j < 4; ++j)
#pragma unroll
      for (int r = 0; r < 4; ++r) {
        int row = wave * 16 + quad * 4 + r;
        int key = j * 16 + mloc;
        sPa[row * 64 + (((key >> 3) ^ (row & 7)) << 3) + (key & 7)] = f2h(acc[j][r]);
      }
    half8v pa[2];
    int prow = wave * 16 + mloc;
#pragma unroll
    for (int f2 = 0; f2 < 2; ++f2)
      pa[f2] = *(const half8v*)&sPa[prow * 64 + (((f2 * 4 + quad) ^ (prow & 7)) << 3)];
#pragma unroll
    for (int dt = 0; dt < 6; ++dt)
#pragma unroll
      for (int f2 = 0; f2 < 2; ++f2) {
        int vrow = dt * 16 + mloc;
        half8v vf = *(const half8v*)&VsT[vrow * 64 + (((f2 * 4 + quad) ^ (vrow & 7)) << 3)];
        of[dt] = __builtin_amdgcn_mfma_f32_16x16x32_f16(pa[f2], vf, of[dt], 0, 0, 0);
      }
  }

  float linv[4];
#pragma unroll
  for (int r = 0; r < 4; ++r) linv[r] = 1.0f / l[r];
#pragma unroll
  for (int dt = 0; dt < 6; ++dt)
#pragma unroll
    for (int r = 0; r < 4; ++r) {
      int row = b * 64 + wave * 16 + quad * 4 + r;
      int col = h * 96 + dt * 16 + mloc;
      aout[(size_t)row * D_ + col] = of[dt][r] * linv[r];
    }
}

// ---------------------------------------------------------------------------
// K14: LayerNorm2 (fp32 in -> fp32 out)
// ---------------------------------------------------------------------------
__global__ __launch_bounds__(256) void k_ln2(const float* __restrict__ f,
    const float* __restrict__ g, const float* __restrict__ bt, float* __restrict__ out)
{
  int row = blockIdx.x, tid = threadIdx.x;
  const float* fr = f + (size_t)row * D_;
  float v0 = fr[tid], v1 = fr[tid + 256], v2 = fr[tid + 512];
  __shared__ float r1[256], r2[256];
  r1[tid] = v0 + v1 + v2;
  r2[tid] = v0 * v0 + v1 * v1 + v2 * v2;
  __syncthreads();
  for (int o = 128; o > 0; o >>= 1) {
    if (tid < o) { r1[tid] += r1[tid + o]; r2[tid] += r2[tid + o]; }
    __syncthreads();
  }
  float mean = r1[0] * (1.0f / D_);
  float var  = r2[0] * (1.0f / D_) - mean * mean;
  float rstd = rsqrtf(var + 1e-5f);
  float* oo = out + (size_t)row * D_;
  oo[tid      ] = (v0 - mean) * rstd * g[tid      ] + bt[tid      ];
  oo[tid + 256] = (v1 - mean) * rstd * g[tid + 256] + bt[tid + 256];
  oo[tid + 512] = (v2 - mean) * rstd * g[tid + 512] + bt[tid + 512];
}

// ---------------------------------------------------------------------------
// Launch
// ---------------------------------------------------------------------------
extern "C" void kernel_launch(void* const* d_in, const int* in_sizes, int n_in,
                              void* d_out, int out_size, void* d_ws, size_t ws_size,
                              hipStream_t stream)
{
  (void)in_sizes; (void)n_in; (void)out_size; (void)ws_size;
  const float* x    = (const float*)d_in[0];
  const float* nois = (const float*)d_in[1];
  const float* n1g  = (const float*)d_in[2];
  const float* n1b  = (const float*)d_in[3];
  const float* sw   = (const float*)d_in[4];
  const float* sb   = (const float*)d_in[5];
  const float* wq   = (const float*)d_in[6];
  const float* wk   = (const float*)d_in[7];
  const float* wv   = (const float*)d_in[8];
  const float* pw   = (const float*)d_in[9];
  const float* pb   = (const float*)d_in[10];
  const float* n2g  = (const float*)d_in[11];
  const float* n2b  = (const float*)d_in[12];
  const float* f1w  = (const float*)d_in[13];
  const float* f1b  = (const float*)d_in[14];
  const float* f2w  = (const float*)d_in[15];
  const float* f2b  = (const float*)d_in[16];

  float* ws    = (float*)d_ws;
  unsigned short* XH = (unsigned short*)ws;                 // fp16 hi plane
  unsigned short* XL = XH + (size_t)NB_ * D_;               // fp16 lo plane
  float* RG    = ws + (size_t)NB_ * D_;
  float* QIN   = RG + (size_t)NB_ * D_;
  float* FEAT  = QIN + (size_t)ML_ * D_;
  float* AOUT  = FEAT + (size_t)ML_ * D_;
  float* QBUF  = AOUT + (size_t)ML_ * D_;
  float* P     = QBUF + (size_t)ML_ * D_;
  unsigned short* QH16 = (unsigned short*)P;  P += (size_t)ML_ * D_ / 2;
  unsigned short* WTQ  = (unsigned short*)P;  P += (size_t)D_ * D_ / 2;
  unsigned short* WTKV = (unsigned short*)P;  P += (size_t)D_ * D_;     // K then V
  unsigned short* WTP  = (unsigned short*)P;  P += (size_t)D_ * D_ / 2;
  unsigned short* WT1  = (unsigned short*)P;  P += (size_t)D_ * 4 * D_ / 2;
  unsigned short* WT2  = (unsigned short*)P;  P += (size_t)D_ * 4 * D_ / 2;
  float* TS    = P;
  float* SQ    = TS + NB_;
  float* DEN   = SQ + NB_;
  float* SCORE = DEN + NB_;
  float* DMAX  = SCORE + NB_;
  int*   IDXD  = (int*)(DMAX + 64);
  int*   IDXC  = IDXD + ML_;
  float* DM    = RG;                               // phase 1
  unsigned short* KVB = (unsigned short*)RG;       // phase 2: [NB_][1536] K|V
  unsigned short* HID = (unsigned short*)RG;       // phase 3

  hipMemsetAsync(DMAX, 0, 64 * sizeof(float), stream);
  k_wt<<<dim3(24, 24), 256, 0, stream>>>(wq, WTQ, D_, D_);
  k_wt<<<dim3(24, 24), 256, 0, stream>>>(wk, WTKV, D_, D_);
  k_wt<<<dim3(24, 24), 256, 0, stream>>>(wv, WTKV + (size_t)D_ * D_, D_, D_);
  k_wt<<<dim3(24, 24), 256, 0, stream>>>(pw, WTP, D_, D_);
  k_wt<<<dim3(24, 96), 256, 0, stream>>>(f1w, WT1, D_, 4 * D_);
  k_wt<<<dim3(96, 24), 256, 0, stream>>>(f2w, WT2, 4 * D_, D_);

  k_ln1<<<NB_, 256, 0, stream>>>(x, n1g, n1b, sw, sb, XH, XL, TS, SQ);
  k_dmg<<<dim3(21, B_), 256, 0, stream>>>(XH, XL, SQ, DM, DMAX);
  k_density<<<NB_, 64, 0, stream>>>(DM, nois, DEN);
  k_dist<<<NB_, 64, 0, stream>>>(DM, DEN, DMAX, SCORE);
  k_topL<<<B_, 256, 0, stream>>>(SCORE, IDXD);
  k_assign<<<B_, 576, 0, stream>>>(DM, IDXD, IDXC);
  k_merge<<<ML_, 256, 0, stream>>>(XH, XL, TS, IDXC, QIN);

  k_mgemm<0, 0><<<dim3(ML_ / 128, D_ / 128), 256, 0, stream>>>(
      QIN, WTQ, nullptr, nullptr, QH16, ML_, D_, D_);
  k_mgemm<0, 1><<<dim3(NB_ / 128, KV_STRIDE_ / 128), 256, 0, stream>>>(
      XH, WTKV, nullptr, nullptr, KVB, NB_, KV_STRIDE_, D_);
  k_attn<<<dim3(H_, B_), 256, 0, stream>>>(QH16, KVB, TS, AOUT);
  k_mgemm<1, 0><<<dim3(ML_ / 128, D_ / 128), 256, 0, stream>>>(
      AOUT, WTP, pb, QIN, FEAT, ML_, D_, D_);
  k_ln2<<<ML_, 256, 0, stream>>>(FEAT, n2g, n2b, QBUF);
  k_mgemm<2, 0><<<dim3(ML_ / 128, (4 * D_) / 128), 256, 0, stream>>>(
      QBUF, WT1, f1b, nullptr, HID, ML_, 4 * D_, D_);
  k_mgemm<1, 1><<<dim3(ML_ / 128, D_ / 128), 256, 0, stream>>>(
      HID, WT2, f2b, FEAT, d_out, ML_, D_, 4 * D_);
}

// Round 7
// 946.646 us; speedup vs baseline: 1.2484x; 1.0484x over previous
//
#include <hip/hip_runtime.h>
#include <math.h>

// Problem constants
#define B_   64
#define N_   576
#define D_   768
#define L_   64
#define H_   8
#define HD_  96
#define NB_  (B_*N_)    // 36864 rows
#define ML_  (B_*L_)    // 4096 rows
#define KV_STRIDE_ 1536
#define SCALE_ 0.10206207f          // 96^-0.5
#define INV_SQRT_D_ 0.03608439182f  // 1/sqrt(768)
#define LO_SCALE_ 4.8828125e-4f     // 2^-11

typedef __attribute__((ext_vector_type(8))) _Float16 half8v;    // 8 fp16 (4 VGPRs)
typedef __attribute__((ext_vector_type(4))) float floatx4;      // MFMA C/D

__device__ __forceinline__ unsigned short f2h(float f) {
  _Float16 h = (_Float16)f;
  unsigned short u; __builtin_memcpy(&u, &h, 2);
  return u;
}
__device__ __forceinline__ float h2f(unsigned short u) {
  _Float16 h; __builtin_memcpy(&h, &u, 2);
  return (float)h;
}
// async global->LDS, 16B/lane: HW writes lds_base + lane*16 (wave-uniform base),
// global source is per-lane.
__device__ __forceinline__ void gload_lds16(const void* g, void* l) {
  __builtin_amdgcn_global_load_lds(
      (const __attribute__((address_space(1))) unsigned*)g,
      (__attribute__((address_space(3))) unsigned*)l, 16, 0, 0);
}

// ---------------------------------------------------------------------------
// K1: LayerNorm1 -> fp16 hi/lo split planes + token_score + row sum-of-squares
// ---------------------------------------------------------------------------
__global__ __launch_bounds__(256) void k_ln1(const float* __restrict__ x,
    const float* __restrict__ g, const float* __restrict__ bt,
    const float* __restrict__ sw, const float* __restrict__ sb,
    unsigned short* __restrict__ xh, unsigned short* __restrict__ xl,
    float* __restrict__ ts, float* __restrict__ sq)
{
  int row = blockIdx.x, tid = threadIdx.x;
  const float* xr = x + (size_t)row * D_;
  float v0 = xr[tid], v1 = xr[tid + 256], v2 = xr[tid + 512];
  __shared__ float r1[256], r2[256];
  r1[tid] = v0 + v1 + v2;
  r2[tid] = v0 * v0 + v1 * v1 + v2 * v2;
  __syncthreads();
  for (int o = 128; o > 0; o >>= 1) {
    if (tid < o) { r1[tid] += r1[tid + o]; r2[tid] += r2[tid + o]; }
    __syncthreads();
  }
  float mean = r1[0] * (1.0f / D_);
  float var  = r2[0] * (1.0f / D_) - mean * mean;
  float rstd = rsqrtf(var + 1e-5f);
  __syncthreads();
  float o0 = (v0 - mean) * rstd * g[tid      ] + bt[tid      ];
  float o1 = (v1 - mean) * rstd * g[tid + 256] + bt[tid + 256];
  float o2 = (v2 - mean) * rstd * g[tid + 512] + bt[tid + 512];
  auto split = [](float o, unsigned short& hu, unsigned short& lu) {
    _Float16 h = (_Float16)o;
    float hf = (float)h;
    _Float16 l = (_Float16)((o - hf) * 2048.0f);
    __builtin_memcpy(&hu, &h, 2);
    __builtin_memcpy(&lu, &l, 2);
  };
  unsigned short h0, l0, h1, l1, h2, l2;
  split(o0, h0, l0); split(o1, h1, l1); split(o2, h2, l2);
  unsigned short* xho = xh + (size_t)row * D_;
  unsigned short* xlo = xl + (size_t)row * D_;
  xho[tid] = h0; xho[tid + 256] = h1; xho[tid + 512] = h2;
  xlo[tid] = l0; xlo[tid + 256] = l1; xlo[tid + 512] = l2;
  r1[tid] = o0 * sw[tid] + o1 * sw[tid + 256] + o2 * sw[tid + 512];
  r2[tid] = o0 * o0 + o1 * o1 + o2 * o2;
  __syncthreads();
  for (int o = 128; o > 0; o >>= 1) {
    if (tid < o) { r1[tid] += r1[tid + o]; r2[tid] += r2[tid + o]; }
    __syncthreads();
  }
  if (tid == 0) { ts[row] = r1[0] + sb[0]; sq[row] = r2[0]; }
}

// ---------------------------------------------------------------------------
// K2: pairwise distances via fp16x2 split-precision MFMA Gram.
// Staging via global_load_lds width=16: linear LDS dest, pre-swizzled global
// source; reads apply the same XOR involution (chunk ^ row&7). BK=64.
// Wave w stages panel w (0:Ah 1:Al 2:Bh 3:Bl). Fused batch-max.
// ---------------------------------------------------------------------------
__global__ __launch_bounds__(256) void k_dmg(const unsigned short* __restrict__ xh,
    const unsigned short* __restrict__ xl, const float* __restrict__ sq,
    float* __restrict__ dm, float* __restrict__ dmax)
{
  __shared__ __align__(16) unsigned short S[4][96 * 64];   // 4 x 12KB = 48KB
  int b = blockIdx.y;
  int t = blockIdx.x, ti = 0, rl = 6;
  while (t >= rl) { t -= rl; ++ti; --rl; }
  int tj = ti + t;
  int tid = threadIdx.x;
  int wave = tid >> 6, lane = tid & 63;
  int wr = (wave >> 1) * 48, wc = (wave & 1) * 48;
  int mloc = lane & 15, quad = lane >> 4;
  size_t rowA = (size_t)b * N_ + ti * 96;
  size_t rowB = (size_t)b * N_ + tj * 96;

  const unsigned short* srcbase =
      (wave == 0) ? xh + rowA * D_ :
      (wave == 1) ? xl + rowA * D_ :
      (wave == 2) ? xh + rowB * D_ : xl + rowB * D_;
  int lrow = lane >> 3, lchunk = lane & 7;
  const unsigned short* gsrc0 = srcbase + (size_t)lrow * D_ + ((lchunk ^ lrow) * 8);
  unsigned short* lbase = &S[wave][0];

  floatx4 a1[3][3], a2[3][3];
#pragma unroll
  for (int i = 0; i < 3; ++i)
#pragma unroll
    for (int j = 0; j < 3; ++j) {
      a1[i][j] = (floatx4){0.f, 0.f, 0.f, 0.f};
      a2[i][j] = (floatx4){0.f, 0.f, 0.f, 0.f};
    }

  for (int kt = 0; kt < D_; kt += 64) {
    __syncthreads();
#pragma unroll
    for (int rb = 0; rb < 12; ++rb)
      gload_lds16(gsrc0 + (size_t)rb * 8 * D_ + kt, lbase + rb * 8 * 64);
    __syncthreads();
#pragma unroll
    for (int ks = 0; ks < 2; ++ks) {
      half8v ah[3], al[3], bh[3], bl[3];
      int cperm = (((ks << 2) | quad) ^ (mloc & 7)) * 8;
#pragma unroll
      for (int i = 0; i < 3; ++i) {
        int ro = (wr + i * 16 + mloc) * 64 + cperm;
        ah[i] = *(const half8v*)&S[0][ro];
        al[i] = *(const half8v*)&S[1][ro];
      }
#pragma unroll
      for (int j = 0; j < 3; ++j) {
        int ro = (wc + j * 16 + mloc) * 64 + cperm;
        bh[j] = *(const half8v*)&S[2][ro];
        bl[j] = *(const half8v*)&S[3][ro];
      }
#pragma unroll
      for (int i = 0; i < 3; ++i)
#pragma unroll
        for (int j = 0; j < 3; ++j) {
          a1[i][j] = __builtin_amdgcn_mfma_f32_16x16x32_f16(ah[i], bh[j], a1[i][j], 0, 0, 0);
          a2[i][j] = __builtin_amdgcn_mfma_f32_16x16x32_f16(ah[i], bl[j], a2[i][j], 0, 0, 0);
          a2[i][j] = __builtin_amdgcn_mfma_f32_16x16x32_f16(al[i], bh[j], a2[i][j], 0, 0, 0);
        }
    }
  }

  const float* sqb = sq + b * N_;
  float* dmb = dm + (size_t)b * N_ * N_;
  bool diag = (ti == tj);
  float vmax = 0.f;
#pragma unroll
  for (int j = 0; j < 3; ++j) {
    int gj = tj * 96 + wc + j * 16 + mloc;
    float sj = sqb[gj];
#pragma unroll
    for (int i = 0; i < 3; ++i) {
      int gi0 = ti * 96 + wr + i * 16 + quad * 4;
#pragma unroll
      for (int reg = 0; reg < 4; ++reg) {
        int gi = gi0 + reg;
        float g = a1[i][j][reg] + a2[i][j][reg] * LO_SCALE_;
        float d = sqb[gi] + sj - 2.0f * g;
        float v = sqrtf(fmaxf(d, 0.0f)) * INV_SQRT_D_;
        vmax = fmaxf(vmax, v);
        if (!diag || gj >= gi) {
          dmb[(size_t)gi * N_ + gj] = v;
          dmb[(size_t)gj * N_ + gi] = v;
        }
      }
    }
  }
#pragma unroll
  for (int msk = 32; msk >= 1; msk >>= 1) vmax = fmaxf(vmax, __shfl_xor(vmax, msk));
  if (lane == 0) atomicMax((unsigned int*)(dmax + b), __float_as_uint(vmax));
}

// ---------------------------------------------------------------------------
// K3: kNN density
// ---------------------------------------------------------------------------
__global__ __launch_bounds__(64) void k_density(const float* __restrict__ dm,
    const float* __restrict__ noise, float* __restrict__ den)
{
  int row = blockIdx.x, lane = threadIdx.x;
  const float* r = dm + (size_t)row * N_;
  float a0 = 1e30f, a1 = 1e30f, a2 = 1e30f, a3 = 1e30f, a4 = 1e30f;
  auto ins5 = [&](float xv) {
    a4 = fminf(a4, xv);
    float t;
    t = fminf(a3, a4); a4 = fmaxf(a3, a4); a3 = t;
    t = fminf(a2, a3); a3 = fmaxf(a2, a3); a2 = t;
    t = fminf(a1, a2); a2 = fmaxf(a1, a2); a1 = t;
    t = fminf(a0, a1); a1 = fmaxf(a0, a1); a0 = t;
  };
#pragma unroll
  for (int t = 0; t < 9; ++t) ins5(r[lane + 64 * t]);
  for (int m = 1; m < 64; m <<= 1) {
    float b0 = __shfl_xor(a0, m), b1 = __shfl_xor(a1, m), b2 = __shfl_xor(a2, m);
    float b3 = __shfl_xor(a3, m), b4 = __shfl_xor(a4, m);
    ins5(b0); ins5(b1); ins5(b2); ins5(b3); ins5(b4);
  }
  if (lane == 0) {
    float ms = (a0 * a0 + a1 * a1 + a2 * a2 + a3 * a3 + a4 * a4) * 0.2f;
    den[row] = expf(-ms) + noise[row] * 1e-6f;
  }
}

// ---------------------------------------------------------------------------
// K5: dist-to-higher-density + score
// ---------------------------------------------------------------------------
__global__ __launch_bounds__(64) void k_dist(const float* __restrict__ dm,
    const float* __restrict__ den, const float* __restrict__ dmax,
    float* __restrict__ score)
{
  int row = blockIdx.x, lane = threadIdx.x;
  int b = row / N_;
  float di = den[row], dx = dmax[b];
  const float* r = dm + (size_t)row * N_;
  const float* db = den + b * N_;
  float m = dx;
#pragma unroll
  for (int t = 0; t < 9; ++t) {
    int j = lane + 64 * t;
    float v = (db[j] > di) ? r[j] : dx;
    m = fminf(m, v);
  }
  for (int msk = 1; msk < 64; msk <<= 1) m = fminf(m, __shfl_xor(m, msk));
  if (lane == 0) score[row] = m * di;
}

// ---------------------------------------------------------------------------
// K6: top-64 scores per batch
// ---------------------------------------------------------------------------
__global__ __launch_bounds__(256) void k_topL(const float* __restrict__ score,
    int* __restrict__ idxd)
{
  int b = blockIdx.x, tid = threadIdx.x;
  __shared__ float s[N_];
  __shared__ float rv[256];
  __shared__ int   ri[256];
  for (int j = tid; j < N_; j += 256) s[j] = score[b * N_ + j];
  __syncthreads();
  for (int it = 0; it < L_; ++it) {
    float bv = -1e30f; int bi = 1 << 30;
    for (int j = tid; j < N_; j += 256) {
      float v = s[j];
      if (v > bv || (v == bv && j < bi)) { bv = v; bi = j; }
    }
    rv[tid] = bv; ri[tid] = bi; __syncthreads();
    for (int o = 128; o > 0; o >>= 1) {
      if (tid < o) {
        float v2 = rv[tid + o]; int i2 = ri[tid + o];
        if (v2 > rv[tid] || (v2 == rv[tid] && i2 < ri[tid])) { rv[tid] = v2; ri[tid] = i2; }
      }
      __syncthreads();
    }
    if (tid == 0) { idxd[b * L_ + it] = ri[0]; s[ri[0]] = -1e30f; }
    __syncthreads();
  }
}

// ---------------------------------------------------------------------------
// K7: assign tokens to nearest center (+ fused center self-assignment)
// ---------------------------------------------------------------------------
__global__ __launch_bounds__(576) void k_assign(const float* __restrict__ dm,
    const int* __restrict__ idxd, int* __restrict__ idxc)
{
  int b = blockIdx.x, n = threadIdx.x;
  __shared__ int ctr[L_];
  if (n < L_) ctr[n] = idxd[b * L_ + n];
  __syncthreads();
  const float* dmb = dm + (size_t)b * N_ * N_;
  float best = 1e30f; int bl = 0;
  for (int l = 0; l < L_; ++l) {
    float v = dmb[(size_t)ctr[l] * N_ + n];
    if (v < best) { best = v; bl = l; }
  }
  for (int l = 0; l < L_; ++l)
    if (ctr[l] == n) bl = l;
  idxc[b * N_ + n] = bl;
}

// ---------------------------------------------------------------------------
// K8: merger (gather form) — reconstructs xn = hi + lo*2^-11
// ---------------------------------------------------------------------------
__global__ __launch_bounds__(256) void k_merge(const unsigned short* __restrict__ xh,
    const unsigned short* __restrict__ xl,
    const float* __restrict__ ts, const int* __restrict__ idxc,
    float* __restrict__ qin)
{
  int blk = blockIdx.x;
  int b = blk >> 6, l = blk & 63;
  int tid = threadIdx.x;
  const int* ic = idxc + b * N_;
  const float* tsb = ts + b * N_;
  const unsigned short* xhb = xh + (size_t)b * N_ * D_;
  const unsigned short* xlb = xl + (size_t)b * N_ * D_;
  float a0 = 0.f, a1 = 0.f, a2 = 0.f, wsum = 0.f;
  for (int n = 0; n < N_; ++n) {
    if (ic[n] == l) {
      float w = expf(tsb[n]);
      wsum += w;
      const unsigned short* hr = xhb + (size_t)n * D_;
      const unsigned short* lr = xlb + (size_t)n * D_;
      float x0 = h2f(hr[tid      ]) + h2f(lr[tid      ]) * LO_SCALE_;
      float x1 = h2f(hr[tid + 256]) + h2f(lr[tid + 256]) * LO_SCALE_;
      float x2 = h2f(hr[tid + 512]) + h2f(lr[tid + 512]) * LO_SCALE_;
      a0 += w * x0; a1 += w * x1; a2 += w * x2;
    }
  }
  float inv = 1.0f / (wsum + 1e-6f);
  float* q = qin + (size_t)blk * D_;
  q[tid] = a0 * inv; q[tid + 256] = a1 * inv; q[tid + 512] = a2 * inv;
}

// ---------------------------------------------------------------------------
// Weight transpose + fp16 cast: W[K,N] fp32 -> WT[N,K] fp16
// ---------------------------------------------------------------------------
__global__ __launch_bounds__(256) void k_wt(const float* __restrict__ W,
    unsigned short* __restrict__ WT, int K, int N)
{
  __shared__ float t[32][33];
  int k0 = blockIdx.x * 32, n0 = blockIdx.y * 32;
  int tid = threadIdx.x;
  int r = tid >> 3, c4 = (tid & 7) * 4;
  float4 v = *(const float4*)(W + (size_t)(k0 + r) * N + n0 + c4);
  t[r][c4] = v.x; t[r][c4 + 1] = v.y; t[r][c4 + 2] = v.z; t[r][c4 + 3] = v.w;
  __syncthreads();
  ushort4 s4;
  s4.x = f2h(t[c4 + 0][r]); s4.y = f2h(t[c4 + 1][r]);
  s4.z = f2h(t[c4 + 2][r]); s4.w = f2h(t[c4 + 3][r]);
  *(ushort4*)(WT + (size_t)(n0 + r) * K + k0 + c4) = s4;
}

// ---------------------------------------------------------------------------
// MFMA GEMM: C[M,N] = epilogue(A[M,K] @ WT[N,K]^T), fp16 MFMA, fp32 accum.
// BK=64; As/Bs [128][64] (128B rows = full bank wrap) with XOR-chunk swizzle
// (chunk ^ row&7): fragment ds_read_b128 is 2-way = free (k_dmg pattern).
// B (and A when fp16) staged via global_load_lds with pre-swizzled source;
// fp32 A reg-staged directly into swizzled positions. MFMA order unchanged
// vs BK=32 version -> bit-identical outputs.
// ASRC 0: A fp32   1: A fp16
// EPI  0: fp16 out  1: +bias +res -> fp32 out  2: +bias, exact GELU -> fp16
// ---------------------------------------------------------------------------
template<int EPI, int ASRC>
__global__ __launch_bounds__(256) void k_mgemm(const void* __restrict__ Ap_,
    const unsigned short* __restrict__ Wt, const float* __restrict__ bias,
    const float* __restrict__ res, void* __restrict__ outp,
    int M, int Nd, int Kd)
{
  __shared__ __align__(16) unsigned short As[128 * 64];
  __shared__ __align__(16) unsigned short Bs[128 * 64];
  int tid = threadIdx.x;
  int bm = blockIdx.x * 128, bn = blockIdx.y * 128;
  int wave = tid >> 6, lane = tid & 63;
  int wr = (wave >> 1) * 64, wc = (wave & 1) * 64;
  int mloc = lane & 15, quad = lane >> 4;

  floatx4 acc[4][4];
#pragma unroll
  for (int i = 0; i < 4; ++i)
#pragma unroll
    for (int j = 0; j < 4; ++j)
      acc[i][j] = (floatx4){0.f, 0.f, 0.f, 0.f};

  // gload lane map: per 1KB load = 8 rows x 8 chunks; wave stages rows
  // [wave*32, wave*32+32) of its panel in 4 loads. Source chunk pre-swizzled.
  int lrow = lane >> 3, lchunk = lane & 7;
  const unsigned short* bsrc0 =
      Wt + (size_t)(bn + wave * 32 + lrow) * Kd + ((lchunk ^ lrow) * 8);
  unsigned short* bdst0 = &Bs[(wave * 32) * 64];
  const unsigned short* asrc0 = (ASRC == 1)
      ? (const unsigned short*)Ap_ + (size_t)(bm + wave * 32 + lrow) * Kd + ((lchunk ^ lrow) * 8)
      : nullptr;
  unsigned short* adst0 = &As[(wave * 32) * 64];

  for (int kt = 0; kt < Kd; kt += 64) {
    __syncthreads();
#pragma unroll
    for (int rb = 0; rb < 4; ++rb)
      gload_lds16(bsrc0 + (size_t)rb * 8 * Kd + kt, bdst0 + rb * 8 * 64);
    if (ASRC == 1) {
#pragma unroll
      for (int rb = 0; rb < 4; ++rb)
        gload_lds16(asrc0 + (size_t)rb * 8 * Kd + kt, adst0 + rb * 8 * 64);
    } else {
      const float* A = (const float*)Ap_;
#pragma unroll
      for (int it = 0; it < 4; ++it) {
        int idx = tid + it * 256;
        int r = idx >> 3, c = idx & 7;
        const float* ap = A + (size_t)(bm + r) * Kd + kt + c * 8;
        float4 f0 = *(const float4*)ap;
        float4 f1 = *(const float4*)(ap + 4);
        uint4 pk;
        pk.x = (unsigned)f2h(f0.x) | ((unsigned)f2h(f0.y) << 16);
        pk.y = (unsigned)f2h(f0.z) | ((unsigned)f2h(f0.w) << 16);
        pk.z = (unsigned)f2h(f1.x) | ((unsigned)f2h(f1.y) << 16);
        pk.w = (unsigned)f2h(f1.z) | ((unsigned)f2h(f1.w) << 16);
        *(uint4*)&As[r * 64 + ((c ^ (r & 7)) * 8)] = pk;
      }
    }
    __syncthreads();
#pragma unroll
    for (int ks = 0; ks < 2; ++ks) {
      half8v af[4], bf[4];
      int cperm = (((ks << 2) | quad) ^ (mloc & 7)) * 8;
#pragma unroll
      for (int i = 0; i < 4; ++i)
        af[i] = *(const half8v*)&As[(wr + i * 16 + mloc) * 64 + cperm];
#pragma unroll
      for (int j = 0; j < 4; ++j)
        bf[j] = *(const half8v*)&Bs[(wc + j * 16 + mloc) * 64 + cperm];
#pragma unroll
      for (int i = 0; i < 4; ++i)
#pragma unroll
        for (int j = 0; j < 4; ++j)
          acc[i][j] = __builtin_amdgcn_mfma_f32_16x16x32_f16(af[i], bf[j], acc[i][j], 0, 0, 0);
    }
  }

  float bv[4] = {0.f, 0.f, 0.f, 0.f};
  if (EPI >= 1) {
#pragma unroll
    for (int j = 0; j < 4; ++j) bv[j] = bias[bn + wc + j * 16 + mloc];
  }
#pragma unroll
  for (int i = 0; i < 4; ++i) {
    int gr0 = bm + wr + i * 16 + quad * 4;
#pragma unroll
    for (int j = 0; j < 4; ++j) {
      int gcn = bn + wc + j * 16 + mloc;
#pragma unroll
      for (int reg = 0; reg < 4; ++reg) {
        float v = acc[i][j][reg];
        size_t off = (size_t)(gr0 + reg) * Nd + gcn;
        if (EPI == 0) {
          ((unsigned short*)outp)[off] = f2h(v);
        } else if (EPI == 1) {
          ((float*)outp)[off] = v + bv[j] + res[off];
        } else {
          v += bv[j];
          v = 0.5f * v * (1.0f + erff(v * 0.70710678f));
          ((unsigned short*)outp)[off] = f2h(v);
        }
      }
    }
  }
}

// ---------------------------------------------------------------------------
// K12: MFMA flash cross-attention with token-score bias (all fp16 operands).
// K/V interleaved in one buffer, row stride 1536 (K at col h*96, V at 768+h*96)
// ---------------------------------------------------------------------------
__global__ __launch_bounds__(256) void k_attn(const unsigned short* __restrict__ Qu,
    const unsigned short* __restrict__ KVu, const float* __restrict__ ts,
    float* __restrict__ aout)
{
  __shared__ __align__(16) unsigned short Ks[64 * 104];
  __shared__ __align__(16) unsigned short VsT[96 * 64];
  __shared__ __align__(16) unsigned short sPa[64 * 64];
  __shared__ float tsb[64];
  int h = blockIdx.x, b = blockIdx.y;
  int tid = threadIdx.x;
  int wave = tid >> 6, lane = tid & 63;
  int mloc = lane & 15, quad = lane >> 4;

  half8v qf[3];
  {
    const unsigned short* qrow = Qu + (size_t)(b * 64 + wave * 16 + mloc) * D_ + h * 96 + quad * 8;
#pragma unroll
    for (int k = 0; k < 3; ++k) qf[k] = *(const half8v*)(qrow + k * 32);
  }

  floatx4 of[6];
#pragma unroll
  for (int dt = 0; dt < 6; ++dt) of[dt] = (floatx4){0.f, 0.f, 0.f, 0.f};
  float m[4], l[4];
#pragma unroll
  for (int r = 0; r < 4; ++r) { m[r] = -1e30f; l[r] = 0.f; }

  for (int jt = 0; jt < 9; ++jt) {
    int j0 = jt * 64;
    __syncthreads();
#pragma unroll
    for (int t = 0; t < 3; ++t) {
      int id = tid + t * 256;
      int row = id / 12, c = id % 12;
      *(uint4*)&Ks[row * 104 + c * 8] =
          *(const uint4*)(KVu + (size_t)(b * N_ + j0 + row) * KV_STRIDE_ + h * 96 + c * 8);
    }
#pragma unroll
    for (int t = 0; t < 3; ++t) {
      int id = tid + t * 256;
      int keyp = id & 31, dq = (id >> 5) * 4;
      int key = keyp * 2;
      const unsigned short* vp =
          KVu + (size_t)(b * N_ + j0 + key) * KV_STRIDE_ + 768 + h * 96 + dq;
      ushort4 v0 = *(const ushort4*)vp;
      ushort4 v1 = *(const ushort4*)(vp + KV_STRIDE_);
      unsigned pk0 = (unsigned)v0.x | ((unsigned)v1.x << 16);
      unsigned pk1 = (unsigned)v0.y | ((unsigned)v1.y << 16);
      unsigned pk2 = (unsigned)v0.z | ((unsigned)v1.z << 16);
      unsigned pk3 = (unsigned)v0.w | ((unsigned)v1.w << 16);
      int cbase = key >> 3, off = key & 7;
#pragma unroll
      for (int i = 0; i < 4; ++i) {
        int d = dq + i;
        unsigned pv = (i == 0) ? pk0 : (i == 1) ? pk1 : (i == 2) ? pk2 : pk3;
        *(unsigned*)&VsT[d * 64 + ((cbase ^ (d & 7)) << 3) + off] = pv;
      }
    }
    if (tid < 64) tsb[tid] = ts[b * N_ + j0 + tid];
    __syncthreads();

    floatx4 acc[4];
#pragma unroll
    for (int j = 0; j < 4; ++j) acc[j] = (floatx4){0.f, 0.f, 0.f, 0.f};
#pragma unroll
    for (int j = 0; j < 4; ++j)
#pragma unroll
      for (int k = 0; k < 3; ++k) {
        half8v kf = *(const half8v*)&Ks[(j * 16 + mloc) * 104 + k * 32 + quad * 8];
        acc[j] = __builtin_amdgcn_mfma_f32_16x16x32_f16(qf[k], kf, acc[j], 0, 0, 0);
      }

    float ts4[4];
#pragma unroll
    for (int j = 0; j < 4; ++j) ts4[j] = tsb[j * 16 + mloc];
    float rm[4] = {-1e30f, -1e30f, -1e30f, -1e30f};
#pragma unroll
    for (int j = 0; j < 4; ++j)
#pragma unroll
      for (int r = 0; r < 4; ++r) {
        acc[j][r] = acc[j][r] * SCALE_ + ts4[j];
        rm[r] = fmaxf(rm[r], acc[j][r]);
      }
#pragma unroll
    for (int r = 0; r < 4; ++r) {
      rm[r] = fmaxf(rm[r], __shfl_xor(rm[r], 1));
      rm[r] = fmaxf(rm[r], __shfl_xor(rm[r], 2));
      rm[r] = fmaxf(rm[r], __shfl_xor(rm[r], 4));
      rm[r] = fmaxf(rm[r], __shfl_xor(rm[r], 8));
    }
    float alpha[4], rs[4];
#pragma unroll
    for (int r = 0; r < 4; ++r) {
      float mn = fmaxf(m[r], rm[r]);
      alpha[r] = __expf(m[r] - mn);
      m[r] = mn;
      rs[r] = 0.f;
    }
#pragma unroll
    for (int j = 0; j < 4; ++j)
#pragma unroll
      for (int r = 0; r < 4; ++r) {
        float p = __expf(acc[j][r] - m[r]);
        acc[j][r] = p; rs[r] += p;
      }
#pragma unroll
    for (int r = 0; r < 4; ++r) {
      rs[r] += __shfl_xor(rs[r], 1); rs[r] += __shfl_xor(rs[r], 2);
      rs[r] += __shfl_xor(rs[r], 4); rs[r] += __shfl_xor(rs[r], 8);
      l[r] = l[r] * alpha[r] + rs[r];
    }
#pragma unroll
    for (int dt = 0; dt < 6; ++dt)
#pragma unroll
      for (int r = 0; r < 4; ++r) of[dt][r] *= alpha[r];

#pragma unroll
    for (int j = 0; j < 4; ++j)
#pragma unroll
      for (int r = 0; r < 4; ++r) {
        int row = wave * 16 + quad * 4 + r;
        int key = j * 16 + mloc;
        sPa[row * 64 + (((key >> 3) ^ (row & 7)) << 3) + (key & 7)] = f2h(acc[j][r]);
      }
    half8v pa[2];
    int prow = wave * 16 + mloc;
#pragma unroll
    for (int f2 = 0; f2 < 2; ++f2)
      pa[f2] = *(const half8v*)&sPa[prow * 64 + (((f2 * 4 + quad) ^ (prow & 7)) << 3)];
#pragma unroll
    for (int dt = 0; dt < 6; ++dt)
#pragma unroll
      for (int f2 = 0; f2 < 2; ++f2) {
        int vrow = dt * 16 + mloc;
        half8v vf = *(const half8v*)&VsT[vrow * 64 + (((f2 * 4 + quad) ^ (vrow & 7)) << 3)];
        of[dt] = __builtin_amdgcn_mfma_f32_16x16x32_f16(pa[f2], vf, of[dt], 0, 0, 0);
      }
  }

  float linv[4];
#pragma unroll
  for (int r = 0; r < 4; ++r) linv[r] = 1.0f / l[r];
#pragma unroll
  for (int dt = 0; dt < 6; ++dt)
#pragma unroll
    for (int r = 0; r < 4; ++r) {
      int row = b * 64 + wave * 16 + quad * 4 + r;
      int col = h * 96 + dt * 16 + mloc;
      aout[(size_t)row * D_ + col] = of[dt][r] * linv[r];
    }
}

// ---------------------------------------------------------------------------
// K14: LayerNorm2 (fp32 in -> fp32 out)
// ---------------------------------------------------------------------------
__global__ __launch_bounds__(256) void k_ln2(const float* __restrict__ f,
    const float* __restrict__ g, const float* __restrict__ bt, float* __restrict__ out)
{
  int row = blockIdx.x, tid = threadIdx.x;
  const float* fr = f + (size_t)row * D_;
  float v0 = fr[tid], v1 = fr[tid + 256], v2 = fr[tid + 512];
  __shared__ float r1[256], r2[256];
  r1[tid] = v0 + v1 + v2;
  r2[tid] = v0 * v0 + v1 * v1 + v2 * v2;
  __syncthreads();
  for (int o = 128; o > 0; o >>= 1) {
    if (tid < o) { r1[tid] += r1[tid + o]; r2[tid] += r2[tid + o]; }
    __syncthreads();
  }
  float mean = r1[0] * (1.0f / D_);
  float var  = r2[0] * (1.0f / D_) - mean * mean;
  float rstd = rsqrtf(var + 1e-5f);
  float* oo = out + (size_t)row * D_;
  oo[tid      ] = (v0 - mean) * rstd * g[tid      ] + bt[tid      ];
  oo[tid + 256] = (v1 - mean) * rstd * g[tid + 256] + bt[tid + 256];
  oo[tid + 512] = (v2 - mean) * rstd * g[tid + 512] + bt[tid + 512];
}

// ---------------------------------------------------------------------------
// Launch
// ---------------------------------------------------------------------------
extern "C" void kernel_launch(void* const* d_in, const int* in_sizes, int n_in,
                              void* d_out, int out_size, void* d_ws, size_t ws_size,
                              hipStream_t stream)
{
  (void)in_sizes; (void)n_in; (void)out_size; (void)ws_size;
  const float* x    = (const float*)d_in[0];
  const float* nois = (const float*)d_in[1];
  const float* n1g  = (const float*)d_in[2];
  const float* n1b  = (const float*)d_in[3];
  const float* sw   = (const float*)d_in[4];
  const float* sb   = (const float*)d_in[5];
  const float* wq   = (const float*)d_in[6];
  const float* wk   = (const float*)d_in[7];
  const float* wv   = (const float*)d_in[8];
  const float* pw   = (const float*)d_in[9];
  const float* pb   = (const float*)d_in[10];
  const float* n2g  = (const float*)d_in[11];
  const float* n2b  = (const float*)d_in[12];
  const float* f1w  = (const float*)d_in[13];
  const float* f1b  = (const float*)d_in[14];
  const float* f2w  = (const float*)d_in[15];
  const float* f2b  = (const float*)d_in[16];

  float* ws    = (float*)d_ws;
  unsigned short* XH = (unsigned short*)ws;                 // fp16 hi plane
  unsigned short* XL = XH + (size_t)NB_ * D_;               // fp16 lo plane
  float* RG    = ws + (size_t)NB_ * D_;
  float* QIN   = RG + (size_t)NB_ * D_;
  float* FEAT  = QIN + (size_t)ML_ * D_;
  float* AOUT  = FEAT + (size_t)ML_ * D_;
  float* QBUF  = AOUT + (size_t)ML_ * D_;
  float* P     = QBUF + (size_t)ML_ * D_;
  unsigned short* QH16 = (unsigned short*)P;  P += (size_t)ML_ * D_ / 2;
  unsigned short* WTQ  = (unsigned short*)P;  P += (size_t)D_ * D_ / 2;
  unsigned short* WTKV = (unsigned short*)P;  P += (size_t)D_ * D_;     // K then V
  unsigned short* WTP  = (unsigned short*)P;  P += (size_t)D_ * D_ / 2;
  unsigned short* WT1  = (unsigned short*)P;  P += (size_t)D_ * 4 * D_ / 2;
  unsigned short* WT2  = (unsigned short*)P;  P += (size_t)D_ * 4 * D_ / 2;
  float* TS    = P;
  float* SQ    = TS + NB_;
  float* DEN   = SQ + NB_;
  float* SCORE = DEN + NB_;
  float* DMAX  = SCORE + NB_;
  int*   IDXD  = (int*)(DMAX + 64);
  int*   IDXC  = IDXD + ML_;
  float* DM    = RG;                               // phase 1
  unsigned short* KVB = (unsigned short*)RG;       // phase 2: [NB_][1536] K|V
  unsigned short* HID = (unsigned short*)RG;       // phase 3

  hipMemsetAsync(DMAX, 0, 64 * sizeof(float), stream);
  k_wt<<<dim3(24, 24), 256, 0, stream>>>(wq, WTQ, D_, D_);
  k_wt<<<dim3(24, 24), 256, 0, stream>>>(wk, WTKV, D_, D_);
  k_wt<<<dim3(24, 24), 256, 0, stream>>>(wv, WTKV + (size_t)D_ * D_, D_, D_);
  k_wt<<<dim3(24, 24), 256, 0, stream>>>(pw, WTP, D_, D_);
  k_wt<<<dim3(24, 96), 256, 0, stream>>>(f1w, WT1, D_, 4 * D_);
  k_wt<<<dim3(96, 24), 256, 0, stream>>>(f2w, WT2, 4 * D_, D_);

  k_ln1<<<NB_, 256, 0, stream>>>(x, n1g, n1b, sw, sb, XH, XL, TS, SQ);
  k_dmg<<<dim3(21, B_), 256, 0, stream>>>(XH, XL, SQ, DM, DMAX);
  k_density<<<NB_, 64, 0, stream>>>(DM, nois, DEN);
  k_dist<<<NB_, 64, 0, stream>>>(DM, DEN, DMAX, SCORE);
  k_topL<<<B_, 256, 0, stream>>>(SCORE, IDXD);
  k_assign<<<B_, 576, 0, stream>>>(DM, IDXD, IDXC);
  k_merge<<<ML_, 256, 0, stream>>>(XH, XL, TS, IDXC, QIN);

  k_mgemm<0, 0><<<dim3(ML_ / 128, D_ / 128), 256, 0, stream>>>(
      QIN, WTQ, nullptr, nullptr, QH16, ML_, D_, D_);
  k_mgemm<0, 1><<<dim3(NB_ / 128, KV_STRIDE_ / 128), 256, 0, stream>>>(
      XH, WTKV, nullptr, nullptr, KVB, NB_, KV_STRIDE_, D_);
  k_attn<<<dim3(H_, B_), 256, 0, stream>>>(QH16, KVB, TS, AOUT);
  k_mgemm<1, 0><<<dim3(ML_ / 128, D_ / 128), 256, 0, stream>>>(
      AOUT, WTP, pb, QIN, FEAT, ML_, D_, D_);
  k_ln2<<<ML_, 256, 0, stream>>>(FEAT, n2g, n2b, QBUF);
  k_mgemm<2, 0><<<dim3(ML_ / 128, (4 * D_) / 128), 256, 0, stream>>>(
      QBUF, WT1, f1b, nullptr, HID, ML_, 4 * D_, D_);
  k_mgemm<1, 1><<<dim3(ML_ / 128, D_ / 128), 256, 0, stream>>>(
      HID, WT2, f2b, FEAT, d_out, ML_, D_, 4 * D_);
}

// Round 8
// 870.376 us; speedup vs baseline: 1.3578x; 1.0876x over previous
//
#include <hip/hip_runtime.h>
#include <math.h>

// Problem constants
#define B_   64
#define N_   576
#define D_   768
#define L_   64
#define H_   8
#define HD_  96
#define NB_  (B_*N_)    // 36864 rows
#define ML_  (B_*L_)    // 4096 rows
#define KV_STRIDE_ 1536
#define SCALE_ 0.10206207f          // 96^-0.5
#define INV_SQRT_D_ 0.03608439182f  // 1/sqrt(768)
#define LO_SCALE_ 4.8828125e-4f     // 2^-11

typedef __attribute__((ext_vector_type(8))) _Float16 half8v;    // 8 fp16 (4 VGPRs)
typedef __attribute__((ext_vector_type(4))) float floatx4;      // MFMA C/D

__device__ __forceinline__ unsigned short f2h(float f) {
  _Float16 h = (_Float16)f;
  unsigned short u; __builtin_memcpy(&u, &h, 2);
  return u;
}
__device__ __forceinline__ float h2f(unsigned short u) {
  _Float16 h; __builtin_memcpy(&h, &u, 2);
  return (float)h;
}
// async global->LDS, 16B/lane: HW writes lds_base + lane*16 (wave-uniform base),
// global source is per-lane.
__device__ __forceinline__ void gload_lds16(const void* g, void* l) {
  __builtin_amdgcn_global_load_lds(
      (const __attribute__((address_space(1))) unsigned*)g,
      (__attribute__((address_space(3))) unsigned*)l, 16, 0, 0);
}

// ---------------------------------------------------------------------------
// K1: LayerNorm1 -> fp16 hi/lo split planes + token_score + row sum-of-squares
// ---------------------------------------------------------------------------
__global__ __launch_bounds__(256) void k_ln1(const float* __restrict__ x,
    const float* __restrict__ g, const float* __restrict__ bt,
    const float* __restrict__ sw, const float* __restrict__ sb,
    unsigned short* __restrict__ xh, unsigned short* __restrict__ xl,
    float* __restrict__ ts, float* __restrict__ sq)
{
  int row = blockIdx.x, tid = threadIdx.x;
  const float* xr = x + (size_t)row * D_;
  float v0 = xr[tid], v1 = xr[tid + 256], v2 = xr[tid + 512];
  __shared__ float r1[256], r2[256];
  r1[tid] = v0 + v1 + v2;
  r2[tid] = v0 * v0 + v1 * v1 + v2 * v2;
  __syncthreads();
  for (int o = 128; o > 0; o >>= 1) {
    if (tid < o) { r1[tid] += r1[tid + o]; r2[tid] += r2[tid + o]; }
    __syncthreads();
  }
  float mean = r1[0] * (1.0f / D_);
  float var  = r2[0] * (1.0f / D_) - mean * mean;
  float rstd = rsqrtf(var + 1e-5f);
  __syncthreads();
  float o0 = (v0 - mean) * rstd * g[tid      ] + bt[tid      ];
  float o1 = (v1 - mean) * rstd * g[tid + 256] + bt[tid + 256];
  float o2 = (v2 - mean) * rstd * g[tid + 512] + bt[tid + 512];
  auto split = [](float o, unsigned short& hu, unsigned short& lu) {
    _Float16 h = (_Float16)o;
    float hf = (float)h;
    _Float16 l = (_Float16)((o - hf) * 2048.0f);
    __builtin_memcpy(&hu, &h, 2);
    __builtin_memcpy(&lu, &l, 2);
  };
  unsigned short h0, l0, h1, l1, h2, l2;
  split(o0, h0, l0); split(o1, h1, l1); split(o2, h2, l2);
  unsigned short* xho = xh + (size_t)row * D_;
  unsigned short* xlo = xl + (size_t)row * D_;
  xho[tid] = h0; xho[tid + 256] = h1; xho[tid + 512] = h2;
  xlo[tid] = l0; xlo[tid + 256] = l1; xlo[tid + 512] = l2;
  r1[tid] = o0 * sw[tid] + o1 * sw[tid + 256] + o2 * sw[tid + 512];
  r2[tid] = o0 * o0 + o1 * o1 + o2 * o2;
  __syncthreads();
  for (int o = 128; o > 0; o >>= 1) {
    if (tid < o) { r1[tid] += r1[tid + o]; r2[tid] += r2[tid + o]; }
    __syncthreads();
  }
  if (tid == 0) { ts[row] = r1[0] + sb[0]; sq[row] = r2[0]; }
}

// ---------------------------------------------------------------------------
// K2: pairwise distances via fp16x2 split-precision MFMA Gram.
// r7 structure (proven: 136us, 0 conflicts) + XCD batch-affinity swizzle ONLY:
// flat grid 1344 = 8 xcd groups; all 21 tiles of a batch land on one XCD so
// its L2 (4MB) holds the batch panels (1.77MB). Single-variable A/B vs r7;
// TRIPWIRE: WRITE_SIZE >= 300MB -> swizzle is the r4 write-amp culprit.
// ---------------------------------------------------------------------------
__global__ __launch_bounds__(256) void k_dmg(const unsigned short* __restrict__ xh,
    const unsigned short* __restrict__ xl, const float* __restrict__ sq,
    float* __restrict__ dm, float* __restrict__ dmax)
{
  __shared__ __align__(16) unsigned short S[4][96 * 64];   // 4 x 12KB = 48KB
  int flat = blockIdx.x;
  int xcd = flat & 7, seq = flat >> 3;
  int b = (seq / 21) * 8 + xcd;
  int t = seq % 21;
  int ti = 0, rl = 6;
  while (t >= rl) { t -= rl; ++ti; --rl; }
  int tj = ti + t;
  int tid = threadIdx.x;
  int wave = tid >> 6, lane = tid & 63;
  int wr = (wave >> 1) * 48, wc = (wave & 1) * 48;
  int mloc = lane & 15, quad = lane >> 4;
  size_t rowA = (size_t)b * N_ + ti * 96;
  size_t rowB = (size_t)b * N_ + tj * 96;

  const unsigned short* srcbase =
      (wave == 0) ? xh + rowA * D_ :
      (wave == 1) ? xl + rowA * D_ :
      (wave == 2) ? xh + rowB * D_ : xl + rowB * D_;
  int lrow = lane >> 3, lchunk = lane & 7;
  const unsigned short* gsrc0 = srcbase + (size_t)lrow * D_ + ((lchunk ^ lrow) * 8);
  unsigned short* lbase = &S[wave][0];

  floatx4 a1[3][3], a2[3][3];
#pragma unroll
  for (int i = 0; i < 3; ++i)
#pragma unroll
    for (int j = 0; j < 3; ++j) {
      a1[i][j] = (floatx4){0.f, 0.f, 0.f, 0.f};
      a2[i][j] = (floatx4){0.f, 0.f, 0.f, 0.f};
    }

  for (int kt = 0; kt < D_; kt += 64) {
    __syncthreads();
#pragma unroll
    for (int rb = 0; rb < 12; ++rb)
      gload_lds16(gsrc0 + (size_t)rb * 8 * D_ + kt, lbase + rb * 8 * 64);
    __syncthreads();
#pragma unroll
    for (int ks = 0; ks < 2; ++ks) {
      half8v ah[3], al[3], bh[3], bl[3];
      int cperm = (((ks << 2) | quad) ^ (mloc & 7)) * 8;
#pragma unroll
      for (int i = 0; i < 3; ++i) {
        int ro = (wr + i * 16 + mloc) * 64 + cperm;
        ah[i] = *(const half8v*)&S[0][ro];
        al[i] = *(const half8v*)&S[1][ro];
      }
#pragma unroll
      for (int j = 0; j < 3; ++j) {
        int ro = (wc + j * 16 + mloc) * 64 + cperm;
        bh[j] = *(const half8v*)&S[2][ro];
        bl[j] = *(const half8v*)&S[3][ro];
      }
#pragma unroll
      for (int i = 0; i < 3; ++i)
#pragma unroll
        for (int j = 0; j < 3; ++j) {
          a1[i][j] = __builtin_amdgcn_mfma_f32_16x16x32_f16(ah[i], bh[j], a1[i][j], 0, 0, 0);
          a2[i][j] = __builtin_amdgcn_mfma_f32_16x16x32_f16(ah[i], bl[j], a2[i][j], 0, 0, 0);
          a2[i][j] = __builtin_amdgcn_mfma_f32_16x16x32_f16(al[i], bh[j], a2[i][j], 0, 0, 0);
        }
    }
  }

  const float* sqb = sq + b * N_;
  float* dmb = dm + (size_t)b * N_ * N_;
  bool diag = (ti == tj);
  float vmax = 0.f;
#pragma unroll
  for (int j = 0; j < 3; ++j) {
    int gj = tj * 96 + wc + j * 16 + mloc;
    float sj = sqb[gj];
#pragma unroll
    for (int i = 0; i < 3; ++i) {
      int gi0 = ti * 96 + wr + i * 16 + quad * 4;
#pragma unroll
      for (int reg = 0; reg < 4; ++reg) {
        int gi = gi0 + reg;
        float g = a1[i][j][reg] + a2[i][j][reg] * LO_SCALE_;
        float d = sqb[gi] + sj - 2.0f * g;
        float v = sqrtf(fmaxf(d, 0.0f)) * INV_SQRT_D_;
        vmax = fmaxf(vmax, v);
        if (!diag || gj >= gi) {
          dmb[(size_t)gi * N_ + gj] = v;
          dmb[(size_t)gj * N_ + gi] = v;
        }
      }
    }
  }
#pragma unroll
  for (int msk = 32; msk >= 1; msk >>= 1) vmax = fmaxf(vmax, __shfl_xor(vmax, msk));
  if (lane == 0) atomicMax((unsigned int*)(dmax + b), __float_as_uint(vmax));
}

// ---------------------------------------------------------------------------
// K3: kNN density
// ---------------------------------------------------------------------------
__global__ __launch_bounds__(64) void k_density(const float* __restrict__ dm,
    const float* __restrict__ noise, float* __restrict__ den)
{
  int row = blockIdx.x, lane = threadIdx.x;
  const float* r = dm + (size_t)row * N_;
  float a0 = 1e30f, a1 = 1e30f, a2 = 1e30f, a3 = 1e30f, a4 = 1e30f;
  auto ins5 = [&](float xv) {
    a4 = fminf(a4, xv);
    float t;
    t = fminf(a3, a4); a4 = fmaxf(a3, a4); a3 = t;
    t = fminf(a2, a3); a3 = fmaxf(a2, a3); a2 = t;
    t = fminf(a1, a2); a2 = fmaxf(a1, a2); a1 = t;
    t = fminf(a0, a1); a1 = fmaxf(a0, a1); a0 = t;
  };
#pragma unroll
  for (int t = 0; t < 9; ++t) ins5(r[lane + 64 * t]);
  for (int m = 1; m < 64; m <<= 1) {
    float b0 = __shfl_xor(a0, m), b1 = __shfl_xor(a1, m), b2 = __shfl_xor(a2, m);
    float b3 = __shfl_xor(a3, m), b4 = __shfl_xor(a4, m);
    ins5(b0); ins5(b1); ins5(b2); ins5(b3); ins5(b4);
  }
  if (lane == 0) {
    float ms = (a0 * a0 + a1 * a1 + a2 * a2 + a3 * a3 + a4 * a4) * 0.2f;
    den[row] = expf(-ms) + noise[row] * 1e-6f;
  }
}

// ---------------------------------------------------------------------------
// K5: dist-to-higher-density + score
// ---------------------------------------------------------------------------
__global__ __launch_bounds__(64) void k_dist(const float* __restrict__ dm,
    const float* __restrict__ den, const float* __restrict__ dmax,
    float* __restrict__ score)
{
  int row = blockIdx.x, lane = threadIdx.x;
  int b = row / N_;
  float di = den[row], dx = dmax[b];
  const float* r = dm + (size_t)row * N_;
  const float* db = den + b * N_;
  float m = dx;
#pragma unroll
  for (int t = 0; t < 9; ++t) {
    int j = lane + 64 * t;
    float v = (db[j] > di) ? r[j] : dx;
    m = fminf(m, v);
  }
  for (int msk = 1; msk < 64; msk <<= 1) m = fminf(m, __shfl_xor(m, msk));
  if (lane == 0) score[row] = m * di;
}

// ---------------------------------------------------------------------------
// K6: top-64 scores per batch — bitonic sort of 1024 (576 real + pad) on
// (score desc, idx asc) full ordering; reproduces jax top_k tie-break.
// 55 barrier stages vs 576 barriers of the old 64x argmax sweep.
// ---------------------------------------------------------------------------
__global__ __launch_bounds__(256) void k_topL(const float* __restrict__ score,
    int* __restrict__ idxd)
{
  int b = blockIdx.x, tid = threadIdx.x;
  __shared__ float s[1024];
  __shared__ int   si[1024];
  for (int i = tid; i < 1024; i += 256) {
    s[i] = (i < N_) ? score[b * N_ + i] : -3.0e38f;
    si[i] = i;
  }
  __syncthreads();
  for (int k = 2; k <= 1024; k <<= 1) {
    for (int j = k >> 1; j > 0; j >>= 1) {
#pragma unroll
      for (int t = 0; t < 2; ++t) {
        int idx512 = tid + t * 256;          // 0..511 pair leaders
        int lo = idx512 & (j - 1);
        int i = ((idx512 ^ lo) << 1) | lo;   // (i & j) == 0
        int p = i | j;
        float as = s[i], bs = s[p];
        int ai = si[i], bi = si[p];
        // b_before_a in descending order (ties -> smaller idx first)
        bool bba = (bs > as) || (bs == as && bi < ai);
        bool up = ((i & k) == 0);
        bool dosw = up ? bba : !bba;
        if (dosw) { s[i] = bs; s[p] = as; si[i] = bi; si[p] = ai; }
      }
      __syncthreads();
    }
  }
  if (tid < L_) idxd[b * L_ + tid] = si[tid];
}

// ---------------------------------------------------------------------------
// K7: assign tokens to nearest center (+ fused center self-assignment)
// ---------------------------------------------------------------------------
__global__ __launch_bounds__(576) void k_assign(const float* __restrict__ dm,
    const int* __restrict__ idxd, int* __restrict__ idxc)
{
  int b = blockIdx.x, n = threadIdx.x;
  __shared__ int ctr[L_];
  if (n < L_) ctr[n] = idxd[b * L_ + n];
  __syncthreads();
  const float* dmb = dm + (size_t)b * N_ * N_;
  float best = 1e30f; int bl = 0;
  for (int l = 0; l < L_; ++l) {
    float v = dmb[(size_t)ctr[l] * N_ + n];
    if (v < best) { best = v; bl = l; }
  }
  for (int l = 0; l < L_; ++l)
    if (ctr[l] == n) bl = l;
  idxc[b * N_ + n] = bl;
}

// ---------------------------------------------------------------------------
// K8: merger (gather form) — reconstructs xn = hi + lo*2^-11
// ---------------------------------------------------------------------------
__global__ __launch_bounds__(256) void k_merge(const unsigned short* __restrict__ xh,
    const unsigned short* __restrict__ xl,
    const float* __restrict__ ts, const int* __restrict__ idxc,
    float* __restrict__ qin)
{
  int blk = blockIdx.x;
  int b = blk >> 6, l = blk & 63;
  int tid = threadIdx.x;
  const int* ic = idxc + b * N_;
  const float* tsb = ts + b * N_;
  const unsigned short* xhb = xh + (size_t)b * N_ * D_;
  const unsigned short* xlb = xl + (size_t)b * N_ * D_;
  float a0 = 0.f, a1 = 0.f, a2 = 0.f, wsum = 0.f;
  for (int n = 0; n < N_; ++n) {
    if (ic[n] == l) {
      float w = expf(tsb[n]);
      wsum += w;
      const unsigned short* hr = xhb + (size_t)n * D_;
      const unsigned short* lr = xlb + (size_t)n * D_;
      float x0 = h2f(hr[tid      ]) + h2f(lr[tid      ]) * LO_SCALE_;
      float x1 = h2f(hr[tid + 256]) + h2f(lr[tid + 256]) * LO_SCALE_;
      float x2 = h2f(hr[tid + 512]) + h2f(lr[tid + 512]) * LO_SCALE_;
      a0 += w * x0; a1 += w * x1; a2 += w * x2;
    }
  }
  float inv = 1.0f / (wsum + 1e-6f);
  float* q = qin + (size_t)blk * D_;
  q[tid] = a0 * inv; q[tid + 256] = a1 * inv; q[tid + 512] = a2 * inv;
}

// ---------------------------------------------------------------------------
// Weight transpose + fp16 cast: W[K,N] fp32 -> WT[N,K] fp16
// ---------------------------------------------------------------------------
__global__ __launch_bounds__(256) void k_wt(const float* __restrict__ W,
    unsigned short* __restrict__ WT, int K, int N)
{
  __shared__ float t[32][33];
  int k0 = blockIdx.x * 32, n0 = blockIdx.y * 32;
  int tid = threadIdx.x;
  int r = tid >> 3, c4 = (tid & 7) * 4;
  float4 v = *(const float4*)(W + (size_t)(k0 + r) * N + n0 + c4);
  t[r][c4] = v.x; t[r][c4 + 1] = v.y; t[r][c4 + 2] = v.z; t[r][c4 + 3] = v.w;
  __syncthreads();
  ushort4 s4;
  s4.x = f2h(t[c4 + 0][r]); s4.y = f2h(t[c4 + 1][r]);
  s4.z = f2h(t[c4 + 2][r]); s4.w = f2h(t[c4 + 3][r]);
  *(ushort4*)(WT + (size_t)(n0 + r) * K + k0 + c4) = s4;
}

// ---------------------------------------------------------------------------
// MFMA GEMM: C[M,N] = epilogue(A[M,K] @ WT[N,K]^T), fp16 MFMA, fp32 accum.
// BK=64; As/Bs [128][64] (128B rows) with XOR-chunk swizzle (chunk ^ row&7).
// B (and A when fp16) staged via global_load_lds with pre-swizzled source;
// fp32 A reg-staged directly into swizzled positions.
// ASRC 0: A fp32   1: A fp16
// EPI  0: fp16 out  1: +bias +res -> fp32 out  2: +bias, exact GELU -> fp16
// ---------------------------------------------------------------------------
template<int EPI, int ASRC>
__global__ __launch_bounds__(256) void k_mgemm(const void* __restrict__ Ap_,
    const unsigned short* __restrict__ Wt, const float* __restrict__ bias,
    const float* __restrict__ res, void* __restrict__ outp,
    int M, int Nd, int Kd)
{
  __shared__ __align__(16) unsigned short As[128 * 64];
  __shared__ __align__(16) unsigned short Bs[128 * 64];
  int tid = threadIdx.x;
  int bm = blockIdx.x * 128, bn = blockIdx.y * 128;
  int wave = tid >> 6, lane = tid & 63;
  int wr = (wave >> 1) * 64, wc = (wave & 1) * 64;
  int mloc = lane & 15, quad = lane >> 4;

  floatx4 acc[4][4];
#pragma unroll
  for (int i = 0; i < 4; ++i)
#pragma unroll
    for (int j = 0; j < 4; ++j)
      acc[i][j] = (floatx4){0.f, 0.f, 0.f, 0.f};

  int lrow = lane >> 3, lchunk = lane & 7;
  const unsigned short* bsrc0 =
      Wt + (size_t)(bn + wave * 32 + lrow) * Kd + ((lchunk ^ lrow) * 8);
  unsigned short* bdst0 = &Bs[(wave * 32) * 64];
  const unsigned short* asrc0 = (ASRC == 1)
      ? (const unsigned short*)Ap_ + (size_t)(bm + wave * 32 + lrow) * Kd + ((lchunk ^ lrow) * 8)
      : nullptr;
  unsigned short* adst0 = &As[(wave * 32) * 64];

  for (int kt = 0; kt < Kd; kt += 64) {
    __syncthreads();
#pragma unroll
    for (int rb = 0; rb < 4; ++rb)
      gload_lds16(bsrc0 + (size_t)rb * 8 * Kd + kt, bdst0 + rb * 8 * 64);
    if (ASRC == 1) {
#pragma unroll
      for (int rb = 0; rb < 4; ++rb)
        gload_lds16(asrc0 + (size_t)rb * 8 * Kd + kt, adst0 + rb * 8 * 64);
    } else {
      const float* A = (const float*)Ap_;
#pragma unroll
      for (int it = 0; it < 4; ++it) {
        int idx = tid + it * 256;
        int r = idx >> 3, c = idx & 7;
        const float* ap = A + (size_t)(bm + r) * Kd + kt + c * 8;
        float4 f0 = *(const float4*)ap;
        float4 f1 = *(const float4*)(ap + 4);
        uint4 pk;
        pk.x = (unsigned)f2h(f0.x) | ((unsigned)f2h(f0.y) << 16);
        pk.y = (unsigned)f2h(f0.z) | ((unsigned)f2h(f0.w) << 16);
        pk.z = (unsigned)f2h(f1.x) | ((unsigned)f2h(f1.y) << 16);
        pk.w = (unsigned)f2h(f1.z) | ((unsigned)f2h(f1.w) << 16);
        *(uint4*)&As[r * 64 + ((c ^ (r & 7)) * 8)] = pk;
      }
    }
    __syncthreads();
#pragma unroll
    for (int ks = 0; ks < 2; ++ks) {
      half8v af[4], bf[4];
      int cperm = (((ks << 2) | quad) ^ (mloc & 7)) * 8;
#pragma unroll
      for (int i = 0; i < 4; ++i)
        af[i] = *(const half8v*)&As[(wr + i * 16 + mloc) * 64 + cperm];
#pragma unroll
      for (int j = 0; j < 4; ++j)
        bf[j] = *(const half8v*)&Bs[(wc + j * 16 + mloc) * 64 + cperm];
#pragma unroll
      for (int i = 0; i < 4; ++i)
#pragma unroll
        for (int j = 0; j < 4; ++j)
          acc[i][j] = __builtin_amdgcn_mfma_f32_16x16x32_f16(af[i], bf[j], acc[i][j], 0, 0, 0);
    }
  }

  float bv[4] = {0.f, 0.f, 0.f, 0.f};
  if (EPI >= 1) {
#pragma unroll
    for (int j = 0; j < 4; ++j) bv[j] = bias[bn + wc + j * 16 + mloc];
  }
#pragma unroll
  for (int i = 0; i < 4; ++i) {
    int gr0 = bm + wr + i * 16 + quad * 4;
#pragma unroll
    for (int j = 0; j < 4; ++j) {
      int gcn = bn + wc + j * 16 + mloc;
#pragma unroll
      for (int reg = 0; reg < 4; ++reg) {
        float v = acc[i][j][reg];
        size_t off = (size_t)(gr0 + reg) * Nd + gcn;
        if (EPI == 0) {
          ((unsigned short*)outp)[off] = f2h(v);
        } else if (EPI == 1) {
          ((float*)outp)[off] = v + bv[j] + res[off];
        } else {
          v += bv[j];
          v = 0.5f * v * (1.0f + erff(v * 0.70710678f));
          ((unsigned short*)outp)[off] = f2h(v);
        }
      }
    }
  }
}

// ---------------------------------------------------------------------------
// K12: MFMA flash cross-attention with token-score bias (all fp16 operands).
// K/V interleaved in one buffer, row stride 1536 (K at col h*96, V at 768+h*96)
// ---------------------------------------------------------------------------
__global__ __launch_bounds__(256) void k_attn(const unsigned short* __restrict__ Qu,
    const unsigned short* __restrict__ KVu, const float* __restrict__ ts,
    float* __restrict__ aout)
{
  __shared__ __align__(16) unsigned short Ks[64 * 104];
  __shared__ __align__(16) unsigned short VsT[96 * 64];
  __shared__ __align__(16) unsigned short sPa[64 * 64];
  __shared__ float tsb[64];
  int h = blockIdx.x, b = blockIdx.y;
  int tid = threadIdx.x;
  int wave = tid >> 6, lane = tid & 63;
  int mloc = lane & 15, quad = lane >> 4;

  half8v qf[3];
  {
    const unsigned short* qrow = Qu + (size_t)(b * 64 + wave * 16 + mloc) * D_ + h * 96 + quad * 8;
#pragma unroll
    for (int k = 0; k < 3; ++k) qf[k] = *(const half8v*)(qrow + k * 32);
  }

  floatx4 of[6];
#pragma unroll
  for (int dt = 0; dt < 6; ++dt) of[dt] = (floatx4){0.f, 0.f, 0.f, 0.f};
  float m[4], l[4];
#pragma unroll
  for (int r = 0; r < 4; ++r) { m[r] = -1e30f; l[r] = 0.f; }

  for (int jt = 0; jt < 9; ++jt) {
    int j0 = jt * 64;
    __syncthreads();
#pragma unroll
    for (int t = 0; t < 3; ++t) {
      int id = tid + t * 256;
      int row = id / 12, c = id % 12;
      *(uint4*)&Ks[row * 104 + c * 8] =
          *(const uint4*)(KVu + (size_t)(b * N_ + j0 + row) * KV_STRIDE_ + h * 96 + c * 8);
    }
#pragma unroll
    for (int t = 0; t < 3; ++t) {
      int id = tid + t * 256;
      int keyp = id & 31, dq = (id >> 5) * 4;
      int key = keyp * 2;
      const unsigned short* vp =
          KVu + (size_t)(b * N_ + j0 + key) * KV_STRIDE_ + 768 + h * 96 + dq;
      ushort4 v0 = *(const ushort4*)vp;
      ushort4 v1 = *(const ushort4*)(vp + KV_STRIDE_);
      unsigned pk0 = (unsigned)v0.x | ((unsigned)v1.x << 16);
      unsigned pk1 = (unsigned)v0.y | ((unsigned)v1.y << 16);
      unsigned pk2 = (unsigned)v0.z | ((unsigned)v1.z << 16);
      unsigned pk3 = (unsigned)v0.w | ((unsigned)v1.w << 16);
      int cbase = key >> 3, off = key & 7;
#pragma unroll
      for (int i = 0; i < 4; ++i) {
        int d = dq + i;
        unsigned pv = (i == 0) ? pk0 : (i == 1) ? pk1 : (i == 2) ? pk2 : pk3;
        *(unsigned*)&VsT[d * 64 + ((cbase ^ (d & 7)) << 3) + off] = pv;
      }
    }
    if (tid < 64) tsb[tid] = ts[b * N_ + j0 + tid];
    __syncthreads();

    floatx4 acc[4];
#pragma unroll
    for (int j = 0; j < 4; ++j) acc[j] = (floatx4){0.f, 0.f, 0.f, 0.f};
#pragma unroll
    for (int j = 0; j < 4; ++j)
#pragma unroll
      for (int k = 0; k < 3; ++k) {
        half8v kf = *(const half8v*)&Ks[(j * 16 + mloc) * 104 + k * 32 + quad * 8];
        acc[j] = __builtin_amdgcn_mfma_f32_16x16x32_f16(qf[k], kf, acc[j], 0, 0, 0);
      }

    float ts4[4];
#pragma unroll
    for (int j = 0; j < 4; ++j) ts4[j] = tsb[j * 16 + mloc];
    float rm[4] = {-1e30f, -1e30f, -1e30f, -1e30f};
#pragma unroll
    for (int j = 0; j < 4; ++j)
#pragma unroll
      for (int r = 0; r < 4; ++r) {
        acc[j][r] = acc[j][r] * SCALE_ + ts4[j];
        rm[r] = fmaxf(rm[r], acc[j][r]);
      }
#pragma unroll
    for (int r = 0; r < 4; ++r) {
      rm[r] = fmaxf(rm[r], __shfl_xor(rm[r], 1));
      rm[r] = fmaxf(rm[r], __shfl_xor(rm[r], 2));
      rm[r] = fmaxf(rm[r], __shfl_xor(rm[r], 4));
      rm[r] = fmaxf(rm[r], __shfl_xor(rm[r], 8));
    }
    float alpha[4], rs[4];
#pragma unroll
    for (int r = 0; r < 4; ++r) {
      float mn = fmaxf(m[r], rm[r]);
      alpha[r] = __expf(m[r] - mn);
      m[r] = mn;
      rs[r] = 0.f;
    }
#pragma unroll
    for (int j = 0; j < 4; ++j)
#pragma unroll
      for (int r = 0; r < 4; ++r) {
        float p = __expf(acc[j][r] - m[r]);
        acc[j][r] = p; rs[r] += p;
      }
#pragma unroll
    for (int r = 0; r < 4; ++r) {
      rs[r] += __shfl_xor(rs[r], 1); rs[r] += __shfl_xor(rs[r], 2);
      rs[r] += __shfl_xor(rs[r], 4); rs[r] += __shfl_xor(rs[r], 8);
      l[r] = l[r] * alpha[r] + rs[r];
    }
#pragma unroll
    for (int dt = 0; dt < 6; ++dt)
#pragma unroll
      for (int r = 0; r < 4; ++r) of[dt][r] *= alpha[r];

#pragma unroll
    for (int j = 0; j < 4; ++j)
#pragma unroll
      for (int r = 0; r < 4; ++r) {
        int row = wave * 16 + quad * 4 + r;
        int key = j * 16 + mloc;
        sPa[row * 64 + (((key >> 3) ^ (row & 7)) << 3) + (key & 7)] = f2h(acc[j][r]);
      }
    half8v pa[2];
    int prow = wave * 16 + mloc;
#pragma unroll
    for (int f2 = 0; f2 < 2; ++f2)
      pa[f2] = *(const half8v*)&sPa[prow * 64 + (((f2 * 4 + quad) ^ (prow & 7)) << 3)];
#pragma unroll
    for (int dt = 0; dt < 6; ++dt)
#pragma unroll
      for (int f2 = 0; f2 < 2; ++f2) {
        int vrow = dt * 16 + mloc;
        half8v vf = *(const half8v*)&VsT[vrow * 64 + (((f2 * 4 + quad) ^ (vrow & 7)) << 3)];
        of[dt] = __builtin_amdgcn_mfma_f32_16x16x32_f16(pa[f2], vf, of[dt], 0, 0, 0);
      }
  }

  float linv[4];
#pragma unroll
  for (int r = 0; r < 4; ++r) linv[r] = 1.0f / l[r];
#pragma unroll
  for (int dt = 0; dt < 6; ++dt)
#pragma unroll
    for (int r = 0; r < 4; ++r) {
      int row = b * 64 + wave * 16 + quad * 4 + r;
      int col = h * 96 + dt * 16 + mloc;
      aout[(size_t)row * D_ + col] = of[dt][r] * linv[r];
    }
}

// ---------------------------------------------------------------------------
// K14: LayerNorm2 (fp32 in -> fp32 out)
// ---------------------------------------------------------------------------
__global__ __launch_bounds__(256) void k_ln2(const float* __restrict__ f,
    const float* __restrict__ g, const float* __restrict__ bt, float* __restrict__ out)
{
  int row = blockIdx.x, tid = threadIdx.x;
  const float* fr = f + (size_t)row * D_;
  float v0 = fr[tid], v1 = fr[tid + 256], v2 = fr[tid + 512];
  __shared__ float r1[256], r2[256];
  r1[tid] = v0 + v1 + v2;
  r2[tid] = v0 * v0 + v1 * v1 + v2 * v2;
  __syncthreads();
  for (int o = 128; o > 0; o >>= 1) {
    if (tid < o) { r1[tid] += r1[tid + o]; r2[tid] += r2[tid + o]; }
    __syncthreads();
  }
  float mean = r1[0] * (1.0f / D_);
  float var  = r2[0] * (1.0f / D_) - mean * mean;
  float rstd = rsqrtf(var + 1e-5f);
  float* oo = out + (size_t)row * D_;
  oo[tid      ] = (v0 - mean) * rstd * g[tid      ] + bt[tid      ];
  oo[tid + 256] = (v1 - mean) * rstd * g[tid + 256] + bt[tid + 256];
  oo[tid + 512] = (v2 - mean) * rstd * g[tid + 512] + bt[tid + 512];
}

// ---------------------------------------------------------------------------
// Launch
// ---------------------------------------------------------------------------
extern "C" void kernel_launch(void* const* d_in, const int* in_sizes, int n_in,
                              void* d_out, int out_size, void* d_ws, size_t ws_size,
                              hipStream_t stream)
{
  (void)in_sizes; (void)n_in; (void)out_size; (void)ws_size;
  const float* x    = (const float*)d_in[0];
  const float* nois = (const float*)d_in[1];
  const float* n1g  = (const float*)d_in[2];
  const float* n1b  = (const float*)d_in[3];
  const float* sw   = (const float*)d_in[4];
  const float* sb   = (const float*)d_in[5];
  const float* wq   = (const float*)d_in[6];
  const float* wk   = (const float*)d_in[7];
  const float* wv   = (const float*)d_in[8];
  const float* pw   = (const float*)d_in[9];
  const float* pb   = (const float*)d_in[10];
  const float* n2g  = (const float*)d_in[11];
  const float* n2b  = (const float*)d_in[12];
  const float* f1w  = (const float*)d_in[13];
  const float* f1b  = (const float*)d_in[14];
  const float* f2w  = (const float*)d_in[15];
  const float* f2b  = (const float*)d_in[16];

  float* ws    = (float*)d_ws;
  unsigned short* XH = (unsigned short*)ws;                 // fp16 hi plane
  unsigned short* XL = XH + (size_t)NB_ * D_;               // fp16 lo plane
  float* RG    = ws + (size_t)NB_ * D_;
  float* QIN   = RG + (size_t)NB_ * D_;
  float* FEAT  = QIN + (size_t)ML_ * D_;
  float* AOUT  = FEAT + (size_t)ML_ * D_;
  float* QBUF  = AOUT + (size_t)ML_ * D_;
  float* P     = QBUF + (size_t)ML_ * D_;
  unsigned short* QH16 = (unsigned short*)P;  P += (size_t)ML_ * D_ / 2;
  unsigned short* WTQ  = (unsigned short*)P;  P += (size_t)D_ * D_ / 2;
  unsigned short* WTKV = (unsigned short*)P;  P += (size_t)D_ * D_;     // K then V
  unsigned short* WTP  = (unsigned short*)P;  P += (size_t)D_ * D_ / 2;
  unsigned short* WT1  = (unsigned short*)P;  P += (size_t)D_ * 4 * D_ / 2;
  unsigned short* WT2  = (unsigned short*)P;  P += (size_t)D_ * 4 * D_ / 2;
  float* TS    = P;
  float* SQ    = TS + NB_;
  float* DEN   = SQ + NB_;
  float* SCORE = DEN + NB_;
  float* DMAX  = SCORE + NB_;
  int*   IDXD  = (int*)(DMAX + 64);
  int*   IDXC  = IDXD + ML_;
  float* DM    = RG;                               // phase 1
  unsigned short* KVB = (unsigned short*)RG;       // phase 2: [NB_][1536] K|V
  unsigned short* HID = (unsigned short*)RG;       // phase 3

  hipMemsetAsync(DMAX, 0, 64 * sizeof(float), stream);
  k_wt<<<dim3(24, 24), 256, 0, stream>>>(wq, WTQ, D_, D_);
  k_wt<<<dim3(24, 24), 256, 0, stream>>>(wk, WTKV, D_, D_);
  k_wt<<<dim3(24, 24), 256, 0, stream>>>(wv, WTKV + (size_t)D_ * D_, D_, D_);
  k_wt<<<dim3(24, 24), 256, 0, stream>>>(pw, WTP, D_, D_);
  k_wt<<<dim3(24, 96), 256, 0, stream>>>(f1w, WT1, D_, 4 * D_);
  k_wt<<<dim3(96, 24), 256, 0, stream>>>(f2w, WT2, 4 * D_, D_);

  k_ln1<<<NB_, 256, 0, stream>>>(x, n1g, n1b, sw, sb, XH, XL, TS, SQ);
  k_dmg<<<1344, 256, 0, stream>>>(XH, XL, SQ, DM, DMAX);
  k_density<<<NB_, 64, 0, stream>>>(DM, nois, DEN);
  k_dist<<<NB_, 64, 0, stream>>>(DM, DEN, DMAX, SCORE);
  k_topL<<<B_, 256, 0, stream>>>(SCORE, IDXD);
  k_assign<<<B_, 576, 0, stream>>>(DM, IDXD, IDXC);
  k_merge<<<ML_, 256, 0, stream>>>(XH, XL, TS, IDXC, QIN);

  k_mgemm<0, 0><<<dim3(ML_ / 128, D_ / 128), 256, 0, stream>>>(
      QIN, WTQ, nullptr, nullptr, QH16, ML_, D_, D_);
  k_mgemm<0, 1><<<dim3(NB_ / 128, KV_STRIDE_ / 128), 256, 0, stream>>>(
      XH, WTKV, nullptr, nullptr, KVB, NB_, KV_STRIDE_, D_);
  k_attn<<<dim3(H_, B_), 256, 0, stream>>>(QH16, KVB, TS, AOUT);
  k_mgemm<1, 0><<<dim3(ML_ / 128, D_ / 128), 256, 0, stream>>>(
      AOUT, WTP, pb, QIN, FEAT, ML_, D_, D_);
  k_ln2<<<ML_, 256, 0, stream>>>(FEAT, n2g, n2b, QBUF);
  k_mgemm<2, 0><<<dim3(ML_ / 128, (4 * D_) / 128), 256, 0, stream>>>(
      QBUF, WT1, f1b, nullptr, HID, ML_, 4 * D_, D_);
  k_mgemm<1, 1><<<dim3(ML_ / 128, D_ / 128), 256, 0, stream>>>(
      HID, WT2, f2b, FEAT, d_out, ML_, D_, 4 * D_);
}

// Round 9
// 826.700 us; speedup vs baseline: 1.4295x; 1.0528x over previous
//
#include <hip/hip_runtime.h>
#include <math.h>

// Problem constants
#define B_   64
#define N_   576
#define D_   768
#define L_   64
#define H_   8
#define HD_  96
#define NB_  (B_*N_)    // 36864 rows
#define ML_  (B_*L_)    // 4096 rows
#define KV_STRIDE_ 1536
#define SCALE_ 0.10206207f          // 96^-0.5
#define INV_SQRT_D_ 0.03608439182f  // 1/sqrt(768)
#define LO_SCALE_ 4.8828125e-4f     // 2^-11

typedef __attribute__((ext_vector_type(8))) _Float16 half8v;    // 8 fp16 (4 VGPRs)
typedef __attribute__((ext_vector_type(4))) float floatx4;      // MFMA C/D

__device__ __forceinline__ unsigned short f2h(float f) {
  _Float16 h = (_Float16)f;
  unsigned short u; __builtin_memcpy(&u, &h, 2);
  return u;
}
__device__ __forceinline__ float h2f(unsigned short u) {
  _Float16 h; __builtin_memcpy(&h, &u, 2);
  return (float)h;
}
// async global->LDS, 16B/lane: HW writes lds_base + lane*16 (wave-uniform base),
// global source is per-lane.
__device__ __forceinline__ void gload_lds16(const void* g, void* l) {
  __builtin_amdgcn_global_load_lds(
      (const __attribute__((address_space(1))) unsigned*)g,
      (__attribute__((address_space(3))) unsigned*)l, 16, 0, 0);
}

// ---------------------------------------------------------------------------
// K1: LayerNorm1 -> fp16 hi/lo split planes + token_score + row sum-of-squares
// ---------------------------------------------------------------------------
__global__ __launch_bounds__(256) void k_ln1(const float* __restrict__ x,
    const float* __restrict__ g, const float* __restrict__ bt,
    const float* __restrict__ sw, const float* __restrict__ sb,
    unsigned short* __restrict__ xh, unsigned short* __restrict__ xl,
    float* __restrict__ ts, float* __restrict__ sq)
{
  int row = blockIdx.x, tid = threadIdx.x;
  const float* xr = x + (size_t)row * D_;
  float v0 = xr[tid], v1 = xr[tid + 256], v2 = xr[tid + 512];
  __shared__ float r1[256], r2[256];
  r1[tid] = v0 + v1 + v2;
  r2[tid] = v0 * v0 + v1 * v1 + v2 * v2;
  __syncthreads();
  for (int o = 128; o > 0; o >>= 1) {
    if (tid < o) { r1[tid] += r1[tid + o]; r2[tid] += r2[tid + o]; }
    __syncthreads();
  }
  float mean = r1[0] * (1.0f / D_);
  float var  = r2[0] * (1.0f / D_) - mean * mean;
  float rstd = rsqrtf(var + 1e-5f);
  __syncthreads();
  float o0 = (v0 - mean) * rstd * g[tid      ] + bt[tid      ];
  float o1 = (v1 - mean) * rstd * g[tid + 256] + bt[tid + 256];
  float o2 = (v2 - mean) * rstd * g[tid + 512] + bt[tid + 512];
  auto split = [](float o, unsigned short& hu, unsigned short& lu) {
    _Float16 h = (_Float16)o;
    float hf = (float)h;
    _Float16 l = (_Float16)((o - hf) * 2048.0f);
    __builtin_memcpy(&hu, &h, 2);
    __builtin_memcpy(&lu, &l, 2);
  };
  unsigned short h0, l0, h1, l1, h2, l2;
  split(o0, h0, l0); split(o1, h1, l1); split(o2, h2, l2);
  unsigned short* xho = xh + (size_t)row * D_;
  unsigned short* xlo = xl + (size_t)row * D_;
  xho[tid] = h0; xho[tid + 256] = h1; xho[tid + 512] = h2;
  xlo[tid] = l0; xlo[tid + 256] = l1; xlo[tid + 512] = l2;
  r1[tid] = o0 * sw[tid] + o1 * sw[tid + 256] + o2 * sw[tid + 512];
  r2[tid] = o0 * o0 + o1 * o1 + o2 * o2;
  __syncthreads();
  for (int o = 128; o > 0; o >>= 1) {
    if (tid < o) { r1[tid] += r1[tid + o]; r2[tid] += r2[tid + o]; }
    __syncthreads();
  }
  if (tid == 0) { ts[row] = r1[0] + sb[0]; sq[row] = r2[0]; }
}

// ---------------------------------------------------------------------------
// K2: pairwise distances via fp16x2 split-precision MFMA Gram.
// gload_lds staging + XOR involution + BK=64 + XCD batch-affinity swizzle.
// ---------------------------------------------------------------------------
__global__ __launch_bounds__(256) void k_dmg(const unsigned short* __restrict__ xh,
    const unsigned short* __restrict__ xl, const float* __restrict__ sq,
    float* __restrict__ dm, float* __restrict__ dmax)
{
  __shared__ __align__(16) unsigned short S[4][96 * 64];   // 4 x 12KB = 48KB
  int flat = blockIdx.x;
  int xcd = flat & 7, seq = flat >> 3;
  int b = (seq / 21) * 8 + xcd;
  int t = seq % 21;
  int ti = 0, rl = 6;
  while (t >= rl) { t -= rl; ++ti; --rl; }
  int tj = ti + t;
  int tid = threadIdx.x;
  int wave = tid >> 6, lane = tid & 63;
  int wr = (wave >> 1) * 48, wc = (wave & 1) * 48;
  int mloc = lane & 15, quad = lane >> 4;
  size_t rowA = (size_t)b * N_ + ti * 96;
  size_t rowB = (size_t)b * N_ + tj * 96;

  const unsigned short* srcbase =
      (wave == 0) ? xh + rowA * D_ :
      (wave == 1) ? xl + rowA * D_ :
      (wave == 2) ? xh + rowB * D_ : xl + rowB * D_;
  int lrow = lane >> 3, lchunk = lane & 7;
  const unsigned short* gsrc0 = srcbase + (size_t)lrow * D_ + ((lchunk ^ lrow) * 8);
  unsigned short* lbase = &S[wave][0];

  floatx4 a1[3][3], a2[3][3];
#pragma unroll
  for (int i = 0; i < 3; ++i)
#pragma unroll
    for (int j = 0; j < 3; ++j) {
      a1[i][j] = (floatx4){0.f, 0.f, 0.f, 0.f};
      a2[i][j] = (floatx4){0.f, 0.f, 0.f, 0.f};
    }

  for (int kt = 0; kt < D_; kt += 64) {
    __syncthreads();
#pragma unroll
    for (int rb = 0; rb < 12; ++rb)
      gload_lds16(gsrc0 + (size_t)rb * 8 * D_ + kt, lbase + rb * 8 * 64);
    __syncthreads();
#pragma unroll
    for (int ks = 0; ks < 2; ++ks) {
      half8v ah[3], al[3], bh[3], bl[3];
      int cperm = (((ks << 2) | quad) ^ (mloc & 7)) * 8;
#pragma unroll
      for (int i = 0; i < 3; ++i) {
        int ro = (wr + i * 16 + mloc) * 64 + cperm;
        ah[i] = *(const half8v*)&S[0][ro];
        al[i] = *(const half8v*)&S[1][ro];
      }
#pragma unroll
      for (int j = 0; j < 3; ++j) {
        int ro = (wc + j * 16 + mloc) * 64 + cperm;
        bh[j] = *(const half8v*)&S[2][ro];
        bl[j] = *(const half8v*)&S[3][ro];
      }
#pragma unroll
      for (int i = 0; i < 3; ++i)
#pragma unroll
        for (int j = 0; j < 3; ++j) {
          a1[i][j] = __builtin_amdgcn_mfma_f32_16x16x32_f16(ah[i], bh[j], a1[i][j], 0, 0, 0);
          a2[i][j] = __builtin_amdgcn_mfma_f32_16x16x32_f16(ah[i], bl[j], a2[i][j], 0, 0, 0);
          a2[i][j] = __builtin_amdgcn_mfma_f32_16x16x32_f16(al[i], bh[j], a2[i][j], 0, 0, 0);
        }
    }
  }

  const float* sqb = sq + b * N_;
  float* dmb = dm + (size_t)b * N_ * N_;
  bool diag = (ti == tj);
  float vmax = 0.f;
#pragma unroll
  for (int j = 0; j < 3; ++j) {
    int gj = tj * 96 + wc + j * 16 + mloc;
    float sj = sqb[gj];
#pragma unroll
    for (int i = 0; i < 3; ++i) {
      int gi0 = ti * 96 + wr + i * 16 + quad * 4;
#pragma unroll
      for (int reg = 0; reg < 4; ++reg) {
        int gi = gi0 + reg;
        float g = a1[i][j][reg] + a2[i][j][reg] * LO_SCALE_;
        float d = sqb[gi] + sj - 2.0f * g;
        float v = sqrtf(fmaxf(d, 0.0f)) * INV_SQRT_D_;
        vmax = fmaxf(vmax, v);
        if (!diag || gj >= gi) {
          dmb[(size_t)gi * N_ + gj] = v;
          dmb[(size_t)gj * N_ + gi] = v;
        }
      }
    }
  }
#pragma unroll
  for (int msk = 32; msk >= 1; msk >>= 1) vmax = fmaxf(vmax, __shfl_xor(vmax, msk));
  if (lane == 0) atomicMax((unsigned int*)(dmax + b), __float_as_uint(vmax));
}

// ---------------------------------------------------------------------------
// K3: kNN density
// ---------------------------------------------------------------------------
__global__ __launch_bounds__(64) void k_density(const float* __restrict__ dm,
    const float* __restrict__ noise, float* __restrict__ den)
{
  int row = blockIdx.x, lane = threadIdx.x;
  const float* r = dm + (size_t)row * N_;
  float a0 = 1e30f, a1 = 1e30f, a2 = 1e30f, a3 = 1e30f, a4 = 1e30f;
  auto ins5 = [&](float xv) {
    a4 = fminf(a4, xv);
    float t;
    t = fminf(a3, a4); a4 = fmaxf(a3, a4); a3 = t;
    t = fminf(a2, a3); a3 = fmaxf(a2, a3); a2 = t;
    t = fminf(a1, a2); a2 = fmaxf(a1, a2); a1 = t;
    t = fminf(a0, a1); a1 = fmaxf(a0, a1); a0 = t;
  };
#pragma unroll
  for (int t = 0; t < 9; ++t) ins5(r[lane + 64 * t]);
  for (int m = 1; m < 64; m <<= 1) {
    float b0 = __shfl_xor(a0, m), b1 = __shfl_xor(a1, m), b2 = __shfl_xor(a2, m);
    float b3 = __shfl_xor(a3, m), b4 = __shfl_xor(a4, m);
    ins5(b0); ins5(b1); ins5(b2); ins5(b3); ins5(b4);
  }
  if (lane == 0) {
    float ms = (a0 * a0 + a1 * a1 + a2 * a2 + a3 * a3 + a4 * a4) * 0.2f;
    den[row] = expf(-ms) + noise[row] * 1e-6f;
  }
}

// ---------------------------------------------------------------------------
// K5: dist-to-higher-density + score
// ---------------------------------------------------------------------------
__global__ __launch_bounds__(64) void k_dist(const float* __restrict__ dm,
    const float* __restrict__ den, const float* __restrict__ dmax,
    float* __restrict__ score)
{
  int row = blockIdx.x, lane = threadIdx.x;
  int b = row / N_;
  float di = den[row], dx = dmax[b];
  const float* r = dm + (size_t)row * N_;
  const float* db = den + b * N_;
  float m = dx;
#pragma unroll
  for (int t = 0; t < 9; ++t) {
    int j = lane + 64 * t;
    float v = (db[j] > di) ? r[j] : dx;
    m = fminf(m, v);
  }
  for (int msk = 1; msk < 64; msk <<= 1) m = fminf(m, __shfl_xor(m, msk));
  if (lane == 0) score[row] = m * di;
}

// ---------------------------------------------------------------------------
// K6: top-64 scores per batch — bitonic sort of 1024 (576 real + pad) on
// (score desc, idx asc); reproduces jax top_k tie-break.
// ---------------------------------------------------------------------------
__global__ __launch_bounds__(256) void k_topL(const float* __restrict__ score,
    int* __restrict__ idxd)
{
  int b = blockIdx.x, tid = threadIdx.x;
  __shared__ float s[1024];
  __shared__ int   si[1024];
  for (int i = tid; i < 1024; i += 256) {
    s[i] = (i < N_) ? score[b * N_ + i] : -3.0e38f;
    si[i] = i;
  }
  __syncthreads();
  for (int k = 2; k <= 1024; k <<= 1) {
    for (int j = k >> 1; j > 0; j >>= 1) {
#pragma unroll
      for (int t = 0; t < 2; ++t) {
        int idx512 = tid + t * 256;
        int lo = idx512 & (j - 1);
        int i = ((idx512 ^ lo) << 1) | lo;
        int p = i | j;
        float as = s[i], bs = s[p];
        int ai = si[i], bi = si[p];
        bool bba = (bs > as) || (bs == as && bi < ai);
        bool up = ((i & k) == 0);
        bool dosw = up ? bba : !bba;
        if (dosw) { s[i] = bs; s[p] = as; si[i] = bi; si[p] = ai; }
      }
      __syncthreads();
    }
  }
  if (tid < L_) idxd[b * L_ + tid] = si[tid];
}

// ---------------------------------------------------------------------------
// K7: assign tokens to nearest center (+ fused center self-assignment)
// ---------------------------------------------------------------------------
__global__ __launch_bounds__(576) void k_assign(const float* __restrict__ dm,
    const int* __restrict__ idxd, int* __restrict__ idxc)
{
  int b = blockIdx.x, n = threadIdx.x;
  __shared__ int ctr[L_];
  if (n < L_) ctr[n] = idxd[b * L_ + n];
  __syncthreads();
  const float* dmb = dm + (size_t)b * N_ * N_;
  float best = 1e30f; int bl = 0;
  for (int l = 0; l < L_; ++l) {
    float v = dmb[(size_t)ctr[l] * N_ + n];
    if (v < best) { best = v; bl = l; }
  }
  for (int l = 0; l < L_; ++l)
    if (ctr[l] == n) bl = l;
  idxc[b * N_ + n] = bl;
}

// ---------------------------------------------------------------------------
// K7b: bucket tokens by cluster (stable counting sort; one thread per cluster)
// ord[b][576]: token indices grouped by cluster, ascending n within cluster.
// starts[b][65]: segment boundaries.
// ---------------------------------------------------------------------------
__global__ __launch_bounds__(64) void k_bucket(const int* __restrict__ idxc,
    int* __restrict__ ord, int* __restrict__ starts)
{
  int b = blockIdx.x, l = threadIdx.x;   // 64 threads = 1 wave
  __shared__ int ic[N_];
  for (int n = l; n < N_; n += 64) ic[n] = idxc[b * N_ + n];
  __syncthreads();
  int cnt = 0;
  for (int n = 0; n < N_; ++n) cnt += (ic[n] == l) ? 1 : 0;
  // inclusive wave prefix-sum of cnt
  int inc = cnt;
  for (int d = 1; d < 64; d <<= 1) {
    int v = __shfl_up(inc, d);
    if (l >= d) inc += v;
  }
  int excl = inc - cnt;
  if (l == 0) starts[b * 65] = 0;
  starts[b * 65 + l + 1] = inc;
  int p = excl;
  for (int n = 0; n < N_; ++n)
    if (ic[n] == l) ord[b * N_ + p++] = n;
}

// ---------------------------------------------------------------------------
// K8: merger (gather via inverted index) — loops only over its own cluster's
// ~9 tokens (was: scan of all 576). Accumulation order (ascending n) and all
// arithmetic identical to the previous passing version -> bit-identical QIN.
// ---------------------------------------------------------------------------
__global__ __launch_bounds__(256) void k_merge(const unsigned short* __restrict__ xh,
    const unsigned short* __restrict__ xl,
    const float* __restrict__ ts, const int* __restrict__ ord,
    const int* __restrict__ starts, float* __restrict__ qin)
{
  int blk = blockIdx.x;
  int b = blk >> 6, l = blk & 63;
  int tid = threadIdx.x;
  int s0 = starts[b * 65 + l], s1 = starts[b * 65 + l + 1];
  const float* tsb = ts + b * N_;
  const int* ob = ord + b * N_;
  const unsigned short* xhb = xh + (size_t)b * N_ * D_;
  const unsigned short* xlb = xl + (size_t)b * N_ * D_;
  float a0 = 0.f, a1 = 0.f, a2 = 0.f, wsum = 0.f;
  for (int k = s0; k < s1; ++k) {
    int n = ob[k];
    float w = expf(tsb[n]);
    wsum += w;
    const unsigned short* hr = xhb + (size_t)n * D_;
    const unsigned short* lr = xlb + (size_t)n * D_;
    float x0 = h2f(hr[tid      ]) + h2f(lr[tid      ]) * LO_SCALE_;
    float x1 = h2f(hr[tid + 256]) + h2f(lr[tid + 256]) * LO_SCALE_;
    float x2 = h2f(hr[tid + 512]) + h2f(lr[tid + 512]) * LO_SCALE_;
    a0 += w * x0; a1 += w * x1; a2 += w * x2;
  }
  float inv = 1.0f / (wsum + 1e-6f);
  float* q = qin + (size_t)blk * D_;
  q[tid] = a0 * inv; q[tid + 256] = a1 * inv; q[tid + 512] = a2 * inv;
}

// ---------------------------------------------------------------------------
// Weight transpose + fp16 cast: W[K,N] fp32 -> WT[N,K] fp16
// ---------------------------------------------------------------------------
__global__ __launch_bounds__(256) void k_wt(const float* __restrict__ W,
    unsigned short* __restrict__ WT, int K, int N)
{
  __shared__ float t[32][33];
  int k0 = blockIdx.x * 32, n0 = blockIdx.y * 32;
  int tid = threadIdx.x;
  int r = tid >> 3, c4 = (tid & 7) * 4;
  float4 v = *(const float4*)(W + (size_t)(k0 + r) * N + n0 + c4);
  t[r][c4] = v.x; t[r][c4 + 1] = v.y; t[r][c4 + 2] = v.z; t[r][c4 + 3] = v.w;
  __syncthreads();
  ushort4 s4;
  s4.x = f2h(t[c4 + 0][r]); s4.y = f2h(t[c4 + 1][r]);
  s4.z = f2h(t[c4 + 2][r]); s4.w = f2h(t[c4 + 3][r]);
  *(ushort4*)(WT + (size_t)(n0 + r) * K + k0 + c4) = s4;
}

// ---------------------------------------------------------------------------
// MFMA GEMM: C[M,N] = epilogue(A[M,K] @ WT[N,K]^T), fp16 MFMA, fp32 accum.
// BK=64; As/Bs [128][64] with XOR-chunk swizzle; gload_lds staging.
// ---------------------------------------------------------------------------
template<int EPI, int ASRC>
__global__ __launch_bounds__(256) void k_mgemm(const void* __restrict__ Ap_,
    const unsigned short* __restrict__ Wt, const float* __restrict__ bias,
    const float* __restrict__ res, void* __restrict__ outp,
    int M, int Nd, int Kd)
{
  __shared__ __align__(16) unsigned short As[128 * 64];
  __shared__ __align__(16) unsigned short Bs[128 * 64];
  int tid = threadIdx.x;
  int bm = blockIdx.x * 128, bn = blockIdx.y * 128;
  int wave = tid >> 6, lane = tid & 63;
  int wr = (wave >> 1) * 64, wc = (wave & 1) * 64;
  int mloc = lane & 15, quad = lane >> 4;

  floatx4 acc[4][4];
#pragma unroll
  for (int i = 0; i < 4; ++i)
#pragma unroll
    for (int j = 0; j < 4; ++j)
      acc[i][j] = (floatx4){0.f, 0.f, 0.f, 0.f};

  int lrow = lane >> 3, lchunk = lane & 7;
  const unsigned short* bsrc0 =
      Wt + (size_t)(bn + wave * 32 + lrow) * Kd + ((lchunk ^ lrow) * 8);
  unsigned short* bdst0 = &Bs[(wave * 32) * 64];
  const unsigned short* asrc0 = (ASRC == 1)
      ? (const unsigned short*)Ap_ + (size_t)(bm + wave * 32 + lrow) * Kd + ((lchunk ^ lrow) * 8)
      : nullptr;
  unsigned short* adst0 = &As[(wave * 32) * 64];

  for (int kt = 0; kt < Kd; kt += 64) {
    __syncthreads();
#pragma unroll
    for (int rb = 0; rb < 4; ++rb)
      gload_lds16(bsrc0 + (size_t)rb * 8 * Kd + kt, bdst0 + rb * 8 * 64);
    if (ASRC == 1) {
#pragma unroll
      for (int rb = 0; rb < 4; ++rb)
        gload_lds16(asrc0 + (size_t)rb * 8 * Kd + kt, adst0 + rb * 8 * 64);
    } else {
      const float* A = (const float*)Ap_;
#pragma unroll
      for (int it = 0; it < 4; ++it) {
        int idx = tid + it * 256;
        int r = idx >> 3, c = idx & 7;
        const float* ap = A + (size_t)(bm + r) * Kd + kt + c * 8;
        float4 f0 = *(const float4*)ap;
        float4 f1 = *(const float4*)(ap + 4);
        uint4 pk;
        pk.x = (unsigned)f2h(f0.x) | ((unsigned)f2h(f0.y) << 16);
        pk.y = (unsigned)f2h(f0.z) | ((unsigned)f2h(f0.w) << 16);
        pk.z = (unsigned)f2h(f1.x) | ((unsigned)f2h(f1.y) << 16);
        pk.w = (unsigned)f2h(f1.z) | ((unsigned)f2h(f1.w) << 16);
        *(uint4*)&As[r * 64 + ((c ^ (r & 7)) * 8)] = pk;
      }
    }
    __syncthreads();
#pragma unroll
    for (int ks = 0; ks < 2; ++ks) {
      half8v af[4], bf[4];
      int cperm = (((ks << 2) | quad) ^ (mloc & 7)) * 8;
#pragma unroll
      for (int i = 0; i < 4; ++i)
        af[i] = *(const half8v*)&As[(wr + i * 16 + mloc) * 64 + cperm];
#pragma unroll
      for (int j = 0; j < 4; ++j)
        bf[j] = *(const half8v*)&Bs[(wc + j * 16 + mloc) * 64 + cperm];
#pragma unroll
      for (int i = 0; i < 4; ++i)
#pragma unroll
        for (int j = 0; j < 4; ++j)
          acc[i][j] = __builtin_amdgcn_mfma_f32_16x16x32_f16(af[i], bf[j], acc[i][j], 0, 0, 0);
    }
  }

  float bv[4] = {0.f, 0.f, 0.f, 0.f};
  if (EPI >= 1) {
#pragma unroll
    for (int j = 0; j < 4; ++j) bv[j] = bias[bn + wc + j * 16 + mloc];
  }
#pragma unroll
  for (int i = 0; i < 4; ++i) {
    int gr0 = bm + wr + i * 16 + quad * 4;
#pragma unroll
    for (int j = 0; j < 4; ++j) {
      int gcn = bn + wc + j * 16 + mloc;
#pragma unroll
      for (int reg = 0; reg < 4; ++reg) {
        float v = acc[i][j][reg];
        size_t off = (size_t)(gr0 + reg) * Nd + gcn;
        if (EPI == 0) {
          ((unsigned short*)outp)[off] = f2h(v);
        } else if (EPI == 1) {
          ((float*)outp)[off] = v + bv[j] + res[off];
        } else {
          v += bv[j];
          v = 0.5f * v * (1.0f + erff(v * 0.70710678f));
          ((unsigned short*)outp)[off] = f2h(v);
        }
      }
    }
  }
}

// ---------------------------------------------------------------------------
// K12: MFMA flash cross-attention with token-score bias (all fp16 operands).
// K/V interleaved in one buffer, row stride 1536 (K at col h*96, V at 768+h*96)
// ---------------------------------------------------------------------------
__global__ __launch_bounds__(256) void k_attn(const unsigned short* __restrict__ Qu,
    const unsigned short* __restrict__ KVu, const float* __restrict__ ts,
    float* __restrict__ aout)
{
  __shared__ __align__(16) unsigned short Ks[64 * 104];
  __shared__ __align__(16) unsigned short VsT[96 * 64];
  __shared__ __align__(16) unsigned short sPa[64 * 64];
  __shared__ float tsb[64];
  int h = blockIdx.x, b = blockIdx.y;
  int tid = threadIdx.x;
  int wave = tid >> 6, lane = tid & 63;
  int mloc = lane & 15, quad = lane >> 4;

  half8v qf[3];
  {
    const unsigned short* qrow = Qu + (size_t)(b * 64 + wave * 16 + mloc) * D_ + h * 96 + quad * 8;
#pragma unroll
    for (int k = 0; k < 3; ++k) qf[k] = *(const half8v*)(qrow + k * 32);
  }

  floatx4 of[6];
#pragma unroll
  for (int dt = 0; dt < 6; ++dt) of[dt] = (floatx4){0.f, 0.f, 0.f, 0.f};
  float m[4], l[4];
#pragma unroll
  for (int r = 0; r < 4; ++r) { m[r] = -1e30f; l[r] = 0.f; }

  for (int jt = 0; jt < 9; ++jt) {
    int j0 = jt * 64;
    __syncthreads();
#pragma unroll
    for (int t = 0; t < 3; ++t) {
      int id = tid + t * 256;
      int row = id / 12, c = id % 12;
      *(uint4*)&Ks[row * 104 + c * 8] =
          *(const uint4*)(KVu + (size_t)(b * N_ + j0 + row) * KV_STRIDE_ + h * 96 + c * 8);
    }
#pragma unroll
    for (int t = 0; t < 3; ++t) {
      int id = tid + t * 256;
      int keyp = id & 31, dq = (id >> 5) * 4;
      int key = keyp * 2;
      const unsigned short* vp =
          KVu + (size_t)(b * N_ + j0 + key) * KV_STRIDE_ + 768 + h * 96 + dq;
      ushort4 v0 = *(const ushort4*)vp;
      ushort4 v1 = *(const ushort4*)(vp + KV_STRIDE_);
      unsigned pk0 = (unsigned)v0.x | ((unsigned)v1.x << 16);
      unsigned pk1 = (unsigned)v0.y | ((unsigned)v1.y << 16);
      unsigned pk2 = (unsigned)v0.z | ((unsigned)v1.z << 16);
      unsigned pk3 = (unsigned)v0.w | ((unsigned)v1.w << 16);
      int cbase = key >> 3, off = key & 7;
#pragma unroll
      for (int i = 0; i < 4; ++i) {
        int d = dq + i;
        unsigned pv = (i == 0) ? pk0 : (i == 1) ? pk1 : (i == 2) ? pk2 : pk3;
        *(unsigned*)&VsT[d * 64 + ((cbase ^ (d & 7)) << 3) + off] = pv;
      }
    }
    if (tid < 64) tsb[tid] = ts[b * N_ + j0 + tid];
    __syncthreads();

    floatx4 acc[4];
#pragma unroll
    for (int j = 0; j < 4; ++j) acc[j] = (floatx4){0.f, 0.f, 0.f, 0.f};
#pragma unroll
    for (int j = 0; j < 4; ++j)
#pragma unroll
      for (int k = 0; k < 3; ++k) {
        half8v kf = *(const half8v*)&Ks[(j * 16 + mloc) * 104 + k * 32 + quad * 8];
        acc[j] = __builtin_amdgcn_mfma_f32_16x16x32_f16(qf[k], kf, acc[j], 0, 0, 0);
      }

    float ts4[4];
#pragma unroll
    for (int j = 0; j < 4; ++j) ts4[j] = tsb[j * 16 + mloc];
    float rm[4] = {-1e30f, -1e30f, -1e30f, -1e30f};
#pragma unroll
    for (int j = 0; j < 4; ++j)
#pragma unroll
      for (int r = 0; r < 4; ++r) {
        acc[j][r] = acc[j][r] * SCALE_ + ts4[j];
        rm[r] = fmaxf(rm[r], acc[j][r]);
      }
#pragma unroll
    for (int r = 0; r < 4; ++r) {
      rm[r] = fmaxf(rm[r], __shfl_xor(rm[r], 1));
      rm[r] = fmaxf(rm[r], __shfl_xor(rm[r], 2));
      rm[r] = fmaxf(rm[r], __shfl_xor(rm[r], 4));
      rm[r] = fmaxf(rm[r], __shfl_xor(rm[r], 8));
    }
    float alpha[4], rs[4];
#pragma unroll
    for (int r = 0; r < 4; ++r) {
      float mn = fmaxf(m[r], rm[r]);
      alpha[r] = __expf(m[r] - mn);
      m[r] = mn;
      rs[r] = 0.f;
    }
#pragma unroll
    for (int j = 0; j < 4; ++j)
#pragma unroll
      for (int r = 0; r < 4; ++r) {
        float p = __expf(acc[j][r] - m[r]);
        acc[j][r] = p; rs[r] += p;
      }
#pragma unroll
    for (int r = 0; r < 4; ++r) {
      rs[r] += __shfl_xor(rs[r], 1); rs[r] += __shfl_xor(rs[r], 2);
      rs[r] += __shfl_xor(rs[r], 4); rs[r] += __shfl_xor(rs[r], 8);
      l[r] = l[r] * alpha[r] + rs[r];
    }
#pragma unroll
    for (int dt = 0; dt < 6; ++dt)
#pragma unroll
      for (int r = 0; r < 4; ++r) of[dt][r] *= alpha[r];

#pragma unroll
    for (int j = 0; j < 4; ++j)
#pragma unroll
      for (int r = 0; r < 4; ++r) {
        int row = wave * 16 + quad * 4 + r;
        int key = j * 16 + mloc;
        sPa[row * 64 + (((key >> 3) ^ (row & 7)) << 3) + (key & 7)] = f2h(acc[j][r]);
      }
    half8v pa[2];
    int prow = wave * 16 + mloc;
#pragma unroll
    for (int f2 = 0; f2 < 2; ++f2)
      pa[f2] = *(const half8v*)&sPa[prow * 64 + (((f2 * 4 + quad) ^ (prow & 7)) << 3)];
#pragma unroll
    for (int dt = 0; dt < 6; ++dt)
#pragma unroll
      for (int f2 = 0; f2 < 2; ++f2) {
        int vrow = dt * 16 + mloc;
        half8v vf = *(const half8v*)&VsT[vrow * 64 + (((f2 * 4 + quad) ^ (vrow & 7)) << 3)];
        of[dt] = __builtin_amdgcn_mfma_f32_16x16x32_f16(pa[f2], vf, of[dt], 0, 0, 0);
      }
  }

  float linv[4];
#pragma unroll
  for (int r = 0; r < 4; ++r) linv[r] = 1.0f / l[r];
#pragma unroll
  for (int dt = 0; dt < 6; ++dt)
#pragma unroll
    for (int r = 0; r < 4; ++r) {
      int row = b * 64 + wave * 16 + quad * 4 + r;
      int col = h * 96 + dt * 16 + mloc;
      aout[(size_t)row * D_ + col] = of[dt][r] * linv[r];
    }
}

// ---------------------------------------------------------------------------
// K14: LayerNorm2 (fp32 in -> fp32 out)
// ---------------------------------------------------------------------------
__global__ __launch_bounds__(256) void k_ln2(const float* __restrict__ f,
    const float* __restrict__ g, const float* __restrict__ bt, float* __restrict__ out)
{
  int row = blockIdx.x, tid = threadIdx.x;
  const float* fr = f + (size_t)row * D_;
  float v0 = fr[tid], v1 = fr[tid + 256], v2 = fr[tid + 512];
  __shared__ float r1[256], r2[256];
  r1[tid] = v0 + v1 + v2;
  r2[tid] = v0 * v0 + v1 * v1 + v2 * v2;
  __syncthreads();
  for (int o = 128; o > 0; o >>= 1) {
    if (tid < o) { r1[tid] += r1[tid + o]; r2[tid] += r2[tid + o]; }
    __syncthreads();
  }
  float mean = r1[0] * (1.0f / D_);
  float var  = r2[0] * (1.0f / D_) - mean * mean;
  float rstd = rsqrtf(var + 1e-5f);
  float* oo = out + (size_t)row * D_;
  oo[tid      ] = (v0 - mean) * rstd * g[tid      ] + bt[tid      ];
  oo[tid + 256] = (v1 - mean) * rstd * g[tid + 256] + bt[tid + 256];
  oo[tid + 512] = (v2 - mean) * rstd * g[tid + 512] + bt[tid + 512];
}

// ---------------------------------------------------------------------------
// Launch
// ---------------------------------------------------------------------------
extern "C" void kernel_launch(void* const* d_in, const int* in_sizes, int n_in,
                              void* d_out, int out_size, void* d_ws, size_t ws_size,
                              hipStream_t stream)
{
  (void)in_sizes; (void)n_in; (void)out_size; (void)ws_size;
  const float* x    = (const float*)d_in[0];
  const float* nois = (const float*)d_in[1];
  const float* n1g  = (const float*)d_in[2];
  const float* n1b  = (const float*)d_in[3];
  const float* sw   = (const float*)d_in[4];
  const float* sb   = (const float*)d_in[5];
  const float* wq   = (const float*)d_in[6];
  const float* wk   = (const float*)d_in[7];
  const float* wv   = (const float*)d_in[8];
  const float* pw   = (const float*)d_in[9];
  const float* pb   = (const float*)d_in[10];
  const float* n2g  = (const float*)d_in[11];
  const float* n2b  = (const float*)d_in[12];
  const float* f1w  = (const float*)d_in[13];
  const float* f1b  = (const float*)d_in[14];
  const float* f2w  = (const float*)d_in[15];
  const float* f2b  = (const float*)d_in[16];

  float* ws    = (float*)d_ws;
  unsigned short* XH = (unsigned short*)ws;                 // fp16 hi plane
  unsigned short* XL = XH + (size_t)NB_ * D_;               // fp16 lo plane
  float* RG    = ws + (size_t)NB_ * D_;
  float* QIN   = RG + (size_t)NB_ * D_;
  float* FEAT  = QIN + (size_t)ML_ * D_;
  float* AOUT  = FEAT + (size_t)ML_ * D_;
  float* QBUF  = AOUT + (size_t)ML_ * D_;
  float* P     = QBUF + (size_t)ML_ * D_;
  unsigned short* QH16 = (unsigned short*)P;  P += (size_t)ML_ * D_ / 2;
  unsigned short* WTQ  = (unsigned short*)P;  P += (size_t)D_ * D_ / 2;
  unsigned short* WTKV = (unsigned short*)P;  P += (size_t)D_ * D_;     // K then V
  unsigned short* WTP  = (unsigned short*)P;  P += (size_t)D_ * D_ / 2;
  unsigned short* WT1  = (unsigned short*)P;  P += (size_t)D_ * 4 * D_ / 2;
  unsigned short* WT2  = (unsigned short*)P;  P += (size_t)D_ * 4 * D_ / 2;
  float* TS    = P;
  float* SQ    = TS + NB_;
  float* DEN   = SQ + NB_;
  float* SCORE = DEN + NB_;
  float* DMAX  = SCORE + NB_;
  int*   IDXD  = (int*)(DMAX + 64);
  int*   IDXC  = IDXD + ML_;
  int*   ORD   = IDXC + NB_;
  int*   STARTS= ORD + NB_;           // B_*65 ints
  float* DM    = RG;                               // phase 1
  unsigned short* KVB = (unsigned short*)RG;       // phase 2: [NB_][1536] K|V
  unsigned short* HID = (unsigned short*)RG;       // phase 3

  hipMemsetAsync(DMAX, 0, 64 * sizeof(float), stream);
  k_wt<<<dim3(24, 24), 256, 0, stream>>>(wq, WTQ, D_, D_);
  k_wt<<<dim3(24, 24), 256, 0, stream>>>(wk, WTKV, D_, D_);
  k_wt<<<dim3(24, 24), 256, 0, stream>>>(wv, WTKV + (size_t)D_ * D_, D_, D_);
  k_wt<<<dim3(24, 24), 256, 0, stream>>>(pw, WTP, D_, D_);
  k_wt<<<dim3(24, 96), 256, 0, stream>>>(f1w, WT1, D_, 4 * D_);
  k_wt<<<dim3(96, 24), 256, 0, stream>>>(f2w, WT2, 4 * D_, D_);

  k_ln1<<<NB_, 256, 0, stream>>>(x, n1g, n1b, sw, sb, XH, XL, TS, SQ);
  k_dmg<<<1344, 256, 0, stream>>>(XH, XL, SQ, DM, DMAX);
  k_density<<<NB_, 64, 0, stream>>>(DM, nois, DEN);
  k_dist<<<NB_, 64, 0, stream>>>(DM, DEN, DMAX, SCORE);
  k_topL<<<B_, 256, 0, stream>>>(SCORE, IDXD);
  k_assign<<<B_, 576, 0, stream>>>(DM, IDXD, IDXC);
  k_bucket<<<B_, 64, 0, stream>>>(IDXC, ORD, STARTS);
  k_merge<<<ML_, 256, 0, stream>>>(XH, XL, TS, ORD, STARTS, QIN);

  k_mgemm<0, 0><<<dim3(ML_ / 128, D_ / 128), 256, 0, stream>>>(
      QIN, WTQ, nullptr, nullptr, QH16, ML_, D_, D_);
  k_mgemm<0, 1><<<dim3(NB_ / 128, KV_STRIDE_ / 128), 256, 0, stream>>>(
      XH, WTKV, nullptr, nullptr, KVB, NB_, KV_STRIDE_, D_);
  k_attn<<<dim3(H_, B_), 256, 0, stream>>>(QH16, KVB, TS, AOUT);
  k_mgemm<1, 0><<<dim3(ML_ / 128, D_ / 128), 256, 0, stream>>>(
      AOUT, WTP, pb, QIN, FEAT, ML_, D_, D_);
  k_ln2<<<ML_, 256, 0, stream>>>(FEAT, n2g, n2b, QBUF);
  k_mgemm<2, 0><<<dim3(ML_ / 128, (4 * D_) / 128), 256, 0, stream>>>(
      QBUF, WT1, f1b, nullptr, HID, ML_, 4 * D_, D_);
  k_mgemm<1, 1><<<dim3(ML_ / 128, D_ / 128), 256, 0, stream>>>(
      HID, WT2, f2b, FEAT, d_out, ML_, D_, 4 * D_);
}

// Round 10
// 815.813 us; speedup vs baseline: 1.4486x; 1.0133x over previous
//
#include <hip/hip_runtime.h>
#include <math.h>

// Problem constants
#define B_   64
#define N_   576
#define D_   768
#define L_   64
#define H_   8
#define HD_  96
#define NB_  (B_*N_)    // 36864 rows
#define ML_  (B_*L_)    // 4096 rows
#define KV_STRIDE_ 1536
#define SCALE_ 0.10206207f          // 96^-0.5
#define INV_SQRT_D_ 0.03608439182f  // 1/sqrt(768)
#define LO_SCALE_ 4.8828125e-4f     // 2^-11

typedef __attribute__((ext_vector_type(8))) _Float16 half8v;    // 8 fp16 (4 VGPRs)
typedef __attribute__((ext_vector_type(4))) float floatx4;      // MFMA C/D

__device__ __forceinline__ unsigned short f2h(float f) {
  _Float16 h = (_Float16)f;
  unsigned short u; __builtin_memcpy(&u, &h, 2);
  return u;
}
__device__ __forceinline__ float h2f(unsigned short u) {
  _Float16 h; __builtin_memcpy(&h, &u, 2);
  return (float)h;
}
// async global->LDS, 16B/lane: HW writes lds_base + lane*16 (wave-uniform base),
// global source is per-lane.
__device__ __forceinline__ void gload_lds16(const void* g, void* l) {
  __builtin_amdgcn_global_load_lds(
      (const __attribute__((address_space(1))) unsigned*)g,
      (__attribute__((address_space(3))) unsigned*)l, 16, 0, 0);
}

// ---------------------------------------------------------------------------
// K1: LayerNorm1 -> fp16 hi/lo split planes + token_score + row sum-of-squares
// ---------------------------------------------------------------------------
__global__ __launch_bounds__(256) void k_ln1(const float* __restrict__ x,
    const float* __restrict__ g, const float* __restrict__ bt,
    const float* __restrict__ sw, const float* __restrict__ sb,
    unsigned short* __restrict__ xh, unsigned short* __restrict__ xl,
    float* __restrict__ ts, float* __restrict__ sq)
{
  int row = blockIdx.x, tid = threadIdx.x;
  const float* xr = x + (size_t)row * D_;
  float v0 = xr[tid], v1 = xr[tid + 256], v2 = xr[tid + 512];
  __shared__ float r1[256], r2[256];
  r1[tid] = v0 + v1 + v2;
  r2[tid] = v0 * v0 + v1 * v1 + v2 * v2;
  __syncthreads();
  for (int o = 128; o > 0; o >>= 1) {
    if (tid < o) { r1[tid] += r1[tid + o]; r2[tid] += r2[tid + o]; }
    __syncthreads();
  }
  float mean = r1[0] * (1.0f / D_);
  float var  = r2[0] * (1.0f / D_) - mean * mean;
  float rstd = rsqrtf(var + 1e-5f);
  __syncthreads();
  float o0 = (v0 - mean) * rstd * g[tid      ] + bt[tid      ];
  float o1 = (v1 - mean) * rstd * g[tid + 256] + bt[tid + 256];
  float o2 = (v2 - mean) * rstd * g[tid + 512] + bt[tid + 512];
  auto split = [](float o, unsigned short& hu, unsigned short& lu) {
    _Float16 h = (_Float16)o;
    float hf = (float)h;
    _Float16 l = (_Float16)((o - hf) * 2048.0f);
    __builtin_memcpy(&hu, &h, 2);
    __builtin_memcpy(&lu, &l, 2);
  };
  unsigned short h0, l0, h1, l1, h2, l2;
  split(o0, h0, l0); split(o1, h1, l1); split(o2, h2, l2);
  unsigned short* xho = xh + (size_t)row * D_;
  unsigned short* xlo = xl + (size_t)row * D_;
  xho[tid] = h0; xho[tid + 256] = h1; xho[tid + 512] = h2;
  xlo[tid] = l0; xlo[tid + 256] = l1; xlo[tid + 512] = l2;
  r1[tid] = o0 * sw[tid] + o1 * sw[tid + 256] + o2 * sw[tid + 512];
  r2[tid] = o0 * o0 + o1 * o1 + o2 * o2;
  __syncthreads();
  for (int o = 128; o > 0; o >>= 1) {
    if (tid < o) { r1[tid] += r1[tid + o]; r2[tid] += r2[tid + o]; }
    __syncthreads();
  }
  if (tid == 0) { ts[row] = r1[0] + sb[0]; sq[row] = r2[0]; }
}

// ---------------------------------------------------------------------------
// K2: pairwise distances via fp16x2 split-precision MFMA Gram.
// gload_lds staging + XOR involution + BK=64 + XCD batch-affinity swizzle.
// ---------------------------------------------------------------------------
__global__ __launch_bounds__(256) void k_dmg(const unsigned short* __restrict__ xh,
    const unsigned short* __restrict__ xl, const float* __restrict__ sq,
    float* __restrict__ dm, float* __restrict__ dmax)
{
  __shared__ __align__(16) unsigned short S[4][96 * 64];   // 4 x 12KB = 48KB
  int flat = blockIdx.x;
  int xcd = flat & 7, seq = flat >> 3;
  int b = (seq / 21) * 8 + xcd;
  int t = seq % 21;
  int ti = 0, rl = 6;
  while (t >= rl) { t -= rl; ++ti; --rl; }
  int tj = ti + t;
  int tid = threadIdx.x;
  int wave = tid >> 6, lane = tid & 63;
  int wr = (wave >> 1) * 48, wc = (wave & 1) * 48;
  int mloc = lane & 15, quad = lane >> 4;
  size_t rowA = (size_t)b * N_ + ti * 96;
  size_t rowB = (size_t)b * N_ + tj * 96;

  const unsigned short* srcbase =
      (wave == 0) ? xh + rowA * D_ :
      (wave == 1) ? xl + rowA * D_ :
      (wave == 2) ? xh + rowB * D_ : xl + rowB * D_;
  int lrow = lane >> 3, lchunk = lane & 7;
  const unsigned short* gsrc0 = srcbase + (size_t)lrow * D_ + ((lchunk ^ lrow) * 8);
  unsigned short* lbase = &S[wave][0];

  floatx4 a1[3][3], a2[3][3];
#pragma unroll
  for (int i = 0; i < 3; ++i)
#pragma unroll
    for (int j = 0; j < 3; ++j) {
      a1[i][j] = (floatx4){0.f, 0.f, 0.f, 0.f};
      a2[i][j] = (floatx4){0.f, 0.f, 0.f, 0.f};
    }

  for (int kt = 0; kt < D_; kt += 64) {
    __syncthreads();
#pragma unroll
    for (int rb = 0; rb < 12; ++rb)
      gload_lds16(gsrc0 + (size_t)rb * 8 * D_ + kt, lbase + rb * 8 * 64);
    __syncthreads();
#pragma unroll
    for (int ks = 0; ks < 2; ++ks) {
      half8v ah[3], al[3], bh[3], bl[3];
      int cperm = (((ks << 2) | quad) ^ (mloc & 7)) * 8;
#pragma unroll
      for (int i = 0; i < 3; ++i) {
        int ro = (wr + i * 16 + mloc) * 64 + cperm;
        ah[i] = *(const half8v*)&S[0][ro];
        al[i] = *(const half8v*)&S[1][ro];
      }
#pragma unroll
      for (int j = 0; j < 3; ++j) {
        int ro = (wc + j * 16 + mloc) * 64 + cperm;
        bh[j] = *(const half8v*)&S[2][ro];
        bl[j] = *(const half8v*)&S[3][ro];
      }
#pragma unroll
      for (int i = 0; i < 3; ++i)
#pragma unroll
        for (int j = 0; j < 3; ++j) {
          a1[i][j] = __builtin_amdgcn_mfma_f32_16x16x32_f16(ah[i], bh[j], a1[i][j], 0, 0, 0);
          a2[i][j] = __builtin_amdgcn_mfma_f32_16x16x32_f16(ah[i], bl[j], a2[i][j], 0, 0, 0);
          a2[i][j] = __builtin_amdgcn_mfma_f32_16x16x32_f16(al[i], bh[j], a2[i][j], 0, 0, 0);
        }
    }
  }

  const float* sqb = sq + b * N_;
  float* dmb = dm + (size_t)b * N_ * N_;
  bool diag = (ti == tj);
  float vmax = 0.f;
#pragma unroll
  for (int j = 0; j < 3; ++j) {
    int gj = tj * 96 + wc + j * 16 + mloc;
    float sj = sqb[gj];
#pragma unroll
    for (int i = 0; i < 3; ++i) {
      int gi0 = ti * 96 + wr + i * 16 + quad * 4;
#pragma unroll
      for (int reg = 0; reg < 4; ++reg) {
        int gi = gi0 + reg;
        float g = a1[i][j][reg] + a2[i][j][reg] * LO_SCALE_;
        float d = sqb[gi] + sj - 2.0f * g;
        float v = sqrtf(fmaxf(d, 0.0f)) * INV_SQRT_D_;
        vmax = fmaxf(vmax, v);
        if (!diag || gj >= gi) {
          dmb[(size_t)gi * N_ + gj] = v;
          dmb[(size_t)gj * N_ + gi] = v;
        }
      }
    }
  }
#pragma unroll
  for (int msk = 32; msk >= 1; msk >>= 1) vmax = fmaxf(vmax, __shfl_xor(vmax, msk));
  if (lane == 0) atomicMax((unsigned int*)(dmax + b), __float_as_uint(vmax));
}

// ---------------------------------------------------------------------------
// K3: kNN density
// ---------------------------------------------------------------------------
__global__ __launch_bounds__(64) void k_density(const float* __restrict__ dm,
    const float* __restrict__ noise, float* __restrict__ den)
{
  int row = blockIdx.x, lane = threadIdx.x;
  const float* r = dm + (size_t)row * N_;
  float a0 = 1e30f, a1 = 1e30f, a2 = 1e30f, a3 = 1e30f, a4 = 1e30f;
  auto ins5 = [&](float xv) {
    a4 = fminf(a4, xv);
    float t;
    t = fminf(a3, a4); a4 = fmaxf(a3, a4); a3 = t;
    t = fminf(a2, a3); a3 = fmaxf(a2, a3); a2 = t;
    t = fminf(a1, a2); a2 = fmaxf(a1, a2); a1 = t;
    t = fminf(a0, a1); a1 = fmaxf(a0, a1); a0 = t;
  };
#pragma unroll
  for (int t = 0; t < 9; ++t) ins5(r[lane + 64 * t]);
  for (int m = 1; m < 64; m <<= 1) {
    float b0 = __shfl_xor(a0, m), b1 = __shfl_xor(a1, m), b2 = __shfl_xor(a2, m);
    float b3 = __shfl_xor(a3, m), b4 = __shfl_xor(a4, m);
    ins5(b0); ins5(b1); ins5(b2); ins5(b3); ins5(b4);
  }
  if (lane == 0) {
    float ms = (a0 * a0 + a1 * a1 + a2 * a2 + a3 * a3 + a4 * a4) * 0.2f;
    den[row] = expf(-ms) + noise[row] * 1e-6f;
  }
}

// ---------------------------------------------------------------------------
// K5: dist-to-higher-density + score
// ---------------------------------------------------------------------------
__global__ __launch_bounds__(64) void k_dist(const float* __restrict__ dm,
    const float* __restrict__ den, const float* __restrict__ dmax,
    float* __restrict__ score)
{
  int row = blockIdx.x, lane = threadIdx.x;
  int b = row / N_;
  float di = den[row], dx = dmax[b];
  const float* r = dm + (size_t)row * N_;
  const float* db = den + b * N_;
  float m = dx;
#pragma unroll
  for (int t = 0; t < 9; ++t) {
    int j = lane + 64 * t;
    float v = (db[j] > di) ? r[j] : dx;
    m = fminf(m, v);
  }
  for (int msk = 1; msk < 64; msk <<= 1) m = fminf(m, __shfl_xor(m, msk));
  if (lane == 0) score[row] = m * di;
}

// ---------------------------------------------------------------------------
// K6: top-64 scores per batch — bitonic sort of 1024 (576 real + pad) on
// (score desc, idx asc); reproduces jax top_k tie-break.
// ---------------------------------------------------------------------------
__global__ __launch_bounds__(256) void k_topL(const float* __restrict__ score,
    int* __restrict__ idxd)
{
  int b = blockIdx.x, tid = threadIdx.x;
  __shared__ float s[1024];
  __shared__ int   si[1024];
  for (int i = tid; i < 1024; i += 256) {
    s[i] = (i < N_) ? score[b * N_ + i] : -3.0e38f;
    si[i] = i;
  }
  __syncthreads();
  for (int k = 2; k <= 1024; k <<= 1) {
    for (int j = k >> 1; j > 0; j >>= 1) {
#pragma unroll
      for (int t = 0; t < 2; ++t) {
        int idx512 = tid + t * 256;
        int lo = idx512 & (j - 1);
        int i = ((idx512 ^ lo) << 1) | lo;
        int p = i | j;
        float as = s[i], bs = s[p];
        int ai = si[i], bi = si[p];
        bool bba = (bs > as) || (bs == as && bi < ai);
        bool up = ((i & k) == 0);
        bool dosw = up ? bba : !bba;
        if (dosw) { s[i] = bs; s[p] = as; si[i] = bi; si[p] = ai; }
      }
      __syncthreads();
    }
  }
  if (tid < L_) idxd[b * L_ + tid] = si[tid];
}

// ---------------------------------------------------------------------------
// K7: assign tokens to nearest center (+ fused center self-assignment)
// ---------------------------------------------------------------------------
__global__ __launch_bounds__(576) void k_assign(const float* __restrict__ dm,
    const int* __restrict__ idxd, int* __restrict__ idxc)
{
  int b = blockIdx.x, n = threadIdx.x;
  __shared__ int ctr[L_];
  if (n < L_) ctr[n] = idxd[b * L_ + n];
  __syncthreads();
  const float* dmb = dm + (size_t)b * N_ * N_;
  float best = 1e30f; int bl = 0;
  for (int l = 0; l < L_; ++l) {
    float v = dmb[(size_t)ctr[l] * N_ + n];
    if (v < best) { best = v; bl = l; }
  }
  for (int l = 0; l < L_; ++l)
    if (ctr[l] == n) bl = l;
  idxc[b * N_ + n] = bl;
}

// ---------------------------------------------------------------------------
// K7b: bucket tokens by cluster (stable counting sort; one thread per cluster)
// ---------------------------------------------------------------------------
__global__ __launch_bounds__(64) void k_bucket(const int* __restrict__ idxc,
    int* __restrict__ ord, int* __restrict__ starts)
{
  int b = blockIdx.x, l = threadIdx.x;   // 64 threads = 1 wave
  __shared__ int ic[N_];
  for (int n = l; n < N_; n += 64) ic[n] = idxc[b * N_ + n];
  __syncthreads();
  int cnt = 0;
  for (int n = 0; n < N_; ++n) cnt += (ic[n] == l) ? 1 : 0;
  int inc = cnt;
  for (int d = 1; d < 64; d <<= 1) {
    int v = __shfl_up(inc, d);
    if (l >= d) inc += v;
  }
  int excl = inc - cnt;
  if (l == 0) starts[b * 65] = 0;
  starts[b * 65 + l + 1] = inc;
  int p = excl;
  for (int n = 0; n < N_; ++n)
    if (ic[n] == l) ord[b * N_ + p++] = n;
}

// ---------------------------------------------------------------------------
// K8: merger (gather via inverted index) — bit-identical to scan version.
// ---------------------------------------------------------------------------
__global__ __launch_bounds__(256) void k_merge(const unsigned short* __restrict__ xh,
    const unsigned short* __restrict__ xl,
    const float* __restrict__ ts, const int* __restrict__ ord,
    const int* __restrict__ starts, float* __restrict__ qin)
{
  int blk = blockIdx.x;
  int b = blk >> 6, l = blk & 63;
  int tid = threadIdx.x;
  int s0 = starts[b * 65 + l], s1 = starts[b * 65 + l + 1];
  const float* tsb = ts + b * N_;
  const int* ob = ord + b * N_;
  const unsigned short* xhb = xh + (size_t)b * N_ * D_;
  const unsigned short* xlb = xl + (size_t)b * N_ * D_;
  float a0 = 0.f, a1 = 0.f, a2 = 0.f, wsum = 0.f;
  for (int k = s0; k < s1; ++k) {
    int n = ob[k];
    float w = expf(tsb[n]);
    wsum += w;
    const unsigned short* hr = xhb + (size_t)n * D_;
    const unsigned short* lr = xlb + (size_t)n * D_;
    float x0 = h2f(hr[tid      ]) + h2f(lr[tid      ]) * LO_SCALE_;
    float x1 = h2f(hr[tid + 256]) + h2f(lr[tid + 256]) * LO_SCALE_;
    float x2 = h2f(hr[tid + 512]) + h2f(lr[tid + 512]) * LO_SCALE_;
    a0 += w * x0; a1 += w * x1; a2 += w * x2;
  }
  float inv = 1.0f / (wsum + 1e-6f);
  float* q = qin + (size_t)blk * D_;
  q[tid] = a0 * inv; q[tid + 256] = a1 * inv; q[tid + 512] = a2 * inv;
}

// ---------------------------------------------------------------------------
// Weight transpose + fp16 cast: W[K,N] fp32 -> WT[N,K] fp16
// ---------------------------------------------------------------------------
__global__ __launch_bounds__(256) void k_wt(const float* __restrict__ W,
    unsigned short* __restrict__ WT, int K, int N)
{
  __shared__ float t[32][33];
  int k0 = blockIdx.x * 32, n0 = blockIdx.y * 32;
  int tid = threadIdx.x;
  int r = tid >> 3, c4 = (tid & 7) * 4;
  float4 v = *(const float4*)(W + (size_t)(k0 + r) * N + n0 + c4);
  t[r][c4] = v.x; t[r][c4 + 1] = v.y; t[r][c4 + 2] = v.z; t[r][c4 + 3] = v.w;
  __syncthreads();
  ushort4 s4;
  s4.x = f2h(t[c4 + 0][r]); s4.y = f2h(t[c4 + 1][r]);
  s4.z = f2h(t[c4 + 2][r]); s4.w = f2h(t[c4 + 3][r]);
  *(ushort4*)(WT + (size_t)(n0 + r) * K + k0 + c4) = s4;
}

// ---------------------------------------------------------------------------
// MFMA GEMM: C[M,N] = epilogue(A[M,K] @ WT[N,K]^T), fp16 MFMA, fp32 accum.
// BK=64; As/Bs [128][64] with XOR-chunk swizzle; gload_lds staging.
// XCD M-panel affinity swizzle (T1): flat 1D grid; xcd = flat&7 owns M-tiles
// bm%8==xcd, and all N-tiles of one M-tile are adjacent in the XCD's stream
// -> A panel fetched once per XCD (L2-hit drains instead of HBM drains).
// Requires gm%8==0 (true for all instances). Bit-identical outputs.
// ---------------------------------------------------------------------------
template<int EPI, int ASRC>
__global__ __launch_bounds__(256) void k_mgemm(const void* __restrict__ Ap_,
    const unsigned short* __restrict__ Wt, const float* __restrict__ bias,
    const float* __restrict__ res, void* __restrict__ outp,
    int M, int Nd, int Kd)
{
  __shared__ __align__(16) unsigned short As[128 * 64];
  __shared__ __align__(16) unsigned short Bs[128 * 64];
  int tid = threadIdx.x;
  int gn = Nd >> 7;
  int flat = blockIdx.x;
  int xcd = flat & 7, seq = flat >> 3;
  int bmg = seq / gn, bnn = seq - bmg * gn;
  int bm = (bmg * 8 + xcd) * 128, bn = bnn * 128;
  int wave = tid >> 6, lane = tid & 63;
  int wr = (wave >> 1) * 64, wc = (wave & 1) * 64;
  int mloc = lane & 15, quad = lane >> 4;

  floatx4 acc[4][4];
#pragma unroll
  for (int i = 0; i < 4; ++i)
#pragma unroll
    for (int j = 0; j < 4; ++j)
      acc[i][j] = (floatx4){0.f, 0.f, 0.f, 0.f};

  int lrow = lane >> 3, lchunk = lane & 7;
  const unsigned short* bsrc0 =
      Wt + (size_t)(bn + wave * 32 + lrow) * Kd + ((lchunk ^ lrow) * 8);
  unsigned short* bdst0 = &Bs[(wave * 32) * 64];
  const unsigned short* asrc0 = (ASRC == 1)
      ? (const unsigned short*)Ap_ + (size_t)(bm + wave * 32 + lrow) * Kd + ((lchunk ^ lrow) * 8)
      : nullptr;
  unsigned short* adst0 = &As[(wave * 32) * 64];

  for (int kt = 0; kt < Kd; kt += 64) {
    __syncthreads();
#pragma unroll
    for (int rb = 0; rb < 4; ++rb)
      gload_lds16(bsrc0 + (size_t)rb * 8 * Kd + kt, bdst0 + rb * 8 * 64);
    if (ASRC == 1) {
#pragma unroll
      for (int rb = 0; rb < 4; ++rb)
        gload_lds16(asrc0 + (size_t)rb * 8 * Kd + kt, adst0 + rb * 8 * 64);
    } else {
      const float* A = (const float*)Ap_;
#pragma unroll
      for (int it = 0; it < 4; ++it) {
        int idx = tid + it * 256;
        int r = idx >> 3, c = idx & 7;
        const float* ap = A + (size_t)(bm + r) * Kd + kt + c * 8;
        float4 f0 = *(const float4*)ap;
        float4 f1 = *(const float4*)(ap + 4);
        uint4 pk;
        pk.x = (unsigned)f2h(f0.x) | ((unsigned)f2h(f0.y) << 16);
        pk.y = (unsigned)f2h(f0.z) | ((unsigned)f2h(f0.w) << 16);
        pk.z = (unsigned)f2h(f1.x) | ((unsigned)f2h(f1.y) << 16);
        pk.w = (unsigned)f2h(f1.z) | ((unsigned)f2h(f1.w) << 16);
        *(uint4*)&As[r * 64 + ((c ^ (r & 7)) * 8)] = pk;
      }
    }
    __syncthreads();
#pragma unroll
    for (int ks = 0; ks < 2; ++ks) {
      half8v af[4], bf[4];
      int cperm = (((ks << 2) | quad) ^ (mloc & 7)) * 8;
#pragma unroll
      for (int i = 0; i < 4; ++i)
        af[i] = *(const half8v*)&As[(wr + i * 16 + mloc) * 64 + cperm];
#pragma unroll
      for (int j = 0; j < 4; ++j)
        bf[j] = *(const half8v*)&Bs[(wc + j * 16 + mloc) * 64 + cperm];
#pragma unroll
      for (int i = 0; i < 4; ++i)
#pragma unroll
        for (int j = 0; j < 4; ++j)
          acc[i][j] = __builtin_amdgcn_mfma_f32_16x16x32_f16(af[i], bf[j], acc[i][j], 0, 0, 0);
    }
  }

  float bv[4] = {0.f, 0.f, 0.f, 0.f};
  if (EPI >= 1) {
#pragma unroll
    for (int j = 0; j < 4; ++j) bv[j] = bias[bn + wc + j * 16 + mloc];
  }
#pragma unroll
  for (int i = 0; i < 4; ++i) {
    int gr0 = bm + wr + i * 16 + quad * 4;
#pragma unroll
    for (int j = 0; j < 4; ++j) {
      int gcn = bn + wc + j * 16 + mloc;
#pragma unroll
      for (int reg = 0; reg < 4; ++reg) {
        float v = acc[i][j][reg];
        size_t off = (size_t)(gr0 + reg) * Nd + gcn;
        if (EPI == 0) {
          ((unsigned short*)outp)[off] = f2h(v);
        } else if (EPI == 1) {
          ((float*)outp)[off] = v + bv[j] + res[off];
        } else {
          v += bv[j];
          v = 0.5f * v * (1.0f + erff(v * 0.70710678f));
          ((unsigned short*)outp)[off] = f2h(v);
        }
      }
    }
  }
}

// ---------------------------------------------------------------------------
// K12: MFMA flash cross-attention with token-score bias (all fp16 operands).
// ---------------------------------------------------------------------------
__global__ __launch_bounds__(256) void k_attn(const unsigned short* __restrict__ Qu,
    const unsigned short* __restrict__ KVu, const float* __restrict__ ts,
    float* __restrict__ aout)
{
  __shared__ __align__(16) unsigned short Ks[64 * 104];
  __shared__ __align__(16) unsigned short VsT[96 * 64];
  __shared__ __align__(16) unsigned short sPa[64 * 64];
  __shared__ float tsb[64];
  int h = blockIdx.x, b = blockIdx.y;
  int tid = threadIdx.x;
  int wave = tid >> 6, lane = tid & 63;
  int mloc = lane & 15, quad = lane >> 4;

  half8v qf[3];
  {
    const unsigned short* qrow = Qu + (size_t)(b * 64 + wave * 16 + mloc) * D_ + h * 96 + quad * 8;
#pragma unroll
    for (int k = 0; k < 3; ++k) qf[k] = *(const half8v*)(qrow + k * 32);
  }

  floatx4 of[6];
#pragma unroll
  for (int dt = 0; dt < 6; ++dt) of[dt] = (floatx4){0.f, 0.f, 0.f, 0.f};
  float m[4], l[4];
#pragma unroll
  for (int r = 0; r < 4; ++r) { m[r] = -1e30f; l[r] = 0.f; }

  for (int jt = 0; jt < 9; ++jt) {
    int j0 = jt * 64;
    __syncthreads();
#pragma unroll
    for (int t = 0; t < 3; ++t) {
      int id = tid + t * 256;
      int row = id / 12, c = id % 12;
      *(uint4*)&Ks[row * 104 + c * 8] =
          *(const uint4*)(KVu + (size_t)(b * N_ + j0 + row) * KV_STRIDE_ + h * 96 + c * 8);
    }
#pragma unroll
    for (int t = 0; t < 3; ++t) {
      int id = tid + t * 256;
      int keyp = id & 31, dq = (id >> 5) * 4;
      int key = keyp * 2;
      const unsigned short* vp =
          KVu + (size_t)(b * N_ + j0 + key) * KV_STRIDE_ + 768 + h * 96 + dq;
      ushort4 v0 = *(const ushort4*)vp;
      ushort4 v1 = *(const ushort4*)(vp + KV_STRIDE_);
      unsigned pk0 = (unsigned)v0.x | ((unsigned)v1.x << 16);
      unsigned pk1 = (unsigned)v0.y | ((unsigned)v1.y << 16);
      unsigned pk2 = (unsigned)v0.z | ((unsigned)v1.z << 16);
      unsigned pk3 = (unsigned)v0.w | ((unsigned)v1.w << 16);
      int cbase = key >> 3, off = key & 7;
#pragma unroll
      for (int i = 0; i < 4; ++i) {
        int d = dq + i;
        unsigned pv = (i == 0) ? pk0 : (i == 1) ? pk1 : (i == 2) ? pk2 : pk3;
        *(unsigned*)&VsT[d * 64 + ((cbase ^ (d & 7)) << 3) + off] = pv;
      }
    }
    if (tid < 64) tsb[tid] = ts[b * N_ + j0 + tid];
    __syncthreads();

    floatx4 acc[4];
#pragma unroll
    for (int j = 0; j < 4; ++j) acc[j] = (floatx4){0.f, 0.f, 0.f, 0.f};
#pragma unroll
    for (int j = 0; j < 4; ++j)
#pragma unroll
      for (int k = 0; k < 3; ++k) {
        half8v kf = *(const half8v*)&Ks[(j * 16 + mloc) * 104 + k * 32 + quad * 8];
        acc[j] = __builtin_amdgcn_mfma_f32_16x16x32_f16(qf[k], kf, acc[j], 0, 0, 0);
      }

    float ts4[4];
#pragma unroll
    for (int j = 0; j < 4; ++j) ts4[j] = tsb[j * 16 + mloc];
    float rm[4] = {-1e30f, -1e30f, -1e30f, -1e30f};
#pragma unroll
    for (int j = 0; j < 4; ++j)
#pragma unroll
      for (int r = 0; r < 4; ++r) {
        acc[j][r] = acc[j][r] * SCALE_ + ts4[j];
        rm[r] = fmaxf(rm[r], acc[j][r]);
      }
#pragma unroll
    for (int r = 0; r < 4; ++r) {
      rm[r] = fmaxf(rm[r], __shfl_xor(rm[r], 1));
      rm[r] = fmaxf(rm[r], __shfl_xor(rm[r], 2));
      rm[r] = fmaxf(rm[r], __shfl_xor(rm[r], 4));
      rm[r] = fmaxf(rm[r], __shfl_xor(rm[r], 8));
    }
    float alpha[4], rs[4];
#pragma unroll
    for (int r = 0; r < 4; ++r) {
      float mn = fmaxf(m[r], rm[r]);
      alpha[r] = __expf(m[r] - mn);
      m[r] = mn;
      rs[r] = 0.f;
    }
#pragma unroll
    for (int j = 0; j < 4; ++j)
#pragma unroll
      for (int r = 0; r < 4; ++r) {
        float p = __expf(acc[j][r] - m[r]);
        acc[j][r] = p; rs[r] += p;
      }
#pragma unroll
    for (int r = 0; r < 4; ++r) {
      rs[r] += __shfl_xor(rs[r], 1); rs[r] += __shfl_xor(rs[r], 2);
      rs[r] += __shfl_xor(rs[r], 4); rs[r] += __shfl_xor(rs[r], 8);
      l[r] = l[r] * alpha[r] + rs[r];
    }
#pragma unroll
    for (int dt = 0; dt < 6; ++dt)
#pragma unroll
      for (int r = 0; r < 4; ++r) of[dt][r] *= alpha[r];

#pragma unroll
    for (int j = 0; j < 4; ++j)
#pragma unroll
      for (int r = 0; r < 4; ++r) {
        int row = wave * 16 + quad * 4 + r;
        int key = j * 16 + mloc;
        sPa[row * 64 + (((key >> 3) ^ (row & 7)) << 3) + (key & 7)] = f2h(acc[j][r]);
      }
    half8v pa[2];
    int prow = wave * 16 + mloc;
#pragma unroll
    for (int f2 = 0; f2 < 2; ++f2)
      pa[f2] = *(const half8v*)&sPa[prow * 64 + (((f2 * 4 + quad) ^ (prow & 7)) << 3)];
#pragma unroll
    for (int dt = 0; dt < 6; ++dt)
#pragma unroll
      for (int f2 = 0; f2 < 2; ++f2) {
        int vrow = dt * 16 + mloc;
        half8v vf = *(const half8v*)&VsT[vrow * 64 + (((f2 * 4 + quad) ^ (vrow & 7)) << 3)];
        of[dt] = __builtin_amdgcn_mfma_f32_16x16x32_f16(pa[f2], vf, of[dt], 0, 0, 0);
      }
  }

  float linv[4];
#pragma unroll
  for (int r = 0; r < 4; ++r) linv[r] = 1.0f / l[r];
#pragma unroll
  for (int dt = 0; dt < 6; ++dt)
#pragma unroll
    for (int r = 0; r < 4; ++r) {
      int row = b * 64 + wave * 16 + quad * 4 + r;
      int col = h * 96 + dt * 16 + mloc;
      aout[(size_t)row * D_ + col] = of[dt][r] * linv[r];
    }
}

// ---------------------------------------------------------------------------
// K14: LayerNorm2 (fp32 in -> fp32 out)
// ---------------------------------------------------------------------------
__global__ __launch_bounds__(256) void k_ln2(const float* __restrict__ f,
    const float* __restrict__ g, const float* __restrict__ bt, float* __restrict__ out)
{
  int row = blockIdx.x, tid = threadIdx.x;
  const float* fr = f + (size_t)row * D_;
  float v0 = fr[tid], v1 = fr[tid + 256], v2 = fr[tid + 512];
  __shared__ float r1[256], r2[256];
  r1[tid] = v0 + v1 + v2;
  r2[tid] = v0 * v0 + v1 * v1 + v2 * v2;
  __syncthreads();
  for (int o = 128; o > 0; o >>= 1) {
    if (tid < o) { r1[tid] += r1[tid + o]; r2[tid] += r2[tid + o]; }
    __syncthreads();
  }
  float mean = r1[0] * (1.0f / D_);
  float var  = r2[0] * (1.0f / D_) - mean * mean;
  float rstd = rsqrtf(var + 1e-5f);
  float* oo = out + (size_t)row * D_;
  oo[tid      ] = (v0 - mean) * rstd * g[tid      ] + bt[tid      ];
  oo[tid + 256] = (v1 - mean) * rstd * g[tid + 256] + bt[tid + 256];
  oo[tid + 512] = (v2 - mean) * rstd * g[tid + 512] + bt[tid + 512];
}

// ---------------------------------------------------------------------------
// Launch
// ---------------------------------------------------------------------------
extern "C" void kernel_launch(void* const* d_in, const int* in_sizes, int n_in,
                              void* d_out, int out_size, void* d_ws, size_t ws_size,
                              hipStream_t stream)
{
  (void)in_sizes; (void)n_in; (void)out_size; (void)ws_size;
  const float* x    = (const float*)d_in[0];
  const float* nois = (const float*)d_in[1];
  const float* n1g  = (const float*)d_in[2];
  const float* n1b  = (const float*)d_in[3];
  const float* sw   = (const float*)d_in[4];
  const float* sb   = (const float*)d_in[5];
  const float* wq   = (const float*)d_in[6];
  const float* wk   = (const float*)d_in[7];
  const float* wv   = (const float*)d_in[8];
  const float* pw   = (const float*)d_in[9];
  const float* pb   = (const float*)d_in[10];
  const float* n2g  = (const float*)d_in[11];
  const float* n2b  = (const float*)d_in[12];
  const float* f1w  = (const float*)d_in[13];
  const float* f1b  = (const float*)d_in[14];
  const float* f2w  = (const float*)d_in[15];
  const float* f2b  = (const float*)d_in[16];

  float* ws    = (float*)d_ws;
  unsigned short* XH = (unsigned short*)ws;                 // fp16 hi plane
  unsigned short* XL = XH + (size_t)NB_ * D_;               // fp16 lo plane
  float* RG    = ws + (size_t)NB_ * D_;
  float* QIN   = RG + (size_t)NB_ * D_;
  float* FEAT  = QIN + (size_t)ML_ * D_;
  float* AOUT  = FEAT + (size_t)ML_ * D_;
  float* QBUF  = AOUT + (size_t)ML_ * D_;
  float* P     = QBUF + (size_t)ML_ * D_;
  unsigned short* QH16 = (unsigned short*)P;  P += (size_t)ML_ * D_ / 2;
  unsigned short* WTQ  = (unsigned short*)P;  P += (size_t)D_ * D_ / 2;
  unsigned short* WTKV = (unsigned short*)P;  P += (size_t)D_ * D_;     // K then V
  unsigned short* WTP  = (unsigned short*)P;  P += (size_t)D_ * D_ / 2;
  unsigned short* WT1  = (unsigned short*)P;  P += (size_t)D_ * 4 * D_ / 2;
  unsigned short* WT2  = (unsigned short*)P;  P += (size_t)D_ * 4 * D_ / 2;
  float* TS    = P;
  float* SQ    = TS + NB_;
  float* DEN   = SQ + NB_;
  float* SCORE = DEN + NB_;
  float* DMAX  = SCORE + NB_;
  int*   IDXD  = (int*)(DMAX + 64);
  int*   IDXC  = IDXD + ML_;
  int*   ORD   = IDXC + NB_;
  int*   STARTS= ORD + NB_;           // B_*65 ints
  float* DM    = RG;                               // phase 1
  unsigned short* KVB = (unsigned short*)RG;       // phase 2: [NB_][1536] K|V
  unsigned short* HID = (unsigned short*)RG;       // phase 3

  hipMemsetAsync(DMAX, 0, 64 * sizeof(float), stream);
  k_wt<<<dim3(24, 24), 256, 0, stream>>>(wq, WTQ, D_, D_);
  k_wt<<<dim3(24, 24), 256, 0, stream>>>(wk, WTKV, D_, D_);
  k_wt<<<dim3(24, 24), 256, 0, stream>>>(wv, WTKV + (size_t)D_ * D_, D_, D_);
  k_wt<<<dim3(24, 24), 256, 0, stream>>>(pw, WTP, D_, D_);
  k_wt<<<dim3(24, 96), 256, 0, stream>>>(f1w, WT1, D_, 4 * D_);
  k_wt<<<dim3(96, 24), 256, 0, stream>>>(f2w, WT2, 4 * D_, D_);

  k_ln1<<<NB_, 256, 0, stream>>>(x, n1g, n1b, sw, sb, XH, XL, TS, SQ);
  k_dmg<<<1344, 256, 0, stream>>>(XH, XL, SQ, DM, DMAX);
  k_density<<<NB_, 64, 0, stream>>>(DM, nois, DEN);
  k_dist<<<NB_, 64, 0, stream>>>(DM, DEN, DMAX, SCORE);
  k_topL<<<B_, 256, 0, stream>>>(SCORE, IDXD);
  k_assign<<<B_, 576, 0, stream>>>(DM, IDXD, IDXC);
  k_bucket<<<B_, 64, 0, stream>>>(IDXC, ORD, STARTS);
  k_merge<<<ML_, 256, 0, stream>>>(XH, XL, TS, ORD, STARTS, QIN);

  k_mgemm<0, 0><<<(ML_ / 128) * (D_ / 128), 256, 0, stream>>>(
      QIN, WTQ, nullptr, nullptr, QH16, ML_, D_, D_);
  k_mgemm<0, 1><<<(NB_ / 128) * (KV_STRIDE_ / 128), 256, 0, stream>>>(
      XH, WTKV, nullptr, nullptr, KVB, NB_, KV_STRIDE_, D_);
  k_attn<<<dim3(H_, B_), 256, 0, stream>>>(QH16, KVB, TS, AOUT);
  k_mgemm<1, 0><<<(ML_ / 128) * (D_ / 128), 256, 0, stream>>>(
      AOUT, WTP, pb, QIN, FEAT, ML_, D_, D_);
  k_ln2<<<ML_, 256, 0, stream>>>(FEAT, n2g, n2b, QBUF);
  k_mgemm<2, 0><<<(ML_ / 128) * ((4 * D_) / 128), 256, 0, stream>>>(
      QBUF, WT1, f1b, nullptr, HID, ML_, 4 * D_, D_);
  k_mgemm<1, 1><<<(ML_ / 128) * (D_ / 128), 256, 0, stream>>>(
      HID, WT2, f2b, FEAT, d_out, ML_, D_, 4 * D_);
}